// Round 1
// 1576.333 us; speedup vs baseline: 1.0261x; 1.0261x over previous
//
#include <hip/hip_runtime.h>
#include <math.h>

#define EPS_NORM 1e-5f
#define EPS_VAR  1e-9f

typedef unsigned short ushort_t;
typedef __attribute__((ext_vector_type(4))) float f32x4;
typedef _Float16 half8 __attribute__((ext_vector_type(8)));

#define MFMAH(a, b, c) __builtin_amdgcn_mfma_f32_16x16x32_f16((a), (b), (c), 0, 0, 0)

// async global->LDS DMA, 16B per lane; LDS dest = wave-uniform base + lane*16
#define GLD16(gp, lp) __builtin_amdgcn_global_load_lds(                          \
    (const __attribute__((address_space(1))) unsigned int*)(gp),                 \
    (__attribute__((address_space(3))) unsigned int*)(lp), 16, 0, 0)

// ---------------------------------------------------------------------------
// fp16 helpers
// ---------------------------------------------------------------------------
__device__ inline ushort_t f16_bits(float x) {
    _Float16 h = (_Float16)x;
    ushort_t u;
    __builtin_memcpy(&u, &h, 2);
    return u;
}
__device__ inline half8 ldh(const ushort_t* p) {   // 16B-aligned load
    half8 h;
    __builtin_memcpy(&h, p, 16);
    return h;
}
__device__ inline uint4 pack8(const ushort_t* s) {
    uint4 r;
    r.x = (unsigned)s[0] | ((unsigned)s[1] << 16);
    r.y = (unsigned)s[2] | ((unsigned)s[3] << 16);
    r.z = (unsigned)s[4] | ((unsigned)s[5] << 16);
    r.w = (unsigned)s[6] | ((unsigned)s[7] << 16);
    return r;
}

// ---------------------------------------------------------------------------
// Stage 1: per-(batch, channel) sum / sumsq over spatial axis (split-N atomic)
// ---------------------------------------------------------------------------
__global__ void __launch_bounds__(256) stat_partial(
    const float* __restrict__ x, float* __restrict__ sum, float* __restrict__ sumsq,
    int N, int Cn, int chG, int nG, int nPer)
{
    int bx = blockIdx.x;
    int b  = bx / (chG * nG);
    int r  = bx % (chG * nG);
    int cg = r / nG;
    int ng = r % nG;
    int ch = cg * 256 + threadIdx.x;
    if (ch >= Cn) return;
    int n0 = ng * nPer;
    int n1 = min(n0 + nPer, N);
    const float* p = x + (long)(b * N) * Cn + ch;
    float s = 0.f, ss = 0.f;
    for (int n = n0; n < n1; ++n) {
        float v = p[(long)n * Cn];
        s += v;
        ss = fmaf(v, v, ss);
    }
    atomicAdd(&sum[b * Cn + ch], s);
    atomicAdd(&sumsq[b * Cn + ch], ss);
}

__global__ void __launch_bounds__(256) stat_finalize(
    float* __restrict__ sum, float* __restrict__ sumsq, int total, float invN)
{
    int i = blockIdx.x * blockDim.x + threadIdx.x;
    if (i >= total) return;
    float m = sum[i] * invN;
    float v = sumsq[i] * invN - m * m;
    sum[i]   = m;
    sumsq[i] = rsqrtf(v + EPS_NORM);
}

// ---------------------------------------------------------------------------
// Prepass: normalize X (B,N,Cn) -> fp16 (same layout)
// ---------------------------------------------------------------------------
__global__ void __launch_bounds__(256) norm_f16(
    const float* __restrict__ x, const float* __restrict__ mean,
    const float* __restrict__ rstd, ushort_t* __restrict__ out, int N, int Cn)
{
    int bn = blockIdx.x;          // b*N + n
    int b  = bn / N;
    long base = (long)bn * Cn;
    for (int ch = threadIdx.x; ch < Cn; ch += 256) {
        float v = (x[base + ch] - mean[b * Cn + ch]) * rstd[b * Cn + ch];
        out[base + ch] = f16_bits(v);
    }
}

// ---------------------------------------------------------------------------
// Prepass: V (B,N,C) -> transposed (B,C,N) fp16  (V^2 squared in-kernel)
// ---------------------------------------------------------------------------
template<int KSEG>
__global__ void __launch_bounds__(256) vsplit_t(
    const float* __restrict__ v, ushort_t* __restrict__ vt, int N, int C)
{
    int cPB = C / 64, nSeg = N / KSEG;
    int bid = blockIdx.x;
    int b   = bid / (cPB * nSeg);
    int rem = bid % (cPB * nSeg);
    int cb  = rem / nSeg;
    int ns  = rem % nSeg;
    int ch  = cb * 64 + (threadIdx.x & 63);
    const int KL = KSEG / 4;
    int k0  = ns * KSEG + (threadIdx.x >> 6) * KL;
    long obase = ((long)b * C + ch) * N;
    for (int k = k0; k < k0 + KL; k += 8) {
        ushort_t h8[8];
#pragma unroll
        for (int i = 0; i < 8; ++i)
            h8[i] = f16_bits(v[((long)b * N + k + i) * C + ch]);
        *(uint4*)(vt + obase + k) = pack8(h8);
    }
}

// ---------------------------------------------------------------------------
// Async DMA tile stagers.  LDS tiles are 64 shorts/row, XOR-swizzled:
// LDS[r][g] (16B granule g of row r) holds global[r][g ^ (r&7)].
// global_load_lds writes linearly (base + lane*16), so the swizzle is applied
// on the GLOBAL source granule; reads undo it via the same XOR (involution).
// ---------------------------------------------------------------------------
__device__ inline void stage64_async(const ushort_t* __restrict__ g, long rowBase,
                                     int gstride, int col0, ushort_t* slab, int tid)
{
    const int l  = tid & 63, w = tid >> 6;
    const int rs = l >> 3;                 // == r & 7
    const int cg = (l & 7) ^ rs;           // pre-swizzled source granule
#pragma unroll
    for (int i = 0; i < 2; ++i) {
        const int r = w * 16 + i * 8 + rs;
        const ushort_t* gp = g + (rowBase + r) * (long)gstride + col0 + (cg << 3);
        ushort_t* lp = slab + (w * 16 + i * 8) * 64 + l * 8;
        GLD16(gp, lp);
    }
}
template<int BROWS>   // BROWS in {16, 32}; BROWS*8 threads, full waves active
__device__ inline void stageQ_async(const ushort_t* __restrict__ g, long rowBase,
                                    int gstride, int col0, ushort_t* slab, int tid)
{
    if (tid < BROWS * 8) {
        const int l  = tid & 63, w = tid >> 6;
        const int rs = l >> 3;
        const int cg = (l & 7) ^ rs;
        const int r  = w * 8 + rs;
        const ushort_t* gp = g + (rowBase + r) * (long)gstride + col0 + (cg << 3);
        ushort_t* lp = slab + w * 8 * 64 + l * 8;
        GLD16(gp, lp);
    }
}
// swizzled LDS read: global granule (soff>>3) of row `row`
__device__ inline half8 ldsw(const ushort_t* slab, int row, int soff)
{
    const int gr = (soff >> 3) ^ (row & 7);
    return ldh(slab + row * 64 + (gr << 3));
}

// ---------------------------------------------------------------------------
// Pipelined flash for scale 2 (N=4096, Cc=448, C=256, QREG, SPLIT=2).
// 3 phases/tile, 2x4-slab LDS ping-pong, counted vmcnt (never 0 in steady
// state), raw s_barrier (no compiler vmcnt(0) drain), setprio around MFMA.
//   A: prefetch K[4..6](t) -> other | compute QK chunks 0..3 (32 MFMA)
//   B: prefetch V(t)       -> other | compute QK chunks 4..6 (24 MFMA) + softmax
//   C: prefetch K[0..3](t+1)-> other| compute PV/PV^2 (64 MFMA)
// ---------------------------------------------------------------------------
__global__ void __launch_bounds__(256, 2) flash_pipe(
    const ushort_t* __restrict__ Qh, const ushort_t* __restrict__ Kh,
    const ushort_t* __restrict__ Vth,
    float* __restrict__ Pmo, float* __restrict__ Plo,
    float* __restrict__ PMo, float* __restrict__ PSo)
{
    constexpr int Cc = 448, C = 256, N = 4096, SPLIT = 2;
    constexpr int NKT = (N / 64) / SPLIT;          // 32 key tiles per block

    __shared__ __align__(16) ushort_t smem[2 * 16384 + 4 * 1152];
    const int tid  = threadIdx.x;
    const int lane = tid & 63;
    const int w    = tid >> 6;
    const int l15  = lane & 15;
    const int quad = lane >> 4;

    const int bq = blockIdx.x / SPLIT;
    const int sp = blockIdx.x % SPLIT;
    const int b  = bq / (N / 64);
    const int qb = bq % (N / 64);
    const int i0 = qb * 64 + w * 16;
    const long po = (long)(b * (N / 16) + qb * 4 + w) * SPLIT + sp;
    ushort_t* Pw = smem + 32768 + w * 1152;

    half8 qf[14];
    {
        const ushort_t* q1 = Qh + ((long)(b * N + i0 + l15)) * Cc + quad * 8;
#pragma unroll
        for (int ks = 0; ks < 14; ++ks) qf[ks] = ldh(q1 + ks * 32);
    }

    float m_r[4], l_l[4], mw = -1e30f;
    f32x4 Mac[16], Sac[16];
#pragma unroll
    for (int r = 0; r < 4; ++r) { m_r[r] = -1e30f; l_l[r] = 0.f; }
#pragma unroll
    for (int ct = 0; ct < 16; ++ct)
#pragma unroll
        for (int r = 0; r < 4; ++r) { Mac[ct][r] = 0.f; Sac[ct][r] = 0.f; }

    const long krow0 = (long)b * N + (long)sp * NKT * 64;
    // prologue: K chunks 0..3 of tile 0 -> buffer 0  (8 DMA insts/wave)
#pragma unroll
    for (int j = 0; j < 4; ++j)
        stage64_async(Kh, krow0, Cc, j * 64, smem + j * 4096, tid);
    int cur = 0;

    for (int t = 0; t < NKT; ++t) {
        const long krow = krow0 + (long)t * 64;
        f32x4 S[4];
#pragma unroll
        for (int ct = 0; ct < 4; ++ct)
#pragma unroll
            for (int r = 0; r < 4; ++r) S[ct][r] = 0.f;

        // ---------------- phase A ----------------
        __builtin_amdgcn_s_barrier();              // everyone done reading other buf
#pragma unroll
        for (int j = 0; j < 3; ++j)                // prefetch K chunks 4..6 (6 insts)
            stage64_async(Kh, krow, Cc, (4 + j) * 64,
                          smem + (cur ^ 1) * 16384 + j * 4096, tid);
        asm volatile("s_waitcnt vmcnt(6)" ::: "memory");   // K 0..3 landed
        __builtin_amdgcn_sched_barrier(0);
        __builtin_amdgcn_s_barrier();              // ... for all waves
        __builtin_amdgcn_s_setprio(1);
        {
            const ushort_t* kb = smem + cur * 16384;
#pragma unroll
            for (int j = 0; j < 4; ++j)
#pragma unroll
                for (int ks = 0; ks < 2; ++ks) {
                    half8 a = qf[j * 2 + ks];
#pragma unroll
                    for (int ct = 0; ct < 4; ++ct) {
                        half8 bf = ldsw(kb + j * 4096, ct * 16 + l15, ks * 32 + quad * 8);
                        S[ct] = MFMAH(a, bf, S[ct]);
                    }
                }
        }
        __builtin_amdgcn_s_setprio(0);
        cur ^= 1;

        // ---------------- phase B ----------------
        __builtin_amdgcn_s_barrier();
#pragma unroll
        for (int j = 0; j < 4; ++j)                // prefetch V slabs (8 insts)
            stage64_async(Vth, (long)b * C + j * 64, N, (sp * NKT + t) * 64,
                          smem + (cur ^ 1) * 16384 + j * 4096, tid);
        asm volatile("s_waitcnt vmcnt(8)" ::: "memory");   // K 4..6 landed
        __builtin_amdgcn_sched_barrier(0);
        __builtin_amdgcn_s_barrier();
        __builtin_amdgcn_s_setprio(1);
        {
            const ushort_t* kb = smem + cur * 16384;
#pragma unroll
            for (int j = 0; j < 3; ++j)
#pragma unroll
                for (int ks = 0; ks < 2; ++ks) {
                    half8 a = qf[(4 + j) * 2 + ks];
#pragma unroll
                    for (int ct = 0; ct < 4; ++ct) {
                        half8 bf = ldsw(kb + j * 4096, ct * 16 + l15, ks * 32 + quad * 8);
                        S[ct] = MFMAH(a, bf, S[ct]);
                    }
                }
        }
        __builtin_amdgcn_s_setprio(0);

        // ---- online softmax, lazy base ----
        float tmax = S[0][0];
#pragma unroll
        for (int ct = 0; ct < 4; ++ct)
#pragma unroll
            for (int r = 0; r < 4; ++r) tmax = fmaxf(tmax, S[ct][r]);
#pragma unroll
        for (int off = 1; off <= 32; off <<= 1)
            tmax = fmaxf(tmax, __shfl_xor(tmax, off, 64));

        if (tmax > mw + 10.f) {
            float rm[4];
#pragma unroll
            for (int r = 0; r < 4; ++r)
                rm[r] = fmaxf(fmaxf(S[0][r], S[1][r]), fmaxf(S[2][r], S[3][r]));
#pragma unroll
            for (int off = 1; off <= 8; off <<= 1)
#pragma unroll
                for (int r = 0; r < 4; ++r)
                    rm[r] = fmaxf(rm[r], __shfl_xor(rm[r], off, 64));
#pragma unroll
            for (int r = 0; r < 4; ++r) {
                float mn = fmaxf(m_r[r], rm[r]);
                float corr = __expf(m_r[r] - mn);
                m_r[r] = mn;
                l_l[r] *= corr;
#pragma unroll
                for (int ct = 0; ct < 16; ++ct) { Mac[ct][r] *= corr; Sac[ct][r] *= corr; }
            }
            float tt = fminf(fminf(m_r[0], m_r[1]), fminf(m_r[2], m_r[3]));
            tt = fminf(tt, __shfl_xor(tt, 16, 64));
            tt = fminf(tt, __shfl_xor(tt, 32, 64));
            mw = tt;
        }

#pragma unroll
        for (int ct = 0; ct < 4; ++ct)
#pragma unroll
            for (int r = 0; r < 4; ++r) {
                float p = __expf(S[ct][r] - m_r[r]);   // p <= e^10, f16-safe
                l_l[r] += p;
                Pw[(quad * 4 + r) * 72 + ct * 16 + l15] = f16_bits(p);
            }
        half8 pf0 = ldh(Pw + l15 * 72 + 0  + quad * 8);
        half8 pf1 = ldh(Pw + l15 * 72 + 32 + quad * 8);
        cur ^= 1;

        // ---------------- phase C ----------------
        __builtin_amdgcn_s_barrier();
        if (t + 1 < NKT) {
#pragma unroll
            for (int j = 0; j < 4; ++j)            // prefetch next tile K 0..3
                stage64_async(Kh, krow + 64, Cc, j * 64,
                              smem + (cur ^ 1) * 16384 + j * 4096, tid);
            asm volatile("s_waitcnt vmcnt(8)" ::: "memory");   // V landed
        } else {
            asm volatile("s_waitcnt vmcnt(0)" ::: "memory");
        }
        __builtin_amdgcn_sched_barrier(0);
        __builtin_amdgcn_s_barrier();
        __builtin_amdgcn_s_setprio(1);
        {
            const ushort_t* vb = smem + cur * 16384;
#pragma unroll
            for (int ks = 0; ks < 2; ++ks) {
                half8 pf = ks ? pf1 : pf0;
#pragma unroll
                for (int j = 0; j < 4; ++j)
#pragma unroll
                    for (int ct = 0; ct < 4; ++ct) {
                        half8 vh = ldsw(vb + j * 4096, ct * 16 + l15, ks * 32 + quad * 8);
                        half8 uh = vh * vh;
                        const int ci = j * 4 + ct;
                        Mac[ci] = MFMAH(pf, vh, Mac[ci]);
                        Sac[ci] = MFMAH(pf, uh, Sac[ci]);
                    }
            }
        }
        __builtin_amdgcn_s_setprio(0);
        cur ^= 1;
    }

    // ---- reduce per-lane l, dump partial state ----
#pragma unroll
    for (int off = 1; off <= 8; off <<= 1)
#pragma unroll
        for (int r = 0; r < 4; ++r) l_l[r] += __shfl_xor(l_l[r], off, 64);

    if (l15 == 0) {
#pragma unroll
        for (int r = 0; r < 4; ++r) {
            Pmo[po * 16 + quad * 4 + r] = m_r[r];
            Plo[po * 16 + quad * 4 + r] = l_l[r];
        }
    }
#pragma unroll
    for (int ct = 0; ct < 16; ++ct)
#pragma unroll
        for (int r = 0; r < 4; ++r) {
            long idx = (po * 16 + quad * 4 + r) * C + ct * 16 + l15;
            PMo[idx] = Mac[ct][r];
            PSo[idx] = Sac[ct][r];
        }
}

// ---------------------------------------------------------------------------
// Generic flash (scales 3/4): __syncthreads structure, async DMA staging,
// swizzled unpadded LDS slabs (4096 shorts each).
// ---------------------------------------------------------------------------
template<int Cc, int C, int N, int CSPLIT, bool QREG, int SPLIT, int SLABS, int KGRP>
__global__ void __launch_bounds__(256, 2) flash_mfma(
    const ushort_t* __restrict__ Qh, const ushort_t* __restrict__ Kh,
    const ushort_t* __restrict__ Vth,
    float* __restrict__ Pmo, float* __restrict__ Plo,
    float* __restrict__ PMo, float* __restrict__ PSo)
{
    constexpr int KC      = Cc / 64;
    constexpr int VC      = C / 64;
    constexpr int VCW     = VC / CSPLIT;
    constexpr int CTCW    = 4 * VCW;
    constexpr int STRIPES = 4 / CSPLIT;
    constexpr int BROWS   = 16 * STRIPES;
    constexpr int QB      = N / BROWS;
    constexpr int TILES   = N / 64;
    constexpr int NKT     = TILES / SPLIT;
    constexpr int NKS     = QREG ? (Cc / 32) : 1;
    constexpr int NGRP    = (KC + KGRP - 1) / KGRP;
    constexpr int G       = 4 / CSPLIT;          // V chunks per wave per PV pair
    constexpr int QCH     = BROWS * 64;          // LDS shorts per staged Q chunk
    constexpr int QOFF    = KGRP * 4096;
    constexpr int KQEND   = QOFF + KGRP * QCH;
    constexpr int REGION  = QREG ? (SLABS * 4096)
                                 : (KQEND > SLABS * 4096 ? KQEND : SLABS * 4096);

    __shared__ __align__(16) ushort_t smem[REGION + 4 * 1152];
    const int tid  = threadIdx.x;
    const int lane = tid & 63;
    const int w    = tid >> 6;
    const int l15  = lane & 15;
    const int quad = lane >> 4;

    const int bq = blockIdx.x / SPLIT;
    const int sp = blockIdx.x % SPLIT;
    const int b  = bq / QB;
    const int qb = bq % QB;
    const int ls  = w / CSPLIT;       // stripe within block
    const int ch2 = w % CSPLIT;       // channel part
    const int i0 = qb * BROWS + ls * 16;
    const long po = (long)(b * (N / 16) + qb * STRIPES + ls) * SPLIT + sp;
    ushort_t* Pw = smem + REGION + w * 1152;

    half8 qf[NKS];
    if constexpr (QREG) {
        const ushort_t* q1 = Qh + ((long)(b * N + i0 + l15)) * Cc + quad * 8;
#pragma unroll
        for (int ks = 0; ks < NKS; ++ks) qf[ks] = ldh(q1 + ks * 32);
    }

    float m_r[4], l_l[4], mw = -1e30f;
    f32x4 Mac[CTCW], Sac[CTCW];
#pragma unroll
    for (int r = 0; r < 4; ++r) { m_r[r] = -1e30f; l_l[r] = 0.f; }
#pragma unroll
    for (int ct = 0; ct < CTCW; ++ct)
#pragma unroll
        for (int r = 0; r < 4; ++r) { Mac[ct][r] = 0.f; Sac[ct][r] = 0.f; }

    for (int kt = sp * NKT; kt < sp * NKT + NKT; ++kt) {
        const long krow = (long)b * N + kt * 64;

        f32x4 S[4];
#pragma unroll
        for (int ct = 0; ct < 4; ++ct)
#pragma unroll
            for (int r = 0; r < 4; ++r) S[ct][r] = 0.f;

        // ---- QK ----
#pragma unroll
        for (int grp = 0; grp < NGRP; ++grp) {
            const int g0 = grp * KGRP;
            const int gn = (KC - g0 < KGRP) ? (KC - g0) : KGRP;
            __syncthreads();
#pragma unroll
            for (int j = 0; j < KGRP; ++j) if (j < gn) {
                stage64_async(Kh, krow, Cc, (g0 + j) * 64, smem + j * 4096, tid);
                if constexpr (!QREG)
                    stageQ_async<BROWS>(Qh, (long)b * N + qb * BROWS, Cc, (g0 + j) * 64,
                                        smem + QOFF + j * QCH, tid);
            }
            __syncthreads();
#pragma unroll
            for (int j = 0; j < KGRP; ++j) if (j < gn) {
#pragma unroll
                for (int ks = 0; ks < 2; ++ks) {
                    half8 a;
                    if constexpr (QREG) a = qf[(g0 + j) * 2 + ks];
                    else a = ldsw(smem + QOFF + j * QCH, ls * 16 + l15, ks * 32 + quad * 8);
#pragma unroll
                    for (int ct = 0; ct < 4; ++ct) {
                        half8 bf = ldsw(smem + j * 4096, ct * 16 + l15, ks * 32 + quad * 8);
                        S[ct] = MFMAH(a, bf, S[ct]);
                    }
                }
            }
        }

        // ---- online softmax, lazy base ----
        float tmax = S[0][0];
#pragma unroll
        for (int ct = 0; ct < 4; ++ct)
#pragma unroll
            for (int r = 0; r < 4; ++r) tmax = fmaxf(tmax, S[ct][r]);
#pragma unroll
        for (int off = 1; off <= 32; off <<= 1)
            tmax = fmaxf(tmax, __shfl_xor(tmax, off, 64));

        if (tmax > mw + 10.f) {
            float rm[4];
#pragma unroll
            for (int r = 0; r < 4; ++r)
                rm[r] = fmaxf(fmaxf(S[0][r], S[1][r]), fmaxf(S[2][r], S[3][r]));
#pragma unroll
            for (int off = 1; off <= 8; off <<= 1)
#pragma unroll
                for (int r = 0; r < 4; ++r)
                    rm[r] = fmaxf(rm[r], __shfl_xor(rm[r], off, 64));
#pragma unroll
            for (int r = 0; r < 4; ++r) {
                float mn = fmaxf(m_r[r], rm[r]);
                float corr = __expf(m_r[r] - mn);
                m_r[r] = mn;
                l_l[r] *= corr;
#pragma unroll
                for (int ct = 0; ct < CTCW; ++ct) { Mac[ct][r] *= corr; Sac[ct][r] *= corr; }
            }
            float t = fminf(fminf(m_r[0], m_r[1]), fminf(m_r[2], m_r[3]));
            t = fminf(t, __shfl_xor(t, 16, 64));
            t = fminf(t, __shfl_xor(t, 32, 64));
            mw = t;
        }

#pragma unroll
        for (int ct = 0; ct < 4; ++ct)
#pragma unroll
            for (int r = 0; r < 4; ++r) {
                float p = __expf(S[ct][r] - m_r[r]);   // p <= e^10, f16-safe
                l_l[r] += p;
                Pw[(quad * 4 + r) * 72 + ct * 16 + l15] = f16_bits(p);
            }

        half8 pf0 = ldh(Pw + l15 * 72 + 0  + quad * 8);
        half8 pf1 = ldh(Pw + l15 * 72 + 32 + quad * 8);

        // ---- PV / PV^2 ----
#pragma unroll
        for (int g = 0; g < VCW; g += G) {
            __syncthreads();
#pragma unroll
            for (int s = 0; s < 4; ++s) {
                const int h = s / G, j = s % G;
                stage64_async(Vth, (long)b * C + (h * VCW + g + j) * 64, N, kt * 64,
                              smem + s * 4096, tid);
            }
            __syncthreads();
#pragma unroll
            for (int ks = 0; ks < 2; ++ks) {
                half8 pf = ks ? pf1 : pf0;
#pragma unroll
                for (int j = 0; j < G; ++j)
#pragma unroll
                    for (int ct = 0; ct < 4; ++ct) {
                        half8 vh = ldsw(smem + (ch2 * G + j) * 4096,
                                        ct * 16 + l15, ks * 32 + quad * 8);
                        half8 uh = vh * vh;
                        const int ci = (g + j) * 4 + ct;
                        Mac[ci] = MFMAH(pf, vh, Mac[ci]);
                        Sac[ci] = MFMAH(pf, uh, Sac[ci]);
                    }
            }
        }
    }

    // ---- reduce per-lane l, dump partial state ----
#pragma unroll
    for (int off = 1; off <= 8; off <<= 1)
#pragma unroll
        for (int r = 0; r < 4; ++r) l_l[r] += __shfl_xor(l_l[r], off, 64);

    if (ch2 == 0 && l15 == 0) {
#pragma unroll
        for (int r = 0; r < 4; ++r) {
            Pmo[po * 16 + quad * 4 + r] = m_r[r];
            Plo[po * 16 + quad * 4 + r] = l_l[r];
        }
    }
    const int chb = ch2 * (C / CSPLIT);
#pragma unroll
    for (int ct = 0; ct < CTCW; ++ct)
#pragma unroll
        for (int r = 0; r < 4; ++r) {
            long idx = (po * 16 + quad * 4 + r) * C + chb + ct * 16 + l15;
            PMo[idx] = Mac[ct][r];
            PSo[idx] = Sac[ct][r];
        }
}

// ---------------------------------------------------------------------------
// Combine: merge SPLIT flash partials per 16-row stripe, fused epilogue + MSE.
// ---------------------------------------------------------------------------
template<int C, int SPLIT>
__global__ void __launch_bounds__(256) combine_aat(
    const float* __restrict__ Pm, const float* __restrict__ Pl,
    const float* __restrict__ PM, const float* __restrict__ PS,
    const float* __restrict__ CT, const float* __restrict__ CS,
    const float* __restrict__ cmean, const float* __restrict__ crstd,
    float* __restrict__ loss, int N)
{
    __shared__ float wS[SPLIT][16];
    __shared__ float invL[16];
    __shared__ float red[4];
    const int pi = blockIdx.x;
    const int nb = N / 16;
    const int b  = pi / nb;
    const long g0 = (long)b * N + (long)(pi % nb) * 16;
    const int tid = threadIdx.x;

    if (tid < 16) {
        float m = -1e30f;
#pragma unroll
        for (int s = 0; s < SPLIT; ++s)
            m = fmaxf(m, Pm[((long)pi * SPLIT + s) * 16 + tid]);
        float L = 0.f;
#pragma unroll
        for (int s = 0; s < SPLIT; ++s) {
            float e = __expf(Pm[((long)pi * SPLIT + s) * 16 + tid] - m);
            wS[s][tid] = e;
            L = fmaf(e, Pl[((long)pi * SPLIT + s) * 16 + tid], L);
        }
        invL[tid] = 1.f / L;
    }
    __syncthreads();

    float acc = 0.f;
    for (int e = tid; e < 16 * C; e += 256) {
        const int r  = e / C;
        const int ch = e % C;
        float Ms = 0.f, Ss = 0.f;
#pragma unroll
        for (int s = 0; s < SPLIT; ++s) {
            const long q = (((long)pi * SPLIT + s) * 16 + r) * C + ch;
            Ms = fmaf(wS[s][r], PM[q], Ms);
            Ss = fmaf(wS[s][r], PS[q], Ss);
        }
        const float M  = Ms * invL[r];
        const float S2 = Ss * invL[r] - M * M;
        const float S  = sqrtf(fmaxf(S2, EPS_VAR));
        const float nc = (CT[(g0 + r) * C + ch] - cmean[b * C + ch]) * crstd[b * C + ch];
        const float d  = CS[(g0 + r) * C + ch] - (S * nc + M);
        acc = fmaf(d, d, acc);
    }
#pragma unroll
    for (int off = 1; off <= 32; off <<= 1) acc += __shfl_xor(acc, off, 64);
    if ((tid & 63) == 0) red[tid >> 6] = acc;
    __syncthreads();
    if (tid == 0) atomicAdd(loss, red[0] + red[1] + red[2] + red[3]);
}

// ---------------------------------------------------------------------------
// Fallback scalar flash kernel (only if ws_size too small)
// ---------------------------------------------------------------------------
template<int CCL, int CL, int NQ>
__global__ void __launch_bounds__(256) flash_aat(
    const float* __restrict__ Q, const float* __restrict__ K, const float* __restrict__ V,
    const float* __restrict__ CT, const float* __restrict__ CS,
    const float* __restrict__ qmean, const float* __restrict__ qrstd,
    const float* __restrict__ kmean, const float* __restrict__ krstd,
    const float* __restrict__ cmean, const float* __restrict__ crstd,
    float* __restrict__ loss, int N)
{
    constexpr int CC   = CCL * 64;
    constexpr int C    = CL * 64;
    constexpr int ROWS = 4 * NQ;
    const int lane = threadIdx.x & 63;
    const int wave = threadIdx.x >> 6;
    const int rowBlocks = N / ROWS;
    const int b  = blockIdx.x / rowBlocks;
    const int rb = blockIdx.x % rowBlocks;
    const int i0 = rb * ROWS + wave * NQ;

    float kmu[CCL], krs[CCL];
#pragma unroll
    for (int t = 0; t < CCL; ++t) {
        int ch = lane + 64 * t;
        kmu[t] = kmean[b * CC + ch];
        krs[t] = krstd[b * CC + ch];
    }
    float q[NQ][CCL];
#pragma unroll
    for (int qi = 0; qi < NQ; ++qi) {
        long base = (long)(b * N + i0 + qi) * CC;
#pragma unroll
        for (int t = 0; t < CCL; ++t) {
            int ch = lane + 64 * t;
            q[qi][t] = (Q[base + ch] - qmean[b * CC + ch]) * qrstd[b * CC + ch];
        }
    }
    float mval[NQ], lsum[NQ];
    float Macc[NQ][CL], Sacc[NQ][CL];
#pragma unroll
    for (int qi = 0; qi < NQ; ++qi) {
        mval[qi] = -1e30f; lsum[qi] = 0.f;
#pragma unroll
        for (int t = 0; t < CL; ++t) { Macc[qi][t] = 0.f; Sacc[qi][t] = 0.f; }
    }
    for (int j = 0; j < N; ++j) {
        long kb = (long)(b * N + j) * CC;
        float dot[NQ];
#pragma unroll
        for (int qi = 0; qi < NQ; ++qi) dot[qi] = 0.f;
#pragma unroll
        for (int t = 0; t < CCL; ++t) {
            float kv = (K[kb + lane + 64 * t] - kmu[t]) * krs[t];
#pragma unroll
            for (int qi = 0; qi < NQ; ++qi) dot[qi] = fmaf(q[qi][t], kv, dot[qi]);
        }
#pragma unroll
        for (int off = 32; off > 0; off >>= 1)
#pragma unroll
            for (int qi = 0; qi < NQ; ++qi) dot[qi] += __shfl_xor(dot[qi], off, 64);
        long vb = (long)(b * N + j) * C;
        float vv[CL];
#pragma unroll
        for (int t = 0; t < CL; ++t) vv[t] = V[vb + lane + 64 * t];
#pragma unroll
        for (int qi = 0; qi < NQ; ++qi) {
            float s = dot[qi];
            float p;
            if (s > mval[qi]) {
                float cr2 = __expf(mval[qi] - s);
                lsum[qi] *= cr2;
#pragma unroll
                for (int t = 0; t < CL; ++t) { Macc[qi][t] *= cr2; Sacc[qi][t] *= cr2; }
                mval[qi] = s; p = 1.f;
            } else p = __expf(s - mval[qi]);
            lsum[qi] += p;
#pragma unroll
            for (int t = 0; t < CL; ++t) {
                float pv = p * vv[t];
                Macc[qi][t] += pv;
                Sacc[qi][t] = fmaf(pv, vv[t], Sacc[qi][t]);
            }
        }
    }
    float acc = 0.f;
#pragma unroll
    for (int qi = 0; qi < NQ; ++qi) {
        float inv_l = 1.f / lsum[qi];
        long base = (long)(b * N + i0 + qi) * C;
#pragma unroll
        for (int t = 0; t < CL; ++t) {
            int ch = lane + 64 * t;
            float M  = Macc[qi][t] * inv_l;
            float S2 = Sacc[qi][t] * inv_l - M * M;
            float S  = sqrtf(fmaxf(S2, EPS_VAR));
            float nc = (CT[base + ch] - cmean[b * C + ch]) * crstd[b * C + ch];
            float d  = CS[base + ch] - (S * nc + M);
            acc = fmaf(d, d, acc);
        }
    }
#pragma unroll
    for (int off = 32; off > 0; off >>= 1) acc += __shfl_xor(acc, off, 64);
    if (lane == 0) atomicAdd(loss, acc);
}

__global__ void combine_loss(const float* __restrict__ lp, float* __restrict__ out,
                             float s0, float s1, float s2)
{
    out[0] = lp[0] * s0 + lp[1] * s1 + lp[2] * s2;
}

// ---------------------------------------------------------------------------
extern "C" void kernel_launch(void* const* d_in, const int* in_sizes, int n_in,
                              void* d_out, int out_size, void* d_ws, size_t ws_size,
                              hipStream_t stream)
{
    const float* cs2 = (const float*)d_in[0];
    const float* c2  = (const float*)d_in[1];
    const float* s2v = (const float*)d_in[2];
    const float* cc2 = (const float*)d_in[3];
    const float* sc2 = (const float*)d_in[4];
    const float* cs3 = (const float*)d_in[5];
    const float* c3  = (const float*)d_in[6];
    const float* s3v = (const float*)d_in[7];
    const float* cc3 = (const float*)d_in[8];
    const float* sc3 = (const float*)d_in[9];
    const float* cs4 = (const float*)d_in[10];
    const float* c4  = (const float*)d_in[11];
    const float* s4v = (const float*)d_in[12];
    const float* cc4 = (const float*)d_in[13];
    const float* sc4 = (const float*)d_in[14];

    const int B = 4;
    float* ws = (float*)d_ws;
    size_t fo = 0;
    auto allocF = [&](size_t n) { float* p = ws + fo; fo += n; return p; };

    float* lossp = allocF(4);
    float* c2m = allocF(B * 256);  float* c2r = allocF(B * 256);
    float* q2m = allocF(B * 448);  float* q2r = allocF(B * 448);
    float* k2m = allocF(B * 448);  float* k2r = allocF(B * 448);
    float* c3m = allocF(B * 512);  float* c3r = allocF(B * 512);
    float* q3m = allocF(B * 960);  float* q3r = allocF(B * 960);
    float* k3m = allocF(B * 960);  float* k3r = allocF(B * 960);
    float* c4m = allocF(B * 512);  float* c4r = allocF(B * 512);
    float* q4m = allocF(B * 1472); float* q4r = allocF(B * 1472);
    float* k4m = allocF(B * 1472); float* k4r = allocF(B * 1472);
    size_t zeroBytes = fo * sizeof(float);

    // partial-state buffers (shared across scales; stream-ordered reuse)
    float* Pm = allocF(32768);
    float* Pl = allocF(32768);
    float* PM = allocF(8388608);
    float* PS = allocF(8388608);

    // fp16 arena (16B aligned), reused per scale
    size_t arenaOff = ((fo * 4 + 15) & ~(size_t)15) / 2;
    ushort_t* arena = (ushort_t*)d_ws + arenaOff;
    const size_t arenaShorts = 18874400;   // max per-scale need (scale 2)
    size_t need = arenaOff * 2 + arenaShorts * 2;
    const bool fast = (ws_size >= need);

    hipMemsetAsync(d_ws, 0, zeroBytes, stream);

    auto stats = [&](const float* x, float* sm, float* sq, int N, int Cn) {
        int chG  = (Cn + 255) / 256;
        int nPer = 256;
        int nG   = (N + nPer - 1) / nPer;
        hipLaunchKernelGGL(stat_partial, dim3(B * chG * nG), dim3(256), 0, stream,
                           x, sm, sq, N, Cn, chG, nG, nPer);
        int total = B * Cn;
        hipLaunchKernelGGL(stat_finalize, dim3((total + 255) / 256), dim3(256), 0, stream,
                           sm, sq, total, 1.0f / (float)N);
    };

    stats(c2,  c2m, c2r, 4096, 256);
    stats(cc2, q2m, q2r, 4096, 448);
    stats(sc2, k2m, k2r, 4096, 448);
    stats(c3,  c3m, c3r, 1024, 512);
    stats(cc3, q3m, q3r, 1024, 960);
    stats(sc3, k3m, k3r, 1024, 960);
    stats(c4,  c4m, c4r, 256, 512);
    stats(cc4, q4m, q4r, 256, 1472);
    stats(sc4, k4m, k4r, 256, 1472);

    if (fast) {
        // ---- scale 2: N=4096, Cc=448, C=256 — pipelined flash (counted vmcnt) ----
        {
            size_t o = 0;
            auto aU = [&](size_t n) { ushort_t* p = arena + o; o += (n + 7) & ~(size_t)7; return p; };
            ushort_t *qh = aU((size_t)B*4096*448), *kh = aU((size_t)B*4096*448);
            ushort_t *vh = aU((size_t)B*4096*256);
            hipLaunchKernelGGL(norm_f16, dim3(B*4096), dim3(256), 0, stream, cc2, q2m, q2r, qh, 4096, 448);
            hipLaunchKernelGGL(norm_f16, dim3(B*4096), dim3(256), 0, stream, sc2, k2m, k2r, kh, 4096, 448);
            hipLaunchKernelGGL((vsplit_t<512>), dim3(B*(256/64)*(4096/512)), dim3(256), 0, stream,
                               s2v, vh, 4096, 256);
            hipLaunchKernelGGL(flash_pipe, dim3(B*(4096/64)*2), dim3(256), 0, stream,
                               qh, kh, vh, Pm, Pl, PM, PS);
            hipLaunchKernelGGL((combine_aat<256, 2>), dim3(B*4096/16), dim3(256), 0, stream,
                               Pm, Pl, PM, PS, c2, cs2, c2m, c2r, &lossp[0], 4096);
        }
        // ---- scale 3: N=1024, Cc=960, C=512, CSPLIT=2, SPLIT=4, KGRP=4 ----
        {
            size_t o = 0;
            auto aU = [&](size_t n) { ushort_t* p = arena + o; o += (n + 7) & ~(size_t)7; return p; };
            ushort_t *qh = aU((size_t)B*1024*960), *kh = aU((size_t)B*1024*960);
            ushort_t *vh = aU((size_t)B*1024*512);
            hipLaunchKernelGGL(norm_f16, dim3(B*1024), dim3(256), 0, stream, cc3, q3m, q3r, qh, 1024, 960);
            hipLaunchKernelGGL(norm_f16, dim3(B*1024), dim3(256), 0, stream, sc3, k3m, k3r, kh, 1024, 960);
            hipLaunchKernelGGL((vsplit_t<512>), dim3(B*(512/64)*(1024/512)), dim3(256), 0, stream,
                               s3v, vh, 1024, 512);
            hipLaunchKernelGGL((flash_mfma<960, 512, 1024, 2, false, 4, 4, 4>),
                               dim3(B*(1024/32)*4), dim3(256), 0, stream,
                               qh, kh, vh, Pm, Pl, PM, PS);
            hipLaunchKernelGGL((combine_aat<512, 4>), dim3(B*1024/16), dim3(256), 0, stream,
                               Pm, Pl, PM, PS, c3, cs3, c3m, c3r, &lossp[1], 1024);
        }
        // ---- scale 4: N=256, Cc=1472, C=512, CSPLIT=4, SPLIT=4, KGRP=4 ----
        {
            size_t o = 0;
            auto aU = [&](size_t n) { ushort_t* p = arena + o; o += (n + 7) & ~(size_t)7; return p; };
            ushort_t *qh = aU((size_t)B*256*1472), *kh = aU((size_t)B*256*1472);
            ushort_t *vh = aU((size_t)B*256*512);
            hipLaunchKernelGGL(norm_f16, dim3(B*256), dim3(256), 0, stream, cc4, q4m, q4r, qh, 256, 1472);
            hipLaunchKernelGGL(norm_f16, dim3(B*256), dim3(256), 0, stream, sc4, k4m, k4r, kh, 256, 1472);
            hipLaunchKernelGGL((vsplit_t<256>), dim3(B*(512/64)*(256/256)), dim3(256), 0, stream,
                               s4v, vh, 256, 512);
            hipLaunchKernelGGL((flash_mfma<1472, 512, 256, 4, false, 4, 4, 4>),
                               dim3(B*(256/16)*4), dim3(256), 0, stream,
                               qh, kh, vh, Pm, Pl, PM, PS);
            hipLaunchKernelGGL((combine_aat<512, 4>), dim3(B*256/16), dim3(256), 0, stream,
                               Pm, Pl, PM, PS, c4, cs4, c4m, c4r, &lossp[2], 256);
        }
    } else {
        hipLaunchKernelGGL((flash_aat<7, 4, 4>), dim3(B * 4096 / 16), dim3(256), 0, stream,
                           cc2, sc2, s2v, c2, cs2, q2m, q2r, k2m, k2r, c2m, c2r, &lossp[0], 4096);
        hipLaunchKernelGGL((flash_aat<15, 8, 2>), dim3(B * 1024 / 8), dim3(256), 0, stream,
                           cc3, sc3, s3v, c3, cs3, q3m, q3r, k3m, k3r, c3m, c3r, &lossp[1], 1024);
        hipLaunchKernelGGL((flash_aat<23, 8, 2>), dim3(B * 256 / 8), dim3(256), 0, stream,
                           cc4, sc4, s4v, c4, cs4, q4m, q4r, k4m, k4r, c4m, c4r, &lossp[2], 256);
    }

    hipLaunchKernelGGL(combine_loss, dim3(1), dim3(1), 0, stream,
                       lossp, (float*)d_out,
                       1.0f / (4.0f * 4096.0f * 256.0f),
                       1.0f / (4.0f * 1024.0f * 512.0f),
                       1.0f / (4.0f * 256.0f * 512.0f));
}

// Round 2
// 751.135 us; speedup vs baseline: 2.1533x; 2.0986x over previous
//
#include <hip/hip_runtime.h>
#include <math.h>

#define EPS_NORM 1e-5f
#define EPS_VAR  1e-9f
#define LOG2E    1.4426950408889634f

typedef unsigned short ushort_t;
typedef __attribute__((ext_vector_type(4))) float f32x4;
typedef _Float16 half8 __attribute__((ext_vector_type(8)));

#define MFMAH(a, b, c) __builtin_amdgcn_mfma_f32_16x16x32_f16((a), (b), (c), 0, 0, 0)

// async global->LDS DMA, 16B per lane; LDS dest = wave-uniform base + lane*16
#define GLD16(gp, lp) __builtin_amdgcn_global_load_lds(                          \
    (const __attribute__((address_space(1))) unsigned int*)(gp),                 \
    (__attribute__((address_space(3))) unsigned int*)(lp), 16, 0, 0)

// ---------------------------------------------------------------------------
// fp16 helpers
// ---------------------------------------------------------------------------
__device__ inline ushort_t f16_bits(float x) {
    _Float16 h = (_Float16)x;
    ushort_t u;
    __builtin_memcpy(&u, &h, 2);
    return u;
}
__device__ inline half8 ldh(const ushort_t* p) {   // 16B-aligned load
    half8 h;
    __builtin_memcpy(&h, p, 16);
    return h;
}
__device__ inline uint4 pack8(const ushort_t* s) {
    uint4 r;
    r.x = (unsigned)s[0] | ((unsigned)s[1] << 16);
    r.y = (unsigned)s[2] | ((unsigned)s[3] << 16);
    r.z = (unsigned)s[4] | ((unsigned)s[5] << 16);
    r.w = (unsigned)s[6] | ((unsigned)s[7] << 16);
    return r;
}

// ---------------------------------------------------------------------------
// Fused stage-1 stats: all 9 tensors in one launch (job table)
// ---------------------------------------------------------------------------
struct StatJobs {
    const float* x[9];
    float* sm[9];
    float* sq[9];
    int N[9], Cn[9], chG[9], nG[9], base[9];
};
__global__ void __launch_bounds__(256) stat_partial_all(StatJobs J)
{
    int bx = blockIdx.x;
    int j = 0;
#pragma unroll
    for (int k = 1; k < 9; ++k) if (bx >= J.base[k]) j = k;
    bx -= J.base[j];
    const int N = J.N[j], Cn = J.Cn[j], chG = J.chG[j], nG = J.nG[j];
    int b  = bx / (chG * nG);
    int r  = bx % (chG * nG);
    int cg = r / nG;
    int ng = r % nG;
    int ch = cg * 256 + threadIdx.x;
    if (ch >= Cn) return;
    int n0 = ng * 256;
    int n1 = min(n0 + 256, N);
    const float* p = J.x[j] + (long)(b * N) * Cn + ch;
    float s = 0.f, ss = 0.f;
    for (int n = n0; n < n1; ++n) {
        float v = p[(long)n * Cn];
        s += v;
        ss = fmaf(v, v, ss);
    }
    atomicAdd(&J.sm[j][b * Cn + ch], s);
    atomicAdd(&J.sq[j][b * Cn + ch], ss);
}

struct FinJobs {
    float* sm[9];
    float* sq[9];
    int base[9];
    float invN[9];
    int total;
};
__global__ void __launch_bounds__(256) stat_finalize_all(FinJobs J)
{
    int i = blockIdx.x * 256 + threadIdx.x;
    if (i >= J.total) return;
    int j = 0;
#pragma unroll
    for (int k = 1; k < 9; ++k) if (i >= J.base[k]) j = k;
    int e = i - J.base[j];
    float m = J.sm[j][e] * J.invN[j];
    float v = J.sq[j][e] * J.invN[j] - m * m;
    J.sm[j][e] = m;
    J.sq[j][e] = rsqrtf(v + EPS_NORM);
}

// ---------------------------------------------------------------------------
// Fused per-scale prep: norm(Q)*log2e -> f16, norm(K) -> f16, V -> (B,C,N) f16
// Q is pre-scaled by log2(e) so flash softmax can use exp2 (1 instr).
// ---------------------------------------------------------------------------
__global__ void __launch_bounds__(256) prep_scale(
    const float* __restrict__ qx, const float* __restrict__ qm, const float* __restrict__ qr,
    ushort_t* __restrict__ qh,
    const float* __restrict__ kx, const float* __restrict__ km, const float* __restrict__ kr,
    ushort_t* __restrict__ kh,
    const float* __restrict__ vx, ushort_t* __restrict__ vt,
    int N, int Cc, int C, int KSEG)
{
    const int R = 4 * N;          // B*N rows per norm job
    int bid = blockIdx.x;
    if (bid < 2 * R) {
        const bool isQ = bid < R;
        int bn = isQ ? bid : bid - R;
        const float* x    = isQ ? qx : kx;
        const float* mean = isQ ? qm : km;
        const float* rstd = isQ ? qr : kr;
        ushort_t* out     = isQ ? qh : kh;
        const float scl   = isQ ? LOG2E : 1.0f;
        int b = bn / N;
        long base = (long)bn * Cc;
        for (int ch = threadIdx.x; ch < Cc; ch += 256) {
            float v = (x[base + ch] - mean[b * Cc + ch]) * rstd[b * Cc + ch] * scl;
            out[base + ch] = f16_bits(v);
        }
    } else {
        int bid2 = bid - 2 * R;
        int cPB = C / 64, nSeg = N / KSEG;
        int b   = bid2 / (cPB * nSeg);
        int rem = bid2 % (cPB * nSeg);
        int cb  = rem / nSeg;
        int ns  = rem % nSeg;
        int ch  = cb * 64 + (threadIdx.x & 63);
        const int KL = KSEG / 4;
        int k0  = ns * KSEG + (threadIdx.x >> 6) * KL;
        long obase = ((long)b * C + ch) * N;
        for (int k = k0; k < k0 + KL; k += 8) {
            ushort_t h8[8];
#pragma unroll
            for (int i = 0; i < 8; ++i)
                h8[i] = f16_bits(vx[((long)b * N + k + i) * C + ch]);
            *(uint4*)(vt + obase + k) = pack8(h8);
        }
    }
}

// ---------------------------------------------------------------------------
// Async DMA tile stagers (generic versions; used by flash_mfma).
// LDS tiles are 64 shorts/row, XOR-swizzled:
// LDS[r][g] (16B granule g of row r) holds global[r][g ^ (r&7)].
// ---------------------------------------------------------------------------
__device__ inline void stage64_async(const ushort_t* __restrict__ g, long rowBase,
                                     int gstride, int col0, ushort_t* slab, int tid)
{
    const int l  = tid & 63, w = tid >> 6;
    const int rs = l >> 3;
    const int cg = (l & 7) ^ rs;
#pragma unroll
    for (int i = 0; i < 2; ++i) {
        const int r = w * 16 + i * 8 + rs;
        const ushort_t* gp = g + (rowBase + r) * (long)gstride + col0 + (cg << 3);
        ushort_t* lp = slab + (w * 16 + i * 8) * 64 + l * 8;
        GLD16(gp, lp);
    }
}
template<int BROWS>
__device__ inline void stageQ_async(const ushort_t* __restrict__ g, long rowBase,
                                    int gstride, int col0, ushort_t* slab, int tid)
{
    if (tid < BROWS * 8) {
        const int l  = tid & 63, w = tid >> 6;
        const int rs = l >> 3;
        const int cg = (l & 7) ^ rs;
        const int r  = w * 8 + rs;
        const ushort_t* gp = g + (rowBase + r) * (long)gstride + col0 + (cg << 3);
        ushort_t* lp = slab + w * 8 * 64 + l * 8;
        GLD16(gp, lp);
    }
}
__device__ inline half8 ldsw(const ushort_t* slab, int row, int soff)
{
    const int gr = (soff >> 3) ^ (row & 7);
    return ldh(slab + row * 64 + (gr << 3));
}

// ---------------------------------------------------------------------------
// Pipelined flash for scale 2 (N=4096, Cc=448, C=256, QREG, SPLIT=2).
// 3 phases/tile, 2x4-slab LDS ping-pong, counted vmcnt, hoisted addressing,
// exp2-domain softmax (Q pre-scaled by log2e in prep).
// ---------------------------------------------------------------------------
__global__ void __launch_bounds__(256, 2) flash_pipe(
    const ushort_t* __restrict__ Qh, const ushort_t* __restrict__ Kh,
    const ushort_t* __restrict__ Vth,
    float* __restrict__ Pmo, float* __restrict__ Plo,
    float* __restrict__ PMo, float* __restrict__ PSo)
{
    constexpr int Cc = 448, C = 256, N = 4096, SPLIT = 2;
    constexpr int NKT  = (N / 64) / SPLIT;     // 32 key tiles per block
    constexpr long VCHO = 64L * N;             // shorts per V chunk block
    constexpr long KADV = 64L * Cc;            // shorts per K tile advance

    __shared__ __align__(16) ushort_t smem[2 * 16384 + 4 * 1152];
    const int tid  = threadIdx.x;
    const int lane = tid & 63;
    const int w    = tid >> 6;
    const int l15  = lane & 15;
    const int quad = lane >> 4;

    const int bq = blockIdx.x / SPLIT;
    const int sp = blockIdx.x % SPLIT;
    const int b  = bq / (N / 64);
    const int qb = bq % (N / 64);
    const int i0 = qb * 64 + w * 16;
    const long po = (long)(b * (N / 16) + qb * 4 + w) * SPLIT + sp;

    // ---- hoisted per-lane constants ----
    const int rs    = lane >> 3;
    const int cg    = (lane & 7) ^ rs;
    const int ldso0 = w * 1024 + lane * 8;     // LDS dest, row block i=0
    const int ldso1 = ldso0 + 512;
    const int xh    = l15 & 7;
    const int lb0   = l15 * 64 + ((quad)     ^ xh) * 8;   // swizzled read base ks=0
    const int lb1   = l15 * 64 + ((4 + quad) ^ xh) * 8;   // ks=1
    ushort_t* const Pw  = smem + 32768 + w * 1152;
    ushort_t* const pww = Pw + quad * 288 + l15;          // P write base
    const ushort_t* const pfr = Pw + l15 * 72 + quad * 8; // P read base

    // staging base pointers (advance incrementally per tile)
    const long krow0 = (long)b * N + (long)sp * NKT * 64;
    const ushort_t* kp0 = Kh + (krow0 + w * 16 + rs) * (long)Cc + (cg << 3);
    const ushort_t* kp1 = kp0 + 8 * Cc;
    const ushort_t* vp0 = Vth + ((long)b * C + w * 16 + rs) * (long)N
                              + (cg << 3) + (long)sp * NKT * 64;
    const ushort_t* vp1 = vp0 + 8 * (long)N;

#define STGK(c, dst) do { GLD16(kp0 + (c) * 64, (dst) + ldso0);                  \
                          GLD16(kp1 + (c) * 64, (dst) + ldso1); } while (0)
#define STGV(c, dst) do { GLD16(vp0 + (c) * VCHO, (dst) + ldso0);                \
                          GLD16(vp1 + (c) * VCHO, (dst) + ldso1); } while (0)

    half8 qf[14];
    {
        const ushort_t* q1 = Qh + ((long)(b * N + i0 + l15)) * Cc + quad * 8;
#pragma unroll
        for (int ks = 0; ks < 14; ++ks) qf[ks] = ldh(q1 + ks * 32);
    }

    float m_r[4], l_l[4], mw = -1e30f;
    f32x4 Mac[16], Sac[16];
#pragma unroll
    for (int r = 0; r < 4; ++r) { m_r[r] = -1e30f; l_l[r] = 0.f; }
#pragma unroll
    for (int ct = 0; ct < 16; ++ct)
#pragma unroll
        for (int r = 0; r < 4; ++r) { Mac[ct][r] = 0.f; Sac[ct][r] = 0.f; }

    // prologue: K chunks 0..3 of tile 0 -> buffer 0  (8 DMA insts/wave)
    STGK(0, smem + 0);
    STGK(1, smem + 4096);
    STGK(2, smem + 8192);
    STGK(3, smem + 12288);
    int cur = 0;

    for (int t = 0; t < NKT; ++t) {
        f32x4 S[4];
#pragma unroll
        for (int ct = 0; ct < 4; ++ct)
#pragma unroll
            for (int r = 0; r < 4; ++r) S[ct][r] = 0.f;

        ushort_t* bufc = smem + cur * 16384;
        ushort_t* bufo = smem + (cur ^ 1) * 16384;

        // ---------------- phase A: compute K0-3, prefetch K4-6 ----------------
        __builtin_amdgcn_s_barrier();
        STGK(4, bufo + 0);
        STGK(5, bufo + 4096);
        STGK(6, bufo + 8192);
        asm volatile("s_waitcnt vmcnt(6)" ::: "memory");
        __builtin_amdgcn_sched_barrier(0);
        __builtin_amdgcn_s_barrier();
        __builtin_amdgcn_s_setprio(1);
#pragma unroll
        for (int j = 0; j < 4; ++j) {
            const ushort_t* sl = bufc + j * 4096;
#pragma unroll
            for (int ct = 0; ct < 4; ++ct) S[ct] = MFMAH(qf[j * 2 + 0], ldh(sl + ct * 1024 + lb0), S[ct]);
#pragma unroll
            for (int ct = 0; ct < 4; ++ct) S[ct] = MFMAH(qf[j * 2 + 1], ldh(sl + ct * 1024 + lb1), S[ct]);
        }
        __builtin_amdgcn_s_setprio(0);
        cur ^= 1; bufc = smem + cur * 16384; bufo = smem + (cur ^ 1) * 16384;

        // ---------------- phase B: compute K4-6 + softmax, prefetch V ----------------
        __builtin_amdgcn_s_barrier();
        STGV(0, bufo + 0);
        STGV(1, bufo + 4096);
        STGV(2, bufo + 8192);
        STGV(3, bufo + 12288);
        asm volatile("s_waitcnt vmcnt(8)" ::: "memory");
        __builtin_amdgcn_sched_barrier(0);
        __builtin_amdgcn_s_barrier();
        __builtin_amdgcn_s_setprio(1);
#pragma unroll
        for (int j = 0; j < 3; ++j) {
            const ushort_t* sl = bufc + j * 4096;
#pragma unroll
            for (int ct = 0; ct < 4; ++ct) S[ct] = MFMAH(qf[(4 + j) * 2 + 0], ldh(sl + ct * 1024 + lb0), S[ct]);
#pragma unroll
            for (int ct = 0; ct < 4; ++ct) S[ct] = MFMAH(qf[(4 + j) * 2 + 1], ldh(sl + ct * 1024 + lb1), S[ct]);
        }
        __builtin_amdgcn_s_setprio(0);

        // ---- online softmax, lazy base (log2 domain; p = 2^(S-m) <= 2^14.43) ----
        {
            float tmax = S[0][0];
#pragma unroll
            for (int ct = 0; ct < 4; ++ct)
#pragma unroll
                for (int r = 0; r < 4; ++r) tmax = fmaxf(tmax, S[ct][r]);
#pragma unroll
            for (int off = 1; off <= 32; off <<= 1)
                tmax = fmaxf(tmax, __shfl_xor(tmax, off, 64));

            if (tmax > mw + 14.4269504f) {
                float rm[4];
#pragma unroll
                for (int r = 0; r < 4; ++r)
                    rm[r] = fmaxf(fmaxf(S[0][r], S[1][r]), fmaxf(S[2][r], S[3][r]));
#pragma unroll
                for (int off = 1; off <= 8; off <<= 1)
#pragma unroll
                    for (int r = 0; r < 4; ++r)
                        rm[r] = fmaxf(rm[r], __shfl_xor(rm[r], off, 64));
#pragma unroll
                for (int r = 0; r < 4; ++r) {
                    float mn = fmaxf(m_r[r], rm[r]);
                    float corr = exp2f(m_r[r] - mn);
                    m_r[r] = mn;
                    l_l[r] *= corr;
#pragma unroll
                    for (int ct = 0; ct < 16; ++ct) { Mac[ct][r] *= corr; Sac[ct][r] *= corr; }
                }
                float tt = fminf(fminf(m_r[0], m_r[1]), fminf(m_r[2], m_r[3]));
                tt = fminf(tt, __shfl_xor(tt, 16, 64));
                tt = fminf(tt, __shfl_xor(tt, 32, 64));
                mw = tt;
            }

#pragma unroll
            for (int ct = 0; ct < 4; ++ct)
#pragma unroll
                for (int r = 0; r < 4; ++r) {
                    float p = exp2f(S[ct][r] - m_r[r]);
                    l_l[r] += p;
                    pww[r * 72 + ct * 16] = f16_bits(p);
                }
        }
        half8 pf0 = ldh(pfr);
        half8 pf1 = ldh(pfr + 32);
        cur ^= 1; bufc = smem + cur * 16384; bufo = smem + (cur ^ 1) * 16384;

        // ---------------- phase C: compute PV/PV^2, prefetch next K0-3 ----------------
        __builtin_amdgcn_s_barrier();
        if (t + 1 < NKT) {
            kp0 += KADV; kp1 += KADV;
            STGK(0, bufo + 0);
            STGK(1, bufo + 4096);
            STGK(2, bufo + 8192);
            STGK(3, bufo + 12288);
            asm volatile("s_waitcnt vmcnt(8)" ::: "memory");
        } else {
            asm volatile("s_waitcnt vmcnt(0)" ::: "memory");
        }
        __builtin_amdgcn_sched_barrier(0);
        __builtin_amdgcn_s_barrier();
        __builtin_amdgcn_s_setprio(1);
#define PVSLAB(J) do {                                                           \
        const ushort_t* sl = bufc + (J) * 4096;                                  \
        _Pragma("unroll")                                                        \
        for (int ct = 0; ct < 4; ++ct) {                                         \
            half8 vh = ldh(sl + ct * 1024 + lb0);                                \
            half8 uh = vh * vh;                                                  \
            Mac[(J) * 4 + ct] = MFMAH(pf0, vh, Mac[(J) * 4 + ct]);               \
            Sac[(J) * 4 + ct] = MFMAH(pf0, uh, Sac[(J) * 4 + ct]);               \
        }                                                                        \
        _Pragma("unroll")                                                        \
        for (int ct = 0; ct < 4; ++ct) {                                         \
            half8 vh = ldh(sl + ct * 1024 + lb1);                                \
            half8 uh = vh * vh;                                                  \
            Mac[(J) * 4 + ct] = MFMAH(pf1, vh, Mac[(J) * 4 + ct]);               \
            Sac[(J) * 4 + ct] = MFMAH(pf1, uh, Sac[(J) * 4 + ct]);               \
        } } while (0)
        PVSLAB(0); PVSLAB(1); PVSLAB(2); PVSLAB(3);
#undef PVSLAB
        __builtin_amdgcn_s_setprio(0);
        cur ^= 1;
        vp0 += 64; vp1 += 64;
    }
#undef STGK
#undef STGV

    // ---- reduce per-lane l, dump partial state ----
#pragma unroll
    for (int off = 1; off <= 8; off <<= 1)
#pragma unroll
        for (int r = 0; r < 4; ++r) l_l[r] += __shfl_xor(l_l[r], off, 64);

    if (l15 == 0) {
#pragma unroll
        for (int r = 0; r < 4; ++r) {
            Pmo[po * 16 + quad * 4 + r] = m_r[r];
            Plo[po * 16 + quad * 4 + r] = l_l[r];
        }
    }
#pragma unroll
    for (int ct = 0; ct < 16; ++ct)
#pragma unroll
        for (int r = 0; r < 4; ++r) {
            long idx = (po * 16 + quad * 4 + r) * C + ct * 16 + l15;
            PMo[idx] = Mac[ct][r];
            PSo[idx] = Sac[ct][r];
        }
}

// ---------------------------------------------------------------------------
// Generic flash (scales 3/4): __syncthreads structure, async DMA staging,
// swizzled unpadded LDS slabs.  Softmax in log2 domain (Q pre-scaled).
// ---------------------------------------------------------------------------
template<int Cc, int C, int N, int CSPLIT, bool QREG, int SPLIT, int SLABS, int KGRP>
__global__ void __launch_bounds__(256, 2) flash_mfma(
    const ushort_t* __restrict__ Qh, const ushort_t* __restrict__ Kh,
    const ushort_t* __restrict__ Vth,
    float* __restrict__ Pmo, float* __restrict__ Plo,
    float* __restrict__ PMo, float* __restrict__ PSo)
{
    constexpr int KC      = Cc / 64;
    constexpr int VC      = C / 64;
    constexpr int VCW     = VC / CSPLIT;
    constexpr int CTCW    = 4 * VCW;
    constexpr int STRIPES = 4 / CSPLIT;
    constexpr int BROWS   = 16 * STRIPES;
    constexpr int QB      = N / BROWS;
    constexpr int TILES   = N / 64;
    constexpr int NKT     = TILES / SPLIT;
    constexpr int NKS     = QREG ? (Cc / 32) : 1;
    constexpr int NGRP    = (KC + KGRP - 1) / KGRP;
    constexpr int G       = 4 / CSPLIT;
    constexpr int QCH     = BROWS * 64;
    constexpr int QOFF    = KGRP * 4096;
    constexpr int KQEND   = QOFF + KGRP * QCH;
    constexpr int REGION  = QREG ? (SLABS * 4096)
                                 : (KQEND > SLABS * 4096 ? KQEND : SLABS * 4096);

    __shared__ __align__(16) ushort_t smem[REGION + 4 * 1152];
    const int tid  = threadIdx.x;
    const int lane = tid & 63;
    const int w    = tid >> 6;
    const int l15  = lane & 15;
    const int quad = lane >> 4;

    const int bq = blockIdx.x / SPLIT;
    const int sp = blockIdx.x % SPLIT;
    const int b  = bq / QB;
    const int qb = bq % QB;
    const int ls  = w / CSPLIT;
    const int ch2 = w % CSPLIT;
    const int i0 = qb * BROWS + ls * 16;
    const long po = (long)(b * (N / 16) + qb * STRIPES + ls) * SPLIT + sp;
    ushort_t* Pw = smem + REGION + w * 1152;

    half8 qf[NKS];
    if constexpr (QREG) {
        const ushort_t* q1 = Qh + ((long)(b * N + i0 + l15)) * Cc + quad * 8;
#pragma unroll
        for (int ks = 0; ks < NKS; ++ks) qf[ks] = ldh(q1 + ks * 32);
    }

    float m_r[4], l_l[4], mw = -1e30f;
    f32x4 Mac[CTCW], Sac[CTCW];
#pragma unroll
    for (int r = 0; r < 4; ++r) { m_r[r] = -1e30f; l_l[r] = 0.f; }
#pragma unroll
    for (int ct = 0; ct < CTCW; ++ct)
#pragma unroll
        for (int r = 0; r < 4; ++r) { Mac[ct][r] = 0.f; Sac[ct][r] = 0.f; }

    for (int kt = sp * NKT; kt < sp * NKT + NKT; ++kt) {
        const long krow = (long)b * N + kt * 64;

        f32x4 S[4];
#pragma unroll
        for (int ct = 0; ct < 4; ++ct)
#pragma unroll
            for (int r = 0; r < 4; ++r) S[ct][r] = 0.f;

        // ---- QK ----
#pragma unroll
        for (int grp = 0; grp < NGRP; ++grp) {
            const int g0 = grp * KGRP;
            const int gn = (KC - g0 < KGRP) ? (KC - g0) : KGRP;
            __syncthreads();
#pragma unroll
            for (int j = 0; j < KGRP; ++j) if (j < gn) {
                stage64_async(Kh, krow, Cc, (g0 + j) * 64, smem + j * 4096, tid);
                if constexpr (!QREG)
                    stageQ_async<BROWS>(Qh, (long)b * N + qb * BROWS, Cc, (g0 + j) * 64,
                                        smem + QOFF + j * QCH, tid);
            }
            __syncthreads();
#pragma unroll
            for (int j = 0; j < KGRP; ++j) if (j < gn) {
#pragma unroll
                for (int ks = 0; ks < 2; ++ks) {
                    half8 a;
                    if constexpr (QREG) a = qf[(g0 + j) * 2 + ks];
                    else a = ldsw(smem + QOFF + j * QCH, ls * 16 + l15, ks * 32 + quad * 8);
#pragma unroll
                    for (int ct = 0; ct < 4; ++ct) {
                        half8 bf = ldsw(smem + j * 4096, ct * 16 + l15, ks * 32 + quad * 8);
                        S[ct] = MFMAH(a, bf, S[ct]);
                    }
                }
            }
        }

        // ---- online softmax, lazy base (log2 domain) ----
        float tmax = S[0][0];
#pragma unroll
        for (int ct = 0; ct < 4; ++ct)
#pragma unroll
            for (int r = 0; r < 4; ++r) tmax = fmaxf(tmax, S[ct][r]);
#pragma unroll
        for (int off = 1; off <= 32; off <<= 1)
            tmax = fmaxf(tmax, __shfl_xor(tmax, off, 64));

        if (tmax > mw + 14.4269504f) {
            float rm[4];
#pragma unroll
            for (int r = 0; r < 4; ++r)
                rm[r] = fmaxf(fmaxf(S[0][r], S[1][r]), fmaxf(S[2][r], S[3][r]));
#pragma unroll
            for (int off = 1; off <= 8; off <<= 1)
#pragma unroll
                for (int r = 0; r < 4; ++r)
                    rm[r] = fmaxf(rm[r], __shfl_xor(rm[r], off, 64));
#pragma unroll
            for (int r = 0; r < 4; ++r) {
                float mn = fmaxf(m_r[r], rm[r]);
                float corr = exp2f(m_r[r] - mn);
                m_r[r] = mn;
                l_l[r] *= corr;
#pragma unroll
                for (int ct = 0; ct < CTCW; ++ct) { Mac[ct][r] *= corr; Sac[ct][r] *= corr; }
            }
            float t = fminf(fminf(m_r[0], m_r[1]), fminf(m_r[2], m_r[3]));
            t = fminf(t, __shfl_xor(t, 16, 64));
            t = fminf(t, __shfl_xor(t, 32, 64));
            mw = t;
        }

#pragma unroll
        for (int ct = 0; ct < 4; ++ct)
#pragma unroll
            for (int r = 0; r < 4; ++r) {
                float p = exp2f(S[ct][r] - m_r[r]);
                l_l[r] += p;
                Pw[(quad * 4 + r) * 72 + ct * 16 + l15] = f16_bits(p);
            }

        half8 pf0 = ldh(Pw + l15 * 72 + 0  + quad * 8);
        half8 pf1 = ldh(Pw + l15 * 72 + 32 + quad * 8);

        // ---- PV / PV^2 ----
#pragma unroll
        for (int g = 0; g < VCW; g += G) {
            __syncthreads();
#pragma unroll
            for (int s = 0; s < 4; ++s) {
                const int h = s / G, j = s % G;
                stage64_async(Vth, (long)b * C + (h * VCW + g + j) * 64, N, kt * 64,
                              smem + s * 4096, tid);
            }
            __syncthreads();
#pragma unroll
            for (int ks = 0; ks < 2; ++ks) {
                half8 pf = ks ? pf1 : pf0;
#pragma unroll
                for (int j = 0; j < G; ++j)
#pragma unroll
                    for (int ct = 0; ct < 4; ++ct) {
                        half8 vh = ldsw(smem + (ch2 * G + j) * 4096,
                                        ct * 16 + l15, ks * 32 + quad * 8);
                        half8 uh = vh * vh;
                        const int ci = (g + j) * 4 + ct;
                        Mac[ci] = MFMAH(pf, vh, Mac[ci]);
                        Sac[ci] = MFMAH(pf, uh, Sac[ci]);
                    }
            }
        }
    }

    // ---- reduce per-lane l, dump partial state ----
#pragma unroll
    for (int off = 1; off <= 8; off <<= 1)
#pragma unroll
        for (int r = 0; r < 4; ++r) l_l[r] += __shfl_xor(l_l[r], off, 64);

    if (ch2 == 0 && l15 == 0) {
#pragma unroll
        for (int r = 0; r < 4; ++r) {
            Pmo[po * 16 + quad * 4 + r] = m_r[r];
            Plo[po * 16 + quad * 4 + r] = l_l[r];
        }
    }
    const int chb = ch2 * (C / CSPLIT);
#pragma unroll
    for (int ct = 0; ct < CTCW; ++ct)
#pragma unroll
        for (int r = 0; r < 4; ++r) {
            long idx = (po * 16 + quad * 4 + r) * C + chb + ct * 16 + l15;
            PMo[idx] = Mac[ct][r];
            PSo[idx] = Sac[ct][r];
        }
}

// ---------------------------------------------------------------------------
// Combine: merge SPLIT flash partials (log2-domain m), fused epilogue + MSE.
// ---------------------------------------------------------------------------
template<int C, int SPLIT>
__global__ void __launch_bounds__(256) combine_aat(
    const float* __restrict__ Pm, const float* __restrict__ Pl,
    const float* __restrict__ PM, const float* __restrict__ PS,
    const float* __restrict__ CT, const float* __restrict__ CS,
    const float* __restrict__ cmean, const float* __restrict__ crstd,
    float* __restrict__ loss, int N)
{
    __shared__ float wS[SPLIT][16];
    __shared__ float invL[16];
    __shared__ float red[4];
    const int pi = blockIdx.x;
    const int nb = N / 16;
    const int b  = pi / nb;
    const long g0 = (long)b * N + (long)(pi % nb) * 16;
    const int tid = threadIdx.x;

    if (tid < 16) {
        float m = -1e30f;
#pragma unroll
        for (int s = 0; s < SPLIT; ++s)
            m = fmaxf(m, Pm[((long)pi * SPLIT + s) * 16 + tid]);
        float L = 0.f;
#pragma unroll
        for (int s = 0; s < SPLIT; ++s) {
            float e = exp2f(Pm[((long)pi * SPLIT + s) * 16 + tid] - m);
            wS[s][tid] = e;
            L = fmaf(e, Pl[((long)pi * SPLIT + s) * 16 + tid], L);
        }
        invL[tid] = 1.f / L;
    }
    __syncthreads();

    float acc = 0.f;
    for (int e = tid; e < 16 * C; e += 256) {
        const int r  = e / C;
        const int ch = e % C;
        float Ms = 0.f, Ss = 0.f;
#pragma unroll
        for (int s = 0; s < SPLIT; ++s) {
            const long q = (((long)pi * SPLIT + s) * 16 + r) * C + ch;
            Ms = fmaf(wS[s][r], PM[q], Ms);
            Ss = fmaf(wS[s][r], PS[q], Ss);
        }
        const float M  = Ms * invL[r];
        const float S2 = Ss * invL[r] - M * M;
        const float S  = sqrtf(fmaxf(S2, EPS_VAR));
        const float nc = (CT[(g0 + r) * C + ch] - cmean[b * C + ch]) * crstd[b * C + ch];
        const float d  = CS[(g0 + r) * C + ch] - (S * nc + M);
        acc = fmaf(d, d, acc);
    }
#pragma unroll
    for (int off = 1; off <= 32; off <<= 1) acc += __shfl_xor(acc, off, 64);
    if ((tid & 63) == 0) red[tid >> 6] = acc;
    __syncthreads();
    if (tid == 0) atomicAdd(loss, red[0] + red[1] + red[2] + red[3]);
}

// ---------------------------------------------------------------------------
// Fallback scalar flash kernel (only if ws_size too small)
// ---------------------------------------------------------------------------
template<int CCL, int CL, int NQ>
__global__ void __launch_bounds__(256) flash_aat(
    const float* __restrict__ Q, const float* __restrict__ K, const float* __restrict__ V,
    const float* __restrict__ CT, const float* __restrict__ CS,
    const float* __restrict__ qmean, const float* __restrict__ qrstd,
    const float* __restrict__ kmean, const float* __restrict__ krstd,
    const float* __restrict__ cmean, const float* __restrict__ crstd,
    float* __restrict__ loss, int N)
{
    constexpr int CC   = CCL * 64;
    constexpr int C    = CL * 64;
    constexpr int ROWS = 4 * NQ;
    const int lane = threadIdx.x & 63;
    const int wave = threadIdx.x >> 6;
    const int rowBlocks = N / ROWS;
    const int b  = blockIdx.x / rowBlocks;
    const int rb = blockIdx.x % rowBlocks;
    const int i0 = rb * ROWS + wave * NQ;

    float kmu[CCL], krs[CCL];
#pragma unroll
    for (int t = 0; t < CCL; ++t) {
        int ch = lane + 64 * t;
        kmu[t] = kmean[b * CC + ch];
        krs[t] = krstd[b * CC + ch];
    }
    float q[NQ][CCL];
#pragma unroll
    for (int qi = 0; qi < NQ; ++qi) {
        long base = (long)(b * N + i0 + qi) * CC;
#pragma unroll
        for (int t = 0; t < CCL; ++t) {
            int ch = lane + 64 * t;
            q[qi][t] = (Q[base + ch] - qmean[b * CC + ch]) * qrstd[b * CC + ch];
        }
    }
    float mval[NQ], lsum[NQ];
    float Macc[NQ][CL], Sacc[NQ][CL];
#pragma unroll
    for (int qi = 0; qi < NQ; ++qi) {
        mval[qi] = -1e30f; lsum[qi] = 0.f;
#pragma unroll
        for (int t = 0; t < CL; ++t) { Macc[qi][t] = 0.f; Sacc[qi][t] = 0.f; }
    }
    for (int j = 0; j < N; ++j) {
        long kb = (long)(b * N + j) * CC;
        float dot[NQ];
#pragma unroll
        for (int qi = 0; qi < NQ; ++qi) dot[qi] = 0.f;
#pragma unroll
        for (int t = 0; t < CCL; ++t) {
            float kv = (K[kb + lane + 64 * t] - kmu[t]) * krs[t];
#pragma unroll
            for (int qi = 0; qi < NQ; ++qi) dot[qi] = fmaf(q[qi][t], kv, dot[qi]);
        }
#pragma unroll
        for (int off = 32; off > 0; off >>= 1)
#pragma unroll
            for (int qi = 0; qi < NQ; ++qi) dot[qi] += __shfl_xor(dot[qi], off, 64);
        long vb = (long)(b * N + j) * C;
        float vv[CL];
#pragma unroll
        for (int t = 0; t < CL; ++t) vv[t] = V[vb + lane + 64 * t];
#pragma unroll
        for (int qi = 0; qi < NQ; ++qi) {
            float s = dot[qi];
            float p;
            if (s > mval[qi]) {
                float cr2 = __expf(mval[qi] - s);
                lsum[qi] *= cr2;
#pragma unroll
                for (int t = 0; t < CL; ++t) { Macc[qi][t] *= cr2; Sacc[qi][t] *= cr2; }
                mval[qi] = s; p = 1.f;
            } else p = __expf(s - mval[qi]);
            lsum[qi] += p;
#pragma unroll
            for (int t = 0; t < CL; ++t) {
                float pv = p * vv[t];
                Macc[qi][t] += pv;
                Sacc[qi][t] = fmaf(pv, vv[t], Sacc[qi][t]);
            }
        }
    }
    float acc = 0.f;
#pragma unroll
    for (int qi = 0; qi < NQ; ++qi) {
        float inv_l = 1.f / lsum[qi];
        long base = (long)(b * N + i0 + qi) * C;
#pragma unroll
        for (int t = 0; t < CL; ++t) {
            int ch = lane + 64 * t;
            float M  = Macc[qi][t] * inv_l;
            float S2 = Sacc[qi][t] * inv_l - M * M;
            float S  = sqrtf(fmaxf(S2, EPS_VAR));
            float nc = (CT[base + ch] - cmean[b * C + ch]) * crstd[b * C + ch];
            float d  = CS[base + ch] - (S * nc + M);
            acc = fmaf(d, d, acc);
        }
    }
#pragma unroll
    for (int off = 32; off > 0; off >>= 1) acc += __shfl_xor(acc, off, 64);
    if (lane == 0) atomicAdd(loss, acc);
}

__global__ void combine_loss(const float* __restrict__ lp, float* __restrict__ out,
                             float s0, float s1, float s2)
{
    out[0] = lp[0] * s0 + lp[1] * s1 + lp[2] * s2;
}

// ---------------------------------------------------------------------------
extern "C" void kernel_launch(void* const* d_in, const int* in_sizes, int n_in,
                              void* d_out, int out_size, void* d_ws, size_t ws_size,
                              hipStream_t stream)
{
    const float* cs2 = (const float*)d_in[0];
    const float* c2  = (const float*)d_in[1];
    const float* s2v = (const float*)d_in[2];
    const float* cc2 = (const float*)d_in[3];
    const float* sc2 = (const float*)d_in[4];
    const float* cs3 = (const float*)d_in[5];
    const float* c3  = (const float*)d_in[6];
    const float* s3v = (const float*)d_in[7];
    const float* cc3 = (const float*)d_in[8];
    const float* sc3 = (const float*)d_in[9];
    const float* cs4 = (const float*)d_in[10];
    const float* c4  = (const float*)d_in[11];
    const float* s4v = (const float*)d_in[12];
    const float* cc4 = (const float*)d_in[13];
    const float* sc4 = (const float*)d_in[14];

    const int B = 4;
    float* ws = (float*)d_ws;
    size_t fo = 0;
    auto allocF = [&](size_t n) { float* p = ws + fo; fo += n; return p; };

    float* lossp = allocF(4);
    float* c2m = allocF(B * 256);  float* c2r = allocF(B * 256);
    float* q2m = allocF(B * 448);  float* q2r = allocF(B * 448);
    float* k2m = allocF(B * 448);  float* k2r = allocF(B * 448);
    float* c3m = allocF(B * 512);  float* c3r = allocF(B * 512);
    float* q3m = allocF(B * 960);  float* q3r = allocF(B * 960);
    float* k3m = allocF(B * 960);  float* k3r = allocF(B * 960);
    float* c4m = allocF(B * 512);  float* c4r = allocF(B * 512);
    float* q4m = allocF(B * 1472); float* q4r = allocF(B * 1472);
    float* k4m = allocF(B * 1472); float* k4r = allocF(B * 1472);
    size_t zeroBytes = fo * sizeof(float);

    // partial-state buffers (shared across scales; stream-ordered reuse)
    float* Pm = allocF(32768);
    float* Pl = allocF(32768);
    float* PM = allocF(8388608);
    float* PS = allocF(8388608);

    // fp16 arena (16B aligned), reused per scale
    size_t arenaOff = ((fo * 4 + 15) & ~(size_t)15) / 2;
    ushort_t* arena = (ushort_t*)d_ws + arenaOff;
    const size_t arenaShorts = 18874400;   // max per-scale need (scale 2)
    size_t need = arenaOff * 2 + arenaShorts * 2;
    const bool fast = (ws_size >= need);

    hipMemsetAsync(d_ws, 0, zeroBytes, stream);

    // ---- fused stats (2 launches for all 9 tensors) ----
    {
        StatJobs SJ; FinJobs FJ;
        const float* xs[9] = {c2, cc2, sc2, c3, cc3, sc3, c4, cc4, sc4};
        float* sms[9] = {c2m, q2m, k2m, c3m, q3m, k3m, c4m, q4m, k4m};
        float* sqs[9] = {c2r, q2r, k2r, c3r, q3r, k3r, c4r, q4r, k4r};
        const int Ns[9]  = {4096, 4096, 4096, 1024, 1024, 1024, 256, 256, 256};
        const int Cns[9] = {256, 448, 448, 512, 960, 960, 512, 1472, 1472};
        int pb = 0, fb = 0;
        for (int j = 0; j < 9; ++j) {
            int chG = (Cns[j] + 255) / 256;
            int nG  = (Ns[j] + 255) / 256;
            SJ.x[j] = xs[j]; SJ.sm[j] = sms[j]; SJ.sq[j] = sqs[j];
            SJ.N[j] = Ns[j]; SJ.Cn[j] = Cns[j]; SJ.chG[j] = chG; SJ.nG[j] = nG;
            SJ.base[j] = pb;
            pb += B * chG * nG;
            FJ.sm[j] = sms[j]; FJ.sq[j] = sqs[j]; FJ.base[j] = fb;
            FJ.invN[j] = 1.0f / (float)Ns[j];
            fb += B * Cns[j];
        }
        FJ.total = fb;
        hipLaunchKernelGGL(stat_partial_all, dim3(pb), dim3(256), 0, stream, SJ);
        hipLaunchKernelGGL(stat_finalize_all, dim3((fb + 255) / 256), dim3(256), 0, stream, FJ);
    }

    if (fast) {
        // ---- scale 2: N=4096, Cc=448, C=256 ----
        {
            size_t o = 0;
            auto aU = [&](size_t n) { ushort_t* p = arena + o; o += (n + 7) & ~(size_t)7; return p; };
            ushort_t *qh = aU((size_t)B*4096*448), *kh = aU((size_t)B*4096*448);
            ushort_t *vh = aU((size_t)B*4096*256);
            hipLaunchKernelGGL(prep_scale, dim3(2*B*4096 + B*(256/64)*(4096/512)), dim3(256), 0, stream,
                               cc2, q2m, q2r, qh, sc2, k2m, k2r, kh, s2v, vh, 4096, 448, 256, 512);
            hipLaunchKernelGGL(flash_pipe, dim3(B*(4096/64)*2), dim3(256), 0, stream,
                               qh, kh, vh, Pm, Pl, PM, PS);
            hipLaunchKernelGGL((combine_aat<256, 2>), dim3(B*4096/16), dim3(256), 0, stream,
                               Pm, Pl, PM, PS, c2, cs2, c2m, c2r, &lossp[0], 4096);
        }
        // ---- scale 3: N=1024, Cc=960, C=512, CSPLIT=2, SPLIT=4, KGRP=4 ----
        {
            size_t o = 0;
            auto aU = [&](size_t n) { ushort_t* p = arena + o; o += (n + 7) & ~(size_t)7; return p; };
            ushort_t *qh = aU((size_t)B*1024*960), *kh = aU((size_t)B*1024*960);
            ushort_t *vh = aU((size_t)B*1024*512);
            hipLaunchKernelGGL(prep_scale, dim3(2*B*1024 + B*(512/64)*(1024/512)), dim3(256), 0, stream,
                               cc3, q3m, q3r, qh, sc3, k3m, k3r, kh, s3v, vh, 1024, 960, 512, 512);
            hipLaunchKernelGGL((flash_mfma<960, 512, 1024, 2, false, 4, 4, 4>),
                               dim3(B*(1024/32)*4), dim3(256), 0, stream,
                               qh, kh, vh, Pm, Pl, PM, PS);
            hipLaunchKernelGGL((combine_aat<512, 4>), dim3(B*1024/16), dim3(256), 0, stream,
                               Pm, Pl, PM, PS, c3, cs3, c3m, c3r, &lossp[1], 1024);
        }
        // ---- scale 4: N=256, Cc=1472, C=512, CSPLIT=4, SPLIT=4, KGRP=4 ----
        {
            size_t o = 0;
            auto aU = [&](size_t n) { ushort_t* p = arena + o; o += (n + 7) & ~(size_t)7; return p; };
            ushort_t *qh = aU((size_t)B*256*1472), *kh = aU((size_t)B*256*1472);
            ushort_t *vh = aU((size_t)B*256*512);
            hipLaunchKernelGGL(prep_scale, dim3(2*B*256 + B*(512/64)*(256/256)), dim3(256), 0, stream,
                               cc4, q4m, q4r, qh, sc4, k4m, k4r, kh, s4v, vh, 256, 1472, 512, 256);
            hipLaunchKernelGGL((flash_mfma<1472, 512, 256, 4, false, 4, 4, 4>),
                               dim3(B*(256/16)*4), dim3(256), 0, stream,
                               qh, kh, vh, Pm, Pl, PM, PS);
            hipLaunchKernelGGL((combine_aat<512, 4>), dim3(B*256/16), dim3(256), 0, stream,
                               Pm, Pl, PM, PS, c4, cs4, c4m, c4r, &lossp[2], 256);
        }
    } else {
        hipLaunchKernelGGL((flash_aat<7, 4, 4>), dim3(B * 4096 / 16), dim3(256), 0, stream,
                           cc2, sc2, s2v, c2, cs2, q2m, q2r, k2m, k2r, c2m, c2r, &lossp[0], 4096);
        hipLaunchKernelGGL((flash_aat<15, 8, 2>), dim3(B * 1024 / 8), dim3(256), 0, stream,
                           cc3, sc3, s3v, c3, cs3, q3m, q3r, k3m, k3r, c3m, c3r, &lossp[1], 1024);
        hipLaunchKernelGGL((flash_aat<23, 8, 2>), dim3(B * 256 / 8), dim3(256), 0, stream,
                           cc4, sc4, s4v, c4, cs4, q4m, q4r, k4m, k4r, c4m, c4r, &lossp[2], 256);
    }

    hipLaunchKernelGGL(combine_loss, dim3(1), dim3(1), 0, stream,
                       lossp, (float*)d_out,
                       1.0f / (4.0f * 4096.0f * 256.0f),
                       1.0f / (4.0f * 1024.0f * 512.0f),
                       1.0f / (4.0f * 256.0f * 512.0f));
}

// Round 4
// 719.201 us; speedup vs baseline: 2.2489x; 1.0444x over previous
//
#include <hip/hip_runtime.h>
#include <math.h>

#define EPS_NORM 1e-5f
#define EPS_VAR  1e-9f
#define LOG2E    1.4426950408889634f

typedef unsigned short ushort_t;
typedef __attribute__((ext_vector_type(4))) float f32x4;
typedef _Float16 half8 __attribute__((ext_vector_type(8)));

#define MFMAH(a, b, c) __builtin_amdgcn_mfma_f32_16x16x32_f16((a), (b), (c), 0, 0, 0)

// async global->LDS DMA, 16B per lane; LDS dest = wave-uniform base + lane*16
#define GLD16(gp, lp) __builtin_amdgcn_global_load_lds(                          \
    (const __attribute__((address_space(1))) unsigned int*)(gp),                 \
    (__attribute__((address_space(3))) unsigned int*)(lp), 16, 0, 0)

// ---------------------------------------------------------------------------
// fp16 helpers
// ---------------------------------------------------------------------------
__device__ inline ushort_t f16_bits(float x) {
    _Float16 h = (_Float16)x;
    ushort_t u;
    __builtin_memcpy(&u, &h, 2);
    return u;
}
__device__ inline half8 ldh(const ushort_t* p) {   // 16B-aligned load
    half8 h;
    __builtin_memcpy(&h, p, 16);
    return h;
}
__device__ inline uint4 pack8(const ushort_t* s) {
    uint4 r;
    r.x = (unsigned)s[0] | ((unsigned)s[1] << 16);
    r.y = (unsigned)s[2] | ((unsigned)s[3] << 16);
    r.z = (unsigned)s[4] | ((unsigned)s[5] << 16);
    r.w = (unsigned)s[6] | ((unsigned)s[7] << 16);
    return r;
}

// ---------------------------------------------------------------------------
// Fused stage-1 stats: all 9 tensors in one launch (job table)
// ---------------------------------------------------------------------------
struct StatJobs {
    const float* x[9];
    float* sm[9];
    float* sq[9];
    int N[9], Cn[9], chG[9], nG[9], base[9];
};
__global__ void __launch_bounds__(256) stat_partial_all(StatJobs J)
{
    int bx = blockIdx.x;
    int j = 0;
#pragma unroll
    for (int k = 1; k < 9; ++k) if (bx >= J.base[k]) j = k;
    bx -= J.base[j];
    const int N = J.N[j], Cn = J.Cn[j], chG = J.chG[j], nG = J.nG[j];
    int b  = bx / (chG * nG);
    int r  = bx % (chG * nG);
    int cg = r / nG;
    int ng = r % nG;
    int ch = cg * 256 + threadIdx.x;
    if (ch >= Cn) return;
    int n0 = ng * 256;
    int n1 = min(n0 + 256, N);
    const float* p = J.x[j] + (long)(b * N) * Cn + ch;
    float s = 0.f, ss = 0.f;
    for (int n = n0; n < n1; ++n) {
        float v = p[(long)n * Cn];
        s += v;
        ss = fmaf(v, v, ss);
    }
    atomicAdd(&J.sm[j][b * Cn + ch], s);
    atomicAdd(&J.sq[j][b * Cn + ch], ss);
}

struct FinJobs {
    float* sm[9];
    float* sq[9];
    int base[9];
    float invN[9];
    int total;
};
__global__ void __launch_bounds__(256) stat_finalize_all(FinJobs J)
{
    int i = blockIdx.x * 256 + threadIdx.x;
    if (i >= J.total) return;
    int j = 0;
#pragma unroll
    for (int k = 1; k < 9; ++k) if (i >= J.base[k]) j = k;
    int e = i - J.base[j];
    float m = J.sm[j][e] * J.invN[j];
    float v = J.sq[j][e] * J.invN[j] - m * m;
    J.sm[j][e] = m;
    J.sq[j][e] = rsqrtf(v + EPS_NORM);
}

// ---------------------------------------------------------------------------
// Fused prep for ALL scales in ONE launch.  Per scale:
//  - norm jobs: wave-per-row, float4 in / uint4 (8 fp16) out; Q scaled log2e
//  - V transpose -> (B,C,N) fp16
// ---------------------------------------------------------------------------
struct PrepJobs {
    const float* qx[3]; const float* qm[3]; const float* qr[3]; ushort_t* qh[3];
    const float* kx[3]; const float* km[3]; const float* kr[3]; ushort_t* kh[3];
    const float* vx[3]; ushort_t* vt[3];
    int N[3], Cc[3], C[3], KSEG[3], nbase[3];
};
__global__ void __launch_bounds__(256) prep_all(PrepJobs J)
{
    int bx = blockIdx.x;
    int j = 0;
#pragma unroll
    for (int k = 1; k < 3; ++k) if (bx >= J.nbase[k]) j = k;
    bx -= J.nbase[j];
    const int N = J.N[j], Cc = J.Cc[j];
    const int normBlocks = 2 * N;             // (2*B*N)/4 rows-blocks, B=4
    if (bx < normBlocks) {
        const int wave = threadIdx.x >> 6, lane = threadIdx.x & 63;
        int rr = bx * 4 + wave;               // 0 .. 2*B*N-1
        const int BN = 4 * N;
        const bool isQ = rr < BN;
        int bn = isQ ? rr : rr - BN;
        const float* x    = isQ ? J.qx[j] : J.kx[j];
        const float* mean = isQ ? J.qm[j] : J.km[j];
        const float* rstd = isQ ? J.qr[j] : J.kr[j];
        ushort_t* out     = isQ ? J.qh[j] : J.kh[j];
        const float scl   = isQ ? LOG2E : 1.0f;
        int b = bn / N;
        long base = (long)bn * Cc;
        const float* mb = mean + b * Cc;
        const float* rb = rstd + b * Cc;
        for (int c8 = lane; c8 * 8 < Cc; c8 += 64) {
            int ch = c8 * 8;
            float4 a0 = *(const float4*)(x + base + ch);
            float4 a1 = *(const float4*)(x + base + ch + 4);
            float4 m0 = *(const float4*)(mb + ch);
            float4 m1 = *(const float4*)(mb + ch + 4);
            float4 r0 = *(const float4*)(rb + ch);
            float4 r1 = *(const float4*)(rb + ch + 4);
            ushort_t h8[8];
            h8[0] = f16_bits((a0.x - m0.x) * r0.x * scl);
            h8[1] = f16_bits((a0.y - m0.y) * r0.y * scl);
            h8[2] = f16_bits((a0.z - m0.z) * r0.z * scl);
            h8[3] = f16_bits((a0.w - m0.w) * r0.w * scl);
            h8[4] = f16_bits((a1.x - m1.x) * r1.x * scl);
            h8[5] = f16_bits((a1.y - m1.y) * r1.y * scl);
            h8[6] = f16_bits((a1.z - m1.z) * r1.z * scl);
            h8[7] = f16_bits((a1.w - m1.w) * r1.w * scl);
            *(uint4*)(out + base + ch) = pack8(h8);
        }
    } else {
        int bid2 = bx - normBlocks;
        const int C = J.C[j], KSEG = J.KSEG[j];
        const float* vx = J.vx[j];
        ushort_t* vt = J.vt[j];
        int cPB = C / 64, nSeg = N / KSEG;
        int b   = bid2 / (cPB * nSeg);
        int rem = bid2 % (cPB * nSeg);
        int cb  = rem / nSeg;
        int ns  = rem % nSeg;
        int ch  = cb * 64 + (threadIdx.x & 63);
        const int KL = KSEG / 4;
        int k0  = ns * KSEG + (threadIdx.x >> 6) * KL;
        long obase = ((long)b * C + ch) * N;
        for (int k = k0; k < k0 + KL; k += 8) {
            ushort_t h8[8];
#pragma unroll
            for (int i = 0; i < 8; ++i)
                h8[i] = f16_bits(vx[((long)b * N + k + i) * C + ch]);
            *(uint4*)(vt + obase + k) = pack8(h8);
        }
    }
}

// ---------------------------------------------------------------------------
// Async DMA tile stagers (generic versions; used by flash_mfma).
// LDS tiles are 64 shorts/row, XOR-swizzled:
// LDS[r][g] (16B granule g of row r) holds global[r][g ^ (r&7)].
// ---------------------------------------------------------------------------
__device__ inline void stage64_async(const ushort_t* __restrict__ g, long rowBase,
                                     int gstride, int col0, ushort_t* slab, int tid)
{
    const int l  = tid & 63, w = tid >> 6;
    const int rs = l >> 3;
    const int cg = (l & 7) ^ rs;
#pragma unroll
    for (int i = 0; i < 2; ++i) {
        const int r = w * 16 + i * 8 + rs;
        const ushort_t* gp = g + (rowBase + r) * (long)gstride + col0 + (cg << 3);
        ushort_t* lp = slab + (w * 16 + i * 8) * 64 + l * 8;
        GLD16(gp, lp);
    }
}
template<int BROWS>
__device__ inline void stageQ_async(const ushort_t* __restrict__ g, long rowBase,
                                    int gstride, int col0, ushort_t* slab, int tid)
{
    if (tid < BROWS * 8) {
        const int l  = tid & 63, w = tid >> 6;
        const int rs = l >> 3;
        const int cg = (l & 7) ^ rs;
        const int r  = w * 8 + rs;
        const ushort_t* gp = g + (rowBase + r) * (long)gstride + col0 + (cg << 3);
        ushort_t* lp = slab + w * 8 * 64 + l * 8;
        GLD16(gp, lp);
    }
}
__device__ inline half8 ldsw(const ushort_t* slab, int row, int soff)
{
    const int gr = (soff >> 3) ^ (row & 7);
    return ldh(slab + row * 64 + (gr << 3));
}

// ---------------------------------------------------------------------------
// Pipelined flash for scale 2 (N=4096, Cc=448, C=256, QREG, SPLIT=2).
// 12-phase double-tile loop, ring of 4 pair-buffers (2 slabs each),
// depth-2 prefetch (stage pair p+2 at phase p), ONE barrier per phase,
// hardcoded counted vmcnt (never 0 mid-loop).
// Pair stream per tile: (K0K1)(K2K3)(K4K5)(K6)(V0V1)(V2V3); slot = pair%4.
// ---------------------------------------------------------------------------
__global__ void __launch_bounds__(256, 2) flash_pipe(
    const ushort_t* __restrict__ Qh, const ushort_t* __restrict__ Kh,
    const ushort_t* __restrict__ Vth,
    float* __restrict__ Pmo, float* __restrict__ Plo,
    float* __restrict__ PMo, float* __restrict__ PSo)
{
    constexpr int Cc = 448, C = 256, N = 4096, SPLIT = 2;
    constexpr int NKT  = (N / 64) / SPLIT;     // 32 key tiles per block
    constexpr long VCHO = 64L * N;             // shorts per V chunk block
    constexpr long KADV = 64L * Cc;            // shorts per K tile advance

    __shared__ __align__(16) ushort_t smem[4 * 8192 + 4 * 1152];
    const int tid  = threadIdx.x;
    const int lane = tid & 63;
    const int w    = tid >> 6;
    const int l15  = lane & 15;
    const int quad = lane >> 4;

    const int bq = blockIdx.x / SPLIT;
    const int sp = blockIdx.x % SPLIT;
    const int b  = bq / (N / 64);
    const int qb = bq % (N / 64);
    const int i0 = qb * 64 + w * 16;
    const long po = (long)(b * (N / 16) + qb * 4 + w) * SPLIT + sp;

    // ---- hoisted per-lane constants ----
    const int rs    = lane >> 3;
    const int cg    = (lane & 7) ^ rs;
    const int ldso0 = w * 1024 + lane * 8;     // LDS dest, row block i=0
    const int ldso1 = ldso0 + 512;
    const int xh    = l15 & 7;
    const int lb0   = l15 * 64 + ((quad)     ^ xh) * 8;   // swizzled read, ks=0
    const int lb1   = l15 * 64 + ((4 + quad) ^ xh) * 8;   // ks=1
    ushort_t* const Pw  = smem + 32768 + w * 1152;
    ushort_t* const pww = Pw + quad * 288 + l15;          // P write base
    const ushort_t* const pfr = Pw + l15 * 72 + quad * 8; // P read base

    // staging base pointers (advance incrementally)
    const long krow0 = (long)b * N + (long)sp * NKT * 64;
    const ushort_t* kp0 = Kh + (krow0 + w * 16 + rs) * (long)Cc + (cg << 3);
    const ushort_t* kp1 = kp0 + 8 * Cc;
    const ushort_t* vp0 = Vth + ((long)b * C + w * 16 + rs) * (long)N
                              + (cg << 3) + (long)sp * NKT * 64;
    const ushort_t* vp1 = vp0 + 8 * (long)N;

#define SLOT(k) (smem + (k) * 8192)
#define STGKP(c0, c1, slot, toff) do {                                           \
    GLD16(kp0 + (toff) + (c0) * 64, SLOT(slot) + ldso0);                         \
    GLD16(kp1 + (toff) + (c0) * 64, SLOT(slot) + ldso1);                         \
    GLD16(kp0 + (toff) + (c1) * 64, SLOT(slot) + 4096 + ldso0);                  \
    GLD16(kp1 + (toff) + (c1) * 64, SLOT(slot) + 4096 + ldso1); } while (0)
#define STGK1(c0, slot, toff) do {                                               \
    GLD16(kp0 + (toff) + (c0) * 64, SLOT(slot) + ldso0);                         \
    GLD16(kp1 + (toff) + (c0) * 64, SLOT(slot) + ldso1); } while (0)
#define STGVP(j0, slot, voff) do {                                               \
    GLD16(vp0 + (voff) + (j0) * VCHO, SLOT(slot) + ldso0);                       \
    GLD16(vp1 + (voff) + (j0) * VCHO, SLOT(slot) + ldso1);                       \
    GLD16(vp0 + (voff) + ((j0) + 1) * VCHO, SLOT(slot) + 4096 + ldso0);          \
    GLD16(vp1 + (voff) + ((j0) + 1) * VCHO, SLOT(slot) + 4096 + ldso1); } while (0)

#define WAITV(NN) asm volatile("s_waitcnt vmcnt(" #NN ")" ::: "memory");         \
    __builtin_amdgcn_sched_barrier(0);                                           \
    __builtin_amdgcn_s_barrier();                                                \
    __builtin_amdgcn_s_setprio(1);
#define PH_END __builtin_amdgcn_s_setprio(0);

#define QKPAIR(slot, c0) do {                                                    \
    const ushort_t* s0_ = SLOT(slot);                                            \
    const ushort_t* s1_ = s0_ + 4096;                                            \
    _Pragma("unroll")                                                            \
    for (int ct = 0; ct < 4; ++ct) S[ct] = MFMAH(qf[2*(c0)+0], ldh(s0_ + ct*1024 + lb0), S[ct]); \
    _Pragma("unroll")                                                            \
    for (int ct = 0; ct < 4; ++ct) S[ct] = MFMAH(qf[2*(c0)+1], ldh(s0_ + ct*1024 + lb1), S[ct]); \
    _Pragma("unroll")                                                            \
    for (int ct = 0; ct < 4; ++ct) S[ct] = MFMAH(qf[2*(c0)+2], ldh(s1_ + ct*1024 + lb0), S[ct]); \
    _Pragma("unroll")                                                            \
    for (int ct = 0; ct < 4; ++ct) S[ct] = MFMAH(qf[2*(c0)+3], ldh(s1_ + ct*1024 + lb1), S[ct]); } while (0)
#define QK1(slot, c0) do {                                                       \
    const ushort_t* s0_ = SLOT(slot);                                            \
    _Pragma("unroll")                                                            \
    for (int ct = 0; ct < 4; ++ct) S[ct] = MFMAH(qf[2*(c0)+0], ldh(s0_ + ct*1024 + lb0), S[ct]); \
    _Pragma("unroll")                                                            \
    for (int ct = 0; ct < 4; ++ct) S[ct] = MFMAH(qf[2*(c0)+1], ldh(s0_ + ct*1024 + lb1), S[ct]); } while (0)
#define PVPAIR(slot, ci0) do {                                                   \
    const ushort_t* s0_ = SLOT(slot);                                            \
    const ushort_t* s1_ = s0_ + 4096;                                            \
    _Pragma("unroll")                                                            \
    for (int ct = 0; ct < 4; ++ct) {                                             \
        half8 vh = ldh(s0_ + ct*1024 + lb0); half8 uh = vh * vh;                 \
        Mac[(ci0)*4 + ct] = MFMAH(pf0, vh, Mac[(ci0)*4 + ct]);                   \
        Sac[(ci0)*4 + ct] = MFMAH(pf0, uh, Sac[(ci0)*4 + ct]); }                 \
    _Pragma("unroll")                                                            \
    for (int ct = 0; ct < 4; ++ct) {                                             \
        half8 vh = ldh(s0_ + ct*1024 + lb1); half8 uh = vh * vh;                 \
        Mac[(ci0)*4 + ct] = MFMAH(pf1, vh, Mac[(ci0)*4 + ct]);                   \
        Sac[(ci0)*4 + ct] = MFMAH(pf1, uh, Sac[(ci0)*4 + ct]); }                 \
    _Pragma("unroll")                                                            \
    for (int ct = 0; ct < 4; ++ct) {                                             \
        half8 vh = ldh(s1_ + ct*1024 + lb0); half8 uh = vh * vh;                 \
        Mac[(ci0+1)*4 + ct] = MFMAH(pf0, vh, Mac[(ci0+1)*4 + ct]);               \
        Sac[(ci0+1)*4 + ct] = MFMAH(pf0, uh, Sac[(ci0+1)*4 + ct]); }             \
    _Pragma("unroll")                                                            \
    for (int ct = 0; ct < 4; ++ct) {                                             \
        half8 vh = ldh(s1_ + ct*1024 + lb1); half8 uh = vh * vh;                 \
        Mac[(ci0+1)*4 + ct] = MFMAH(pf1, vh, Mac[(ci0+1)*4 + ct]);               \
        Sac[(ci0+1)*4 + ct] = MFMAH(pf1, uh, Sac[(ci0+1)*4 + ct]); } } while (0)
#define RESET_S do {                                                             \
    _Pragma("unroll")                                                            \
    for (int ct = 0; ct < 4; ++ct)                                               \
        _Pragma("unroll")                                                        \
        for (int r = 0; r < 4; ++r) S[ct][r] = 0.f; } while (0)

    half8 qf[14];
    {
        const ushort_t* q1 = Qh + ((long)(b * N + i0 + l15)) * Cc + quad * 8;
#pragma unroll
        for (int ks = 0; ks < 14; ++ks) qf[ks] = ldh(q1 + ks * 32);
    }
    asm volatile("s_waitcnt vmcnt(0)" ::: "memory");   // qf drained before DMA counting

    float m_r[4], l_l[4], mw = -1e30f;
    f32x4 Mac[16], Sac[16];
    f32x4 S[4];
    half8 pf0, pf1;
#pragma unroll
    for (int r = 0; r < 4; ++r) { m_r[r] = -1e30f; l_l[r] = 0.f; }
#pragma unroll
    for (int ct = 0; ct < 16; ++ct)
#pragma unroll
        for (int r = 0; r < 4; ++r) { Mac[ct][r] = 0.f; Sac[ct][r] = 0.f; }

    auto softmax_step = [&]() {
        float tmax = S[0][0];
#pragma unroll
        for (int ct = 0; ct < 4; ++ct)
#pragma unroll
            for (int r = 0; r < 4; ++r) tmax = fmaxf(tmax, S[ct][r]);
#pragma unroll
        for (int off = 1; off <= 32; off <<= 1)
            tmax = fmaxf(tmax, __shfl_xor(tmax, off, 64));

        if (tmax > mw + 14.4269504f) {
            float rm[4];
#pragma unroll
            for (int r = 0; r < 4; ++r)
                rm[r] = fmaxf(fmaxf(S[0][r], S[1][r]), fmaxf(S[2][r], S[3][r]));
#pragma unroll
            for (int off = 1; off <= 8; off <<= 1)
#pragma unroll
                for (int r = 0; r < 4; ++r)
                    rm[r] = fmaxf(rm[r], __shfl_xor(rm[r], off, 64));
#pragma unroll
            for (int r = 0; r < 4; ++r) {
                float mn = fmaxf(m_r[r], rm[r]);
                float corr = exp2f(m_r[r] - mn);
                m_r[r] = mn;
                l_l[r] *= corr;
#pragma unroll
                for (int ct = 0; ct < 16; ++ct) { Mac[ct][r] *= corr; Sac[ct][r] *= corr; }
            }
            float tt = fminf(fminf(m_r[0], m_r[1]), fminf(m_r[2], m_r[3]));
            tt = fminf(tt, __shfl_xor(tt, 16, 64));
            tt = fminf(tt, __shfl_xor(tt, 32, 64));
            mw = tt;
        }
#pragma unroll
        for (int ct = 0; ct < 4; ++ct)
#pragma unroll
            for (int r = 0; r < 4; ++r) {
                float p = exp2f(S[ct][r] - m_r[r]);
                l_l[r] += p;
                pww[r * 72 + ct * 16] = f16_bits(p);
            }
        pf0 = ldh(pfr);
        pf1 = ldh(pfr + 32);
    };

    // ---- prologue: pair0 -> slot0, pair1 -> slot1 (8 GLD outstanding) ----
    STGKP(0, 1, 0, 0);
    STGKP(2, 3, 1, 0);

    for (int it = 0; it < NKT / 2; ++it) {
        // ================= tile A =================
        RESET_S;
        // ph0: stage K4K5(A)->s2 | compute K0K1@s0
        STGKP(4, 5, 2, 0);
        WAITV(8)  QKPAIR(0, 0); PH_END;
        // ph1: stage K6(A)->s3 | compute K2K3@s1
        STGK1(6, 3, 0);
        WAITV(6)  QKPAIR(1, 2); PH_END;
        // ph2: stage V0V1(A)->s0 | compute K4K5@s2
        STGVP(0, 0, 0);
        WAITV(6)  QKPAIR(2, 4); PH_END;
        // ph3: stage V2V3(A)->s1 | compute K6@s3 + softmax
        STGVP(2, 1, 0);
        WAITV(8)  QK1(3, 6); PH_END;
        softmax_step();
        // ph4: stage K0K1(B)->s2 | compute PV V0V1@s0
        STGKP(0, 1, 2, KADV);
        WAITV(8)  PVPAIR(0, 0); PH_END;
        // ph5: stage K2K3(B)->s3 | compute PV V2V3@s1
        STGKP(2, 3, 3, KADV);
        WAITV(8)  PVPAIR(1, 2); PH_END;

        // ================= tile B =================
        RESET_S;
        // ph6: stage K4K5(B)->s0 | compute K0K1@s2
        STGKP(4, 5, 0, KADV);
        WAITV(8)  QKPAIR(2, 0); PH_END;
        // ph7: stage K6(B)->s1 | compute K2K3@s3
        STGK1(6, 1, KADV);
        WAITV(6)  QKPAIR(3, 2); PH_END;
        // ph8: stage V0V1(B)->s2 | compute K4K5@s0
        STGVP(0, 2, 64);
        WAITV(6)  QKPAIR(0, 4); PH_END;
        // ph9: stage V2V3(B)->s3 | compute K6@s1 + softmax
        STGVP(2, 3, 64);
        WAITV(8)  QK1(1, 6); PH_END;
        softmax_step();
        // ph10: stage K0K1(A')->s0 | compute PV V0V1@s2
        const bool more = (it + 1 < NKT / 2);
        if (more) {
            kp0 += 2 * KADV; kp1 += 2 * KADV;
            STGKP(0, 1, 0, 0);
            asm volatile("s_waitcnt vmcnt(8)" ::: "memory");
        } else {
            asm volatile("s_waitcnt vmcnt(4)" ::: "memory");
        }
        __builtin_amdgcn_sched_barrier(0);
        __builtin_amdgcn_s_barrier();
        __builtin_amdgcn_s_setprio(1);
        PVPAIR(2, 0);
        PH_END;
        // ph11: stage K2K3(A')->s1 | compute PV V2V3@s3
        if (more) {
            STGKP(2, 3, 1, 0);
            asm volatile("s_waitcnt vmcnt(8)" ::: "memory");
        } else {
            asm volatile("s_waitcnt vmcnt(0)" ::: "memory");
        }
        __builtin_amdgcn_sched_barrier(0);
        __builtin_amdgcn_s_barrier();
        __builtin_amdgcn_s_setprio(1);
        PVPAIR(3, 2);
        PH_END;

        vp0 += 128; vp1 += 128;
    }
#undef SLOT
#undef STGKP
#undef STGK1
#undef STGVP
#undef WAITV
#undef PH_END
#undef QKPAIR
#undef QK1
#undef PVPAIR
#undef RESET_S

    // ---- reduce per-lane l, dump partial state ----
#pragma unroll
    for (int off = 1; off <= 8; off <<= 1)
#pragma unroll
        for (int r = 0; r < 4; ++r) l_l[r] += __shfl_xor(l_l[r], off, 64);

    if (l15 == 0) {
#pragma unroll
        for (int r = 0; r < 4; ++r) {
            Pmo[po * 16 + quad * 4 + r] = m_r[r];
            Plo[po * 16 + quad * 4 + r] = l_l[r];
        }
    }
#pragma unroll
    for (int ct = 0; ct < 16; ++ct)
#pragma unroll
        for (int r = 0; r < 4; ++r) {
            long idx = (po * 16 + quad * 4 + r) * C + ct * 16 + l15;
            PMo[idx] = Mac[ct][r];
            PSo[idx] = Sac[ct][r];
        }
}

// ---------------------------------------------------------------------------
// Generic flash (scales 3/4): __syncthreads structure, async DMA staging,
// swizzled unpadded LDS slabs.  Softmax in log2 domain (Q pre-scaled).
// ---------------------------------------------------------------------------
template<int Cc, int C, int N, int CSPLIT, bool QREG, int SPLIT, int SLABS, int KGRP>
__global__ void __launch_bounds__(256, 2) flash_mfma(
    const ushort_t* __restrict__ Qh, const ushort_t* __restrict__ Kh,
    const ushort_t* __restrict__ Vth,
    float* __restrict__ Pmo, float* __restrict__ Plo,
    float* __restrict__ PMo, float* __restrict__ PSo)
{
    constexpr int KC      = Cc / 64;
    constexpr int VC      = C / 64;
    constexpr int VCW     = VC / CSPLIT;
    constexpr int CTCW    = 4 * VCW;
    constexpr int STRIPES = 4 / CSPLIT;
    constexpr int BROWS   = 16 * STRIPES;
    constexpr int QB      = N / BROWS;
    constexpr int TILES   = N / 64;
    constexpr int NKT     = TILES / SPLIT;
    constexpr int NKS     = QREG ? (Cc / 32) : 1;
    constexpr int NGRP    = (KC + KGRP - 1) / KGRP;
    constexpr int G       = 4 / CSPLIT;
    constexpr int QCH     = BROWS * 64;
    constexpr int QOFF    = KGRP * 4096;
    constexpr int KQEND   = QOFF + KGRP * QCH;
    constexpr int REGION  = QREG ? (SLABS * 4096)
                                 : (KQEND > SLABS * 4096 ? KQEND : SLABS * 4096);

    __shared__ __align__(16) ushort_t smem[REGION + 4 * 1152];
    const int tid  = threadIdx.x;
    const int lane = tid & 63;
    const int w    = tid >> 6;
    const int l15  = lane & 15;
    const int quad = lane >> 4;

    const int bq = blockIdx.x / SPLIT;
    const int sp = blockIdx.x % SPLIT;
    const int b  = bq / QB;
    const int qb = bq % QB;
    const int ls  = w / CSPLIT;
    const int ch2 = w % CSPLIT;
    const int i0 = qb * BROWS + ls * 16;
    const long po = (long)(b * (N / 16) + qb * STRIPES + ls) * SPLIT + sp;
    ushort_t* Pw = smem + REGION + w * 1152;

    half8 qf[NKS];
    if constexpr (QREG) {
        const ushort_t* q1 = Qh + ((long)(b * N + i0 + l15)) * Cc + quad * 8;
#pragma unroll
        for (int ks = 0; ks < NKS; ++ks) qf[ks] = ldh(q1 + ks * 32);
    }

    float m_r[4], l_l[4], mw = -1e30f;
    f32x4 Mac[CTCW], Sac[CTCW];
#pragma unroll
    for (int r = 0; r < 4; ++r) { m_r[r] = -1e30f; l_l[r] = 0.f; }
#pragma unroll
    for (int ct = 0; ct < CTCW; ++ct)
#pragma unroll
        for (int r = 0; r < 4; ++r) { Mac[ct][r] = 0.f; Sac[ct][r] = 0.f; }

    for (int kt = sp * NKT; kt < sp * NKT + NKT; ++kt) {
        const long krow = (long)b * N + kt * 64;

        f32x4 S[4];
#pragma unroll
        for (int ct = 0; ct < 4; ++ct)
#pragma unroll
            for (int r = 0; r < 4; ++r) S[ct][r] = 0.f;

        // ---- QK ----
#pragma unroll
        for (int grp = 0; grp < NGRP; ++grp) {
            const int g0 = grp * KGRP;
            const int gn = (KC - g0 < KGRP) ? (KC - g0) : KGRP;
            __syncthreads();
#pragma unroll
            for (int j = 0; j < KGRP; ++j) if (j < gn) {
                stage64_async(Kh, krow, Cc, (g0 + j) * 64, smem + j * 4096, tid);
                if constexpr (!QREG)
                    stageQ_async<BROWS>(Qh, (long)b * N + qb * BROWS, Cc, (g0 + j) * 64,
                                        smem + QOFF + j * QCH, tid);
            }
            __syncthreads();
#pragma unroll
            for (int j = 0; j < KGRP; ++j) if (j < gn) {
#pragma unroll
                for (int ks = 0; ks < 2; ++ks) {
                    half8 a;
                    if constexpr (QREG) a = qf[(g0 + j) * 2 + ks];
                    else a = ldsw(smem + QOFF + j * QCH, ls * 16 + l15, ks * 32 + quad * 8);
#pragma unroll
                    for (int ct = 0; ct < 4; ++ct) {
                        half8 bf = ldsw(smem + j * 4096, ct * 16 + l15, ks * 32 + quad * 8);
                        S[ct] = MFMAH(a, bf, S[ct]);
                    }
                }
            }
        }

        // ---- online softmax, lazy base (log2 domain) ----
        float tmax = S[0][0];
#pragma unroll
        for (int ct = 0; ct < 4; ++ct)
#pragma unroll
            for (int r = 0; r < 4; ++r) tmax = fmaxf(tmax, S[ct][r]);
#pragma unroll
        for (int off = 1; off <= 32; off <<= 1)
            tmax = fmaxf(tmax, __shfl_xor(tmax, off, 64));

        if (tmax > mw + 14.4269504f) {
            float rm[4];
#pragma unroll
            for (int r = 0; r < 4; ++r)
                rm[r] = fmaxf(fmaxf(S[0][r], S[1][r]), fmaxf(S[2][r], S[3][r]));
#pragma unroll
            for (int off = 1; off <= 8; off <<= 1)
#pragma unroll
                for (int r = 0; r < 4; ++r)
                    rm[r] = fmaxf(rm[r], __shfl_xor(rm[r], off, 64));
#pragma unroll
            for (int r = 0; r < 4; ++r) {
                float mn = fmaxf(m_r[r], rm[r]);
                float corr = exp2f(m_r[r] - mn);
                m_r[r] = mn;
                l_l[r] *= corr;
#pragma unroll
                for (int ct = 0; ct < CTCW; ++ct) { Mac[ct][r] *= corr; Sac[ct][r] *= corr; }
            }
            float t = fminf(fminf(m_r[0], m_r[1]), fminf(m_r[2], m_r[3]));
            t = fminf(t, __shfl_xor(t, 16, 64));
            t = fminf(t, __shfl_xor(t, 32, 64));
            mw = t;
        }

#pragma unroll
        for (int ct = 0; ct < 4; ++ct)
#pragma unroll
            for (int r = 0; r < 4; ++r) {
                float p = exp2f(S[ct][r] - m_r[r]);
                l_l[r] += p;
                Pw[(quad * 4 + r) * 72 + ct * 16 + l15] = f16_bits(p);
            }

        half8 pf0 = ldh(Pw + l15 * 72 + 0  + quad * 8);
        half8 pf1 = ldh(Pw + l15 * 72 + 32 + quad * 8);

        // ---- PV / PV^2 ----
#pragma unroll
        for (int g = 0; g < VCW; g += G) {
            __syncthreads();
#pragma unroll
            for (int s = 0; s < 4; ++s) {
                const int h = s / G, j = s % G;
                stage64_async(Vth, (long)b * C + (h * VCW + g + j) * 64, N, kt * 64,
                              smem + s * 4096, tid);
            }
            __syncthreads();
#pragma unroll
            for (int ks = 0; ks < 2; ++ks) {
                half8 pf = ks ? pf1 : pf0;
#pragma unroll
                for (int j = 0; j < G; ++j)
#pragma unroll
                    for (int ct = 0; ct < 4; ++ct) {
                        half8 vh = ldsw(smem + (ch2 * G + j) * 4096,
                                        ct * 16 + l15, ks * 32 + quad * 8);
                        half8 uh = vh * vh;
                        const int ci = (g + j) * 4 + ct;
                        Mac[ci] = MFMAH(pf, vh, Mac[ci]);
                        Sac[ci] = MFMAH(pf, uh, Sac[ci]);
                    }
            }
        }
    }

    // ---- reduce per-lane l, dump partial state ----
#pragma unroll
    for (int off = 1; off <= 8; off <<= 1)
#pragma unroll
        for (int r = 0; r < 4; ++r) l_l[r] += __shfl_xor(l_l[r], off, 64);

    if (ch2 == 0 && l15 == 0) {
#pragma unroll
        for (int r = 0; r < 4; ++r) {
            Pmo[po * 16 + quad * 4 + r] = m_r[r];
            Plo[po * 16 + quad * 4 + r] = l_l[r];
        }
    }
    const int chb = ch2 * (C / CSPLIT);
#pragma unroll
    for (int ct = 0; ct < CTCW; ++ct)
#pragma unroll
        for (int r = 0; r < 4; ++r) {
            long idx = (po * 16 + quad * 4 + r) * C + chb + ct * 16 + l15;
            PMo[idx] = Mac[ct][r];
            PSo[idx] = Sac[ct][r];
        }
}

// ---------------------------------------------------------------------------
// Combine: merge SPLIT flash partials (log2-domain m), float4 inner loop,
// fused epilogue + MSE.
// ---------------------------------------------------------------------------
template<int C, int SPLIT>
__global__ void __launch_bounds__(256) combine_aat(
    const float* __restrict__ Pm, const float* __restrict__ Pl,
    const float* __restrict__ PM, const float* __restrict__ PS,
    const float* __restrict__ CT, const float* __restrict__ CS,
    const float* __restrict__ cmean, const float* __restrict__ crstd,
    float* __restrict__ loss, int N)
{
    constexpr int CL4 = C / 4;
    __shared__ float wS[SPLIT][16];
    __shared__ float invL[16];
    __shared__ float red[4];
    const int pi = blockIdx.x;
    const int nb = N / 16;
    const int b  = pi / nb;
    const long g0 = (long)b * N + (long)(pi % nb) * 16;
    const int tid = threadIdx.x;

    if (tid < 16) {
        float m = -1e30f;
#pragma unroll
        for (int s = 0; s < SPLIT; ++s)
            m = fmaxf(m, Pm[((long)pi * SPLIT + s) * 16 + tid]);
        float L = 0.f;
#pragma unroll
        for (int s = 0; s < SPLIT; ++s) {
            float e = exp2f(Pm[((long)pi * SPLIT + s) * 16 + tid] - m);
            wS[s][tid] = e;
            L = fmaf(e, Pl[((long)pi * SPLIT + s) * 16 + tid], L);
        }
        invL[tid] = 1.f / L;
    }
    __syncthreads();

    float acc = 0.f;
    for (int v = tid; v < 4 * C; v += 256) {
        const int r  = v / CL4;
        const int c0 = (v - r * CL4) * 4;
        const long q0 = (((long)pi * SPLIT) * 16 + r) * C + c0;
        float4 Ms = {0.f, 0.f, 0.f, 0.f}, Ss = {0.f, 0.f, 0.f, 0.f};
#pragma unroll
        for (int s = 0; s < SPLIT; ++s) {
            const float ws_ = wS[s][r];
            const float4 pm = *(const float4*)&PM[q0 + (long)s * 16 * C];
            const float4 ps = *(const float4*)&PS[q0 + (long)s * 16 * C];
            Ms.x = fmaf(ws_, pm.x, Ms.x); Ms.y = fmaf(ws_, pm.y, Ms.y);
            Ms.z = fmaf(ws_, pm.z, Ms.z); Ms.w = fmaf(ws_, pm.w, Ms.w);
            Ss.x = fmaf(ws_, ps.x, Ss.x); Ss.y = fmaf(ws_, ps.y, Ss.y);
            Ss.z = fmaf(ws_, ps.z, Ss.z); Ss.w = fmaf(ws_, ps.w, Ss.w);
        }
        const float iL = invL[r];
        const float4 ctv = *(const float4*)&CT[(g0 + r) * C + c0];
        const float4 csv = *(const float4*)&CS[(g0 + r) * C + c0];
        const float4 cmv = *(const float4*)&cmean[b * C + c0];
        const float4 crv = *(const float4*)&crstd[b * C + c0];
#pragma unroll
        for (int e = 0; e < 4; ++e) {
            const float Msx = (&Ms.x)[e] * iL;
            const float S2  = (&Ss.x)[e] * iL - Msx * Msx;
            const float Sx  = sqrtf(fmaxf(S2, EPS_VAR));
            const float nc  = ((&ctv.x)[e] - (&cmv.x)[e]) * (&crv.x)[e];
            const float d   = (&csv.x)[e] - (Sx * nc + Msx);
            acc = fmaf(d, d, acc);
        }
    }
#pragma unroll
    for (int off = 1; off <= 32; off <<= 1) acc += __shfl_xor(acc, off, 64);
    if ((tid & 63) == 0) red[tid >> 6] = acc;
    __syncthreads();
    if (tid == 0) atomicAdd(loss, red[0] + red[1] + red[2] + red[3]);
}

// ---------------------------------------------------------------------------
// Fallback scalar flash kernel (only if ws_size too small)
// ---------------------------------------------------------------------------
template<int CCL, int CL, int NQ>
__global__ void __launch_bounds__(256) flash_aat(
    const float* __restrict__ Q, const float* __restrict__ K, const float* __restrict__ V,
    const float* __restrict__ CT, const float* __restrict__ CS,
    const float* __restrict__ qmean, const float* __restrict__ qrstd,
    const float* __restrict__ kmean, const float* __restrict__ krstd,
    const float* __restrict__ cmean, const float* __restrict__ crstd,
    float* __restrict__ loss, int N)
{
    constexpr int CC   = CCL * 64;
    constexpr int C    = CL * 64;
    constexpr int ROWS = 4 * NQ;
    const int lane = threadIdx.x & 63;
    const int wave = threadIdx.x >> 6;
    const int rowBlocks = N / ROWS;
    const int b  = blockIdx.x / rowBlocks;
    const int rb = blockIdx.x % rowBlocks;
    const int i0 = rb * ROWS + wave * NQ;

    float kmu[CCL], krs[CCL];
#pragma unroll
    for (int t = 0; t < CCL; ++t) {
        int ch = lane + 64 * t;
        kmu[t] = kmean[b * CC + ch];
        krs[t] = krstd[b * CC + ch];
    }
    float q[NQ][CCL];
#pragma unroll
    for (int qi = 0; qi < NQ; ++qi) {
        long base = (long)(b * N + i0 + qi) * CC;
#pragma unroll
        for (int t = 0; t < CCL; ++t) {
            int ch = lane + 64 * t;
            q[qi][t] = (Q[base + ch] - qmean[b * CC + ch]) * qrstd[b * CC + ch];
        }
    }
    float mval[NQ], lsum[NQ];
    float Macc[NQ][CL], Sacc[NQ][CL];
#pragma unroll
    for (int qi = 0; qi < NQ; ++qi) {
        mval[qi] = -1e30f; lsum[qi] = 0.f;
#pragma unroll
        for (int t = 0; t < CL; ++t) { Macc[qi][t] = 0.f; Sacc[qi][t] = 0.f; }
    }
    for (int j = 0; j < N; ++j) {
        long kb = (long)(b * N + j) * CC;
        float dot[NQ];
#pragma unroll
        for (int qi = 0; qi < NQ; ++qi) dot[qi] = 0.f;
#pragma unroll
        for (int t = 0; t < CCL; ++t) {
            float kv = (K[kb + lane + 64 * t] - kmu[t]) * krs[t];
#pragma unroll
            for (int qi = 0; qi < NQ; ++qi) dot[qi] = fmaf(q[qi][t], kv, dot[qi]);
        }
#pragma unroll
        for (int off = 32; off > 0; off >>= 1)
#pragma unroll
            for (int qi = 0; qi < NQ; ++qi) dot[qi] += __shfl_xor(dot[qi], off, 64);
        long vb = (long)(b * N + j) * C;
        float vv[CL];
#pragma unroll
        for (int t = 0; t < CL; ++t) vv[t] = V[vb + lane + 64 * t];
#pragma unroll
        for (int qi = 0; qi < NQ; ++qi) {
            float s = dot[qi];
            float p;
            if (s > mval[qi]) {
                float cr2 = __expf(mval[qi] - s);
                lsum[qi] *= cr2;
#pragma unroll
                for (int t = 0; t < CL; ++t) { Macc[qi][t] *= cr2; Sacc[qi][t] *= cr2; }
                mval[qi] = s; p = 1.f;
            } else p = __expf(s - mval[qi]);
            lsum[qi] += p;
#pragma unroll
            for (int t = 0; t < CL; ++t) {
                float pv = p * vv[t];
                Macc[qi][t] += pv;
                Sacc[qi][t] = fmaf(pv, vv[t], Sacc[qi][t]);
            }
        }
    }
    float acc = 0.f;
#pragma unroll
    for (int qi = 0; qi < NQ; ++qi) {
        float inv_l = 1.f / lsum[qi];
        long base = (long)(b * N + i0 + qi) * C;
#pragma unroll
        for (int t = 0; t < CL; ++t) {
            int ch = lane + 64 * t;
            float M  = Macc[qi][t] * inv_l;
            float S2 = Sacc[qi][t] * inv_l - M * M;
            float S  = sqrtf(fmaxf(S2, EPS_VAR));
            float nc = (CT[base + ch] - cmean[b * C + ch]) * crstd[b * C + ch];
            float d  = CS[base + ch] - (S * nc + M);
            acc = fmaf(d, d, acc);
        }
    }
#pragma unroll
    for (int off = 32; off > 0; off >>= 1) acc += __shfl_xor(acc, off, 64);
    if (lane == 0) atomicAdd(loss, acc);
}

__global__ void combine_loss(const float* __restrict__ lp, float* __restrict__ out,
                             float s0, float s1, float s2)
{
    out[0] = lp[0] * s0 + lp[1] * s1 + lp[2] * s2;
}

// ---------------------------------------------------------------------------
extern "C" void kernel_launch(void* const* d_in, const int* in_sizes, int n_in,
                              void* d_out, int out_size, void* d_ws, size_t ws_size,
                              hipStream_t stream)
{
    const float* cs2 = (const float*)d_in[0];
    const float* c2  = (const float*)d_in[1];
    const float* s2v = (const float*)d_in[2];
    const float* cc2 = (const float*)d_in[3];
    const float* sc2 = (const float*)d_in[4];
    const float* cs3 = (const float*)d_in[5];
    const float* c3  = (const float*)d_in[6];
    const float* s3v = (const float*)d_in[7];
    const float* cc3 = (const float*)d_in[8];
    const float* sc3 = (const float*)d_in[9];
    const float* cs4 = (const float*)d_in[10];
    const float* c4  = (const float*)d_in[11];
    const float* s4v = (const float*)d_in[12];
    const float* cc4 = (const float*)d_in[13];
    const float* sc4 = (const float*)d_in[14];

    const int B = 4;
    float* ws = (float*)d_ws;
    size_t fo = 0;
    auto allocF = [&](size_t n) { float* p = ws + fo; fo += n; return p; };

    float* lossp = allocF(4);
    float* c2m = allocF(B * 256);  float* c2r = allocF(B * 256);
    float* q2m = allocF(B * 448);  float* q2r = allocF(B * 448);
    float* k2m = allocF(B * 448);  float* k2r = allocF(B * 448);
    float* c3m = allocF(B * 512);  float* c3r = allocF(B * 512);
    float* q3m = allocF(B * 960);  float* q3r = allocF(B * 960);
    float* k3m = allocF(B * 960);  float* k3r = allocF(B * 960);
    float* c4m = allocF(B * 512);  float* c4r = allocF(B * 512);
    float* q4m = allocF(B * 1472); float* q4r = allocF(B * 1472);
    float* k4m = allocF(B * 1472); float* k4r = allocF(B * 1472);
    size_t zeroBytes = fo * sizeof(float);

    // partial-state buffers (shared across scales; stream-ordered reuse)
    float* Pm = allocF(32768);
    float* Pl = allocF(32768);
    float* PM = allocF(8388608);
    float* PS = allocF(8388608);

    // fp16 arena (16B aligned), reused per scale
    size_t arenaOff = ((fo * 4 + 15) & ~(size_t)15) / 2;
    ushort_t* arena = (ushort_t*)d_ws + arenaOff;
    const size_t arenaShorts = 18874400;   // max per-scale need (scale 2)
    size_t need = arenaOff * 2 + arenaShorts * 2;
    const bool fast = (ws_size >= need);

    hipMemsetAsync(d_ws, 0, zeroBytes, stream);

    // ---- fused stats (2 launches for all 9 tensors) ----
    {
        StatJobs SJ; FinJobs FJ;
        const float* xs[9] = {c2, cc2, sc2, c3, cc3, sc3, c4, cc4, sc4};
        float* sms[9] = {c2m, q2m, k2m, c3m, q3m, k3m, c4m, q4m, k4m};
        float* sqs[9] = {c2r, q2r, k2r, c3r, q3r, k3r, c4r, q4r, k4r};
        const int Ns[9]  = {4096, 4096, 4096, 1024, 1024, 1024, 256, 256, 256};
        const int Cns[9] = {256, 448, 448, 512, 960, 960, 512, 1472, 1472};
        int pb = 0, fb = 0;
        for (int j = 0; j < 9; ++j) {
            int chG = (Cns[j] + 255) / 256;
            int nG  = (Ns[j] + 255) / 256;
            SJ.x[j] = xs[j]; SJ.sm[j] = sms[j]; SJ.sq[j] = sqs[j];
            SJ.N[j] = Ns[j]; SJ.Cn[j] = Cns[j]; SJ.chG[j] = chG; SJ.nG[j] = nG;
            SJ.base[j] = pb;
            pb += B * chG * nG;
            FJ.sm[j] = sms[j]; FJ.sq[j] = sqs[j]; FJ.base[j] = fb;
            FJ.invN[j] = 1.0f / (float)Ns[j];
            fb += B * Cns[j];
        }
        FJ.total = fb;
        hipLaunchKernelGGL(stat_partial_all, dim3(pb), dim3(256), 0, stream, SJ);
        hipLaunchKernelGGL(stat_finalize_all, dim3((fb + 255) / 256), dim3(256), 0, stream, FJ);
    }

    if (fast) {
        // arena sub-allocation per scale (same regions reused sequentially,
        // but pointers computed up-front for the fused prep)
        auto arenaFor = [&](size_t& o, size_t n) {
            ushort_t* p = arena + o; o += (n + 7) & ~(size_t)7; return p;
        };
        size_t o2 = 0;
        ushort_t* qh2 = arenaFor(o2, (size_t)B*4096*448);
        ushort_t* kh2 = arenaFor(o2, (size_t)B*4096*448);
        ushort_t* vh2 = arenaFor(o2, (size_t)B*4096*256);
        size_t o3 = 0;
        ushort_t* qh3 = arenaFor(o3, (size_t)B*1024*960);
        ushort_t* kh3 = arenaFor(o3, (size_t)B*1024*960);
        ushort_t* vh3 = arenaFor(o3, (size_t)B*1024*512);
        size_t o4 = 0;
        ushort_t* qh4 = arenaFor(o4, (size_t)B*256*1472);
        ushort_t* kh4 = arenaFor(o4, (size_t)B*256*1472);
        ushort_t* vh4 = arenaFor(o4, (size_t)B*256*512);

        // scale-3/4 prep outputs would overlap scale-2's region if packed at
        // arena base -> fuse all preps only when the workspace can hold all
        // three scales' fp16 tensors simultaneously; else prep per scale.
        size_t totShorts = o2 + o3 + o4;
        bool prepFused = (ws_size >= arenaOff * 2 + totShorts * 2);
        if (prepFused) {
            qh3 = arena + o2;        kh3 = qh3 + (((size_t)B*1024*960 + 7) & ~(size_t)7);
            vh3 = kh3 + (((size_t)B*1024*960 + 7) & ~(size_t)7);
            qh4 = arena + o2 + o3;   kh4 = qh4 + (((size_t)B*256*1472 + 7) & ~(size_t)7);
            vh4 = kh4 + (((size_t)B*256*1472 + 7) & ~(size_t)7);

            PrepJobs PJ;
            PJ.qx[0]=cc2; PJ.qm[0]=q2m; PJ.qr[0]=q2r; PJ.qh[0]=qh2;
            PJ.kx[0]=sc2; PJ.km[0]=k2m; PJ.kr[0]=k2r; PJ.kh[0]=kh2;
            PJ.vx[0]=s2v; PJ.vt[0]=vh2; PJ.N[0]=4096; PJ.Cc[0]=448; PJ.C[0]=256; PJ.KSEG[0]=512;
            PJ.qx[1]=cc3; PJ.qm[1]=q3m; PJ.qr[1]=q3r; PJ.qh[1]=qh3;
            PJ.kx[1]=sc3; PJ.km[1]=k3m; PJ.kr[1]=k3r; PJ.kh[1]=kh3;
            PJ.vx[1]=s3v; PJ.vt[1]=vh3; PJ.N[1]=1024; PJ.Cc[1]=960; PJ.C[1]=512; PJ.KSEG[1]=512;
            PJ.qx[2]=cc4; PJ.qm[2]=q4m; PJ.qr[2]=q4r; PJ.qh[2]=qh4;
            PJ.kx[2]=sc4; PJ.km[2]=k4m; PJ.kr[2]=k4r; PJ.kh[2]=kh4;
            PJ.vx[2]=s4v; PJ.vt[2]=vh4; PJ.N[2]=256;  PJ.Cc[2]=1472; PJ.C[2]=512; PJ.KSEG[2]=256;
            int g0n = 2*4096 + B*(256/64)*(4096/512);   // 8192 + 128
            int g1n = 2*1024 + B*(512/64)*(1024/512);   // 2048 + 64
            int g2n = 2*256  + B*(512/64)*(256/256);    // 512 + 32
            PJ.nbase[0] = 0; PJ.nbase[1] = g0n; PJ.nbase[2] = g0n + g1n;
            hipLaunchKernelGGL(prep_all, dim3(g0n + g1n + g2n), dim3(256), 0, stream, PJ);
        }

        // ---- scale 2 ----
        {
            if (!prepFused) {
                PrepJobs PJ;
                PJ.qx[0]=cc2; PJ.qm[0]=q2m; PJ.qr[0]=q2r; PJ.qh[0]=qh2;
                PJ.kx[0]=sc2; PJ.km[0]=k2m; PJ.kr[0]=k2r; PJ.kh[0]=kh2;
                PJ.vx[0]=s2v; PJ.vt[0]=vh2; PJ.N[0]=4096; PJ.Cc[0]=448; PJ.C[0]=256; PJ.KSEG[0]=512;
                for (int k = 1; k < 3; ++k) { PJ.N[k]=4096; PJ.Cc[k]=448; PJ.C[k]=256; PJ.KSEG[k]=512;
                    PJ.qx[k]=cc2; PJ.qm[k]=q2m; PJ.qr[k]=q2r; PJ.qh[k]=qh2;
                    PJ.kx[k]=sc2; PJ.km[k]=k2m; PJ.kr[k]=k2r; PJ.kh[k]=kh2;
                    PJ.vx[k]=s2v; PJ.vt[k]=vh2; }
                int gn = 2*4096 + B*(256/64)*(4096/512);
                PJ.nbase[0]=0; PJ.nbase[1]=gn; PJ.nbase[2]=gn;
                hipLaunchKernelGGL(prep_all, dim3(gn), dim3(256), 0, stream, PJ);
            }
            hipLaunchKernelGGL(flash_pipe, dim3(B*(4096/64)*2), dim3(256), 0, stream,
                               qh2, kh2, vh2, Pm, Pl, PM, PS);
            hipLaunchKernelGGL((combine_aat<256, 2>), dim3(B*4096/16), dim3(256), 0, stream,
                               Pm, Pl, PM, PS, c2, cs2, c2m, c2r, &lossp[0], 4096);
        }
        // ---- scale 3 ----
        {
            if (!prepFused) {
                PrepJobs PJ;
                PJ.qx[0]=cc3; PJ.qm[0]=q3m; PJ.qr[0]=q3r; PJ.qh[0]=qh3;
                PJ.kx[0]=sc3; PJ.km[0]=k3m; PJ.kr[0]=k3r; PJ.kh[0]=kh3;
                PJ.vx[0]=s3v; PJ.vt[0]=vh3; PJ.N[0]=1024; PJ.Cc[0]=960; PJ.C[0]=512; PJ.KSEG[0]=512;
                for (int k = 1; k < 3; ++k) { PJ.N[k]=1024; PJ.Cc[k]=960; PJ.C[k]=512; PJ.KSEG[k]=512;
                    PJ.qx[k]=cc3; PJ.qm[k]=q3m; PJ.qr[k]=q3r; PJ.qh[k]=qh3;
                    PJ.kx[k]=sc3; PJ.km[k]=k3m; PJ.kr[k]=k3r; PJ.kh[k]=kh3;
                    PJ.vx[k]=s3v; PJ.vt[k]=vh3; }
                int gn = 2*1024 + B*(512/64)*(1024/512);
                PJ.nbase[0]=0; PJ.nbase[1]=gn; PJ.nbase[2]=gn;
                hipLaunchKernelGGL(prep_all, dim3(gn), dim3(256), 0, stream, PJ);
            }
            hipLaunchKernelGGL((flash_mfma<960, 512, 1024, 2, false, 4, 4, 4>),
                               dim3(B*(1024/32)*4), dim3(256), 0, stream,
                               qh3, kh3, vh3, Pm, Pl, PM, PS);
            hipLaunchKernelGGL((combine_aat<512, 4>), dim3(B*1024/16), dim3(256), 0, stream,
                               Pm, Pl, PM, PS, c3, cs3, c3m, c3r, &lossp[1], 1024);
        }
        // ---- scale 4 ----
        {
            if (!prepFused) {
                PrepJobs PJ;
                PJ.qx[0]=cc4; PJ.qm[0]=q4m; PJ.qr[0]=q4r; PJ.qh[0]=qh4;
                PJ.kx[0]=sc4; PJ.km[0]=k4m; PJ.kr[0]=k4r; PJ.kh[0]=kh4;
                PJ.vx[0]=s4v; PJ.vt[0]=vh4; PJ.N[0]=256; PJ.Cc[0]=1472; PJ.C[0]=512; PJ.KSEG[0]=256;
                for (int k = 1; k < 3; ++k) { PJ.N[k]=256; PJ.Cc[k]=1472; PJ.C[k]=512; PJ.KSEG[k]=256;
                    PJ.qx[k]=cc4; PJ.qm[k]=q4m; PJ.qr[k]=q4r; PJ.qh[k]=qh4;
                    PJ.kx[k]=sc4; PJ.km[k]=k4m; PJ.kr[k]=k4r; PJ.kh[k]=kh4;
                    PJ.vx[k]=s4v; PJ.vt[k]=vh4; }
                int gn = 2*256 + B*(512/64)*(256/256);
                PJ.nbase[0]=0; PJ.nbase[1]=gn; PJ.nbase[2]=gn;
                hipLaunchKernelGGL(prep_all, dim3(gn), dim3(256), 0, stream, PJ);
            }
            hipLaunchKernelGGL((flash_mfma<1472, 512, 256, 4, false, 4, 4, 4>),
                               dim3(B*(256/16)*4), dim3(256), 0, stream,
                               qh4, kh4, vh4, Pm, Pl, PM, PS);
            hipLaunchKernelGGL((combine_aat<512, 4>), dim3(B*256/16), dim3(256), 0, stream,
                               Pm, Pl, PM, PS, c4, cs4, c4m, c4r, &lossp[2], 256);
        }
    } else {
        hipLaunchKernelGGL((flash_aat<7, 4, 4>), dim3(B * 4096 / 16), dim3(256), 0, stream,
                           cc2, sc2, s2v, c2, cs2, q2m, q2r, k2m, k2r, c2m, c2r, &lossp[0], 4096);
        hipLaunchKernelGGL((flash_aat<15, 8, 2>), dim3(B * 1024 / 8), dim3(256), 0, stream,
                           cc3, sc3, s3v, c3, cs3, q3m, q3r, k3m, k3r, c3m, c3r, &lossp[1], 1024);
        hipLaunchKernelGGL((flash_aat<23, 8, 2>), dim3(B * 256 / 8), dim3(256), 0, stream,
                           cc4, sc4, s4v, c4, cs4, q4m, q4r, k4m, k4r, c4m, c4r, &lossp[2], 256);
    }

    hipLaunchKernelGGL(combine_loss, dim3(1), dim3(1), 0, stream,
                       lossp, (float*)d_out,
                       1.0f / (4.0f * 4096.0f * 256.0f),
                       1.0f / (4.0f * 1024.0f * 512.0f),
                       1.0f / (4.0f * 256.0f * 512.0f));
}

// Round 5
// 682.143 us; speedup vs baseline: 2.3711x; 1.0543x over previous
//
#include <hip/hip_runtime.h>
#include <math.h>

#define EPS_NORM 1e-5f
#define EPS_VAR  1e-9f
#define LOG2E    1.4426950408889634f

typedef unsigned short ushort_t;
typedef __attribute__((ext_vector_type(4))) float f32x4;
typedef _Float16 half8 __attribute__((ext_vector_type(8)));

#define MFMAH(a, b, c) __builtin_amdgcn_mfma_f32_16x16x32_f16((a), (b), (c), 0, 0, 0)

// async global->LDS DMA, 16B per lane; LDS dest = wave-uniform base + lane*16
#define GLD16(gp, lp) __builtin_amdgcn_global_load_lds(                          \
    (const __attribute__((address_space(1))) unsigned int*)(gp),                 \
    (__attribute__((address_space(3))) unsigned int*)(lp), 16, 0, 0)

// ---------------------------------------------------------------------------
// fp16 helpers
// ---------------------------------------------------------------------------
__device__ inline ushort_t f16_bits(float x) {
    _Float16 h = (_Float16)x;
    ushort_t u;
    __builtin_memcpy(&u, &h, 2);
    return u;
}
__device__ inline half8 ldh(const ushort_t* p) {   // 16B-aligned load
    half8 h;
    __builtin_memcpy(&h, p, 16);
    return h;
}
__device__ inline uint4 pack8(const ushort_t* s) {
    uint4 r;
    r.x = (unsigned)s[0] | ((unsigned)s[1] << 16);
    r.y = (unsigned)s[2] | ((unsigned)s[3] << 16);
    r.z = (unsigned)s[4] | ((unsigned)s[5] << 16);
    r.w = (unsigned)s[6] | ((unsigned)s[7] << 16);
    return r;
}

// ---------------------------------------------------------------------------
// Fused stage-1 stats: all 9 tensors in one launch (job table)
// ---------------------------------------------------------------------------
struct StatJobs {
    const float* x[9];
    float* sm[9];
    float* sq[9];
    int N[9], Cn[9], chG[9], nG[9], base[9];
};
__global__ void __launch_bounds__(256) stat_partial_all(StatJobs J)
{
    int bx = blockIdx.x;
    int j = 0;
#pragma unroll
    for (int k = 1; k < 9; ++k) if (bx >= J.base[k]) j = k;
    bx -= J.base[j];
    const int N = J.N[j], Cn = J.Cn[j], chG = J.chG[j], nG = J.nG[j];
    int b  = bx / (chG * nG);
    int r  = bx % (chG * nG);
    int cg = r / nG;
    int ng = r % nG;
    int ch = cg * 256 + threadIdx.x;
    if (ch >= Cn) return;
    int n0 = ng * 256;
    int n1 = min(n0 + 256, N);
    const float* p = J.x[j] + (long)(b * N) * Cn + ch;
    float s = 0.f, ss = 0.f;
    for (int n = n0; n < n1; ++n) {
        float v = p[(long)n * Cn];
        s += v;
        ss = fmaf(v, v, ss);
    }
    atomicAdd(&J.sm[j][b * Cn + ch], s);
    atomicAdd(&J.sq[j][b * Cn + ch], ss);
}

struct FinJobs {
    float* sm[9];
    float* sq[9];
    int base[9];
    float invN[9];
    int total;
};
__global__ void __launch_bounds__(256) stat_finalize_all(FinJobs J)
{
    int i = blockIdx.x * 256 + threadIdx.x;
    if (i >= J.total) return;
    int j = 0;
#pragma unroll
    for (int k = 1; k < 9; ++k) if (i >= J.base[k]) j = k;
    int e = i - J.base[j];
    float m = J.sm[j][e] * J.invN[j];
    float v = J.sq[j][e] * J.invN[j] - m * m;
    J.sm[j][e] = m;
    J.sq[j][e] = rsqrtf(v + EPS_NORM);
}

// ---------------------------------------------------------------------------
// Fused prep for ALL scales in ONE launch.  Per scale:
//  - norm jobs: wave-per-row, float4 in / uint4 (8 fp16) out; Q scaled log2e
//  - V transpose -> (B,C,N) fp16 via LDS tile (coalesced reads AND writes)
// ---------------------------------------------------------------------------
struct PrepJobs {
    const float* qx[3]; const float* qm[3]; const float* qr[3]; ushort_t* qh[3];
    const float* kx[3]; const float* km[3]; const float* kr[3]; ushort_t* kh[3];
    const float* vx[3]; ushort_t* vt[3];
    int N[3], Cc[3], C[3], nbase[3];
};
__global__ void __launch_bounds__(256) prep_all(PrepJobs J)
{
    __shared__ __align__(16) ushort_t tbuf[64 * 72];
    int bx = blockIdx.x;
    int j = 0;
#pragma unroll
    for (int k = 1; k < 3; ++k) if (bx >= J.nbase[k]) j = k;
    bx -= J.nbase[j];
    const int N = J.N[j], Cc = J.Cc[j];
    const int normBlocks = 2 * N;             // (2*B*N)/4 rows-blocks, B=4
    if (bx < normBlocks) {
        const int wave = threadIdx.x >> 6, lane = threadIdx.x & 63;
        int rr = bx * 4 + wave;               // 0 .. 2*B*N-1
        const int BN = 4 * N;
        const bool isQ = rr < BN;
        int bn = isQ ? rr : rr - BN;
        const float* x    = isQ ? J.qx[j] : J.kx[j];
        const float* mean = isQ ? J.qm[j] : J.km[j];
        const float* rstd = isQ ? J.qr[j] : J.kr[j];
        ushort_t* out     = isQ ? J.qh[j] : J.kh[j];
        const float scl   = isQ ? LOG2E : 1.0f;
        int b = bn / N;
        long base = (long)bn * Cc;
        const float* mb = mean + b * Cc;
        const float* rb = rstd + b * Cc;
        for (int c8 = lane; c8 * 8 < Cc; c8 += 64) {
            int ch = c8 * 8;
            float4 a0 = *(const float4*)(x + base + ch);
            float4 a1 = *(const float4*)(x + base + ch + 4);
            float4 m0 = *(const float4*)(mb + ch);
            float4 m1 = *(const float4*)(mb + ch + 4);
            float4 r0 = *(const float4*)(rb + ch);
            float4 r1 = *(const float4*)(rb + ch + 4);
            ushort_t h8[8];
            h8[0] = f16_bits((a0.x - m0.x) * r0.x * scl);
            h8[1] = f16_bits((a0.y - m0.y) * r0.y * scl);
            h8[2] = f16_bits((a0.z - m0.z) * r0.z * scl);
            h8[3] = f16_bits((a0.w - m0.w) * r0.w * scl);
            h8[4] = f16_bits((a1.x - m1.x) * r1.x * scl);
            h8[5] = f16_bits((a1.y - m1.y) * r1.y * scl);
            h8[6] = f16_bits((a1.z - m1.z) * r1.z * scl);
            h8[7] = f16_bits((a1.w - m1.w) * r1.w * scl);
            *(uint4*)(out + base + ch) = pack8(h8);
        }
    } else {
        // V transpose: one 64ch x 64n tile per block, via LDS
        int bid2 = bx - normBlocks;
        const int C = J.C[j];
        const int cT = C >> 6, nT = N >> 6;
        int b   = bid2 / (cT * nT);
        int rem = bid2 % (cT * nT);
        int ch0 = (rem / nT) << 6;
        int n0  = (rem % nT) << 6;
        const int lane = threadIdx.x & 63, wv = threadIdx.x >> 6;
        const float* vb_ = J.vx[j] + (long)b * N * C + ch0 + lane;
        // phase 1: coalesced row reads, pack 8 n-values per thread, LDS write
#pragma unroll
        for (int jj = 0; jj < 2; ++jj) {
            int nl = wv * 16 + jj * 8;
            ushort_t h8[8];
#pragma unroll
            for (int i = 0; i < 8; ++i)
                h8[i] = f16_bits(vb_[(long)(n0 + nl + i) * C]);
            *(uint4*)&tbuf[lane * 72 + nl] = pack8(h8);
        }
        __syncthreads();
        // phase 2: coalesced global writes along n
        {
            const int chl = threadIdx.x >> 2;
            const int nq  = (threadIdx.x & 3) * 16;
            ushort_t* op = J.vt[j] + ((long)b * C + ch0 + chl) * N + n0 + nq;
            *(uint4*)op       = *(const uint4*)&tbuf[chl * 72 + nq];
            *(uint4*)(op + 8) = *(const uint4*)&tbuf[chl * 72 + nq + 8];
        }
    }
}

// ---------------------------------------------------------------------------
// Async DMA tile stagers (generic versions; used by flash_mfma).
// LDS tiles are 64 shorts/row, XOR-swizzled:
// LDS[r][g] (16B granule g of row r) holds global[r][g ^ (r&7)].
// ---------------------------------------------------------------------------
__device__ inline void stage64_async(const ushort_t* __restrict__ g, long rowBase,
                                     int gstride, int col0, ushort_t* slab, int tid)
{
    const int l  = tid & 63, w = tid >> 6;
    const int rs = l >> 3;
    const int cg = (l & 7) ^ rs;
#pragma unroll
    for (int i = 0; i < 2; ++i) {
        const int r = w * 16 + i * 8 + rs;
        const ushort_t* gp = g + (rowBase + r) * (long)gstride + col0 + (cg << 3);
        ushort_t* lp = slab + (w * 16 + i * 8) * 64 + l * 8;
        GLD16(gp, lp);
    }
}
template<int BROWS>
__device__ inline void stageQ_async(const ushort_t* __restrict__ g, long rowBase,
                                    int gstride, int col0, ushort_t* slab, int tid)
{
    if (tid < BROWS * 8) {
        const int l  = tid & 63, w = tid >> 6;
        const int rs = l >> 3;
        const int cg = (l & 7) ^ rs;
        const int r  = w * 8 + rs;
        const ushort_t* gp = g + (rowBase + r) * (long)gstride + col0 + (cg << 3);
        ushort_t* lp = slab + w * 8 * 64 + l * 8;
        GLD16(gp, lp);
    }
}
__device__ inline half8 ldsw(const ushort_t* slab, int row, int soff)
{
    const int gr = (soff >> 3) ^ (row & 7);
    return ldh(slab + row * 64 + (gr << 3));
}

// ---------------------------------------------------------------------------
// Pipelined flash for scale 2 (N=4096, Cc=448, C=256, QREG, SPLIT=2).
// 12-phase double-tile loop, ring of 4 pair-buffers, depth-2 prefetch,
// counted vmcnt.  XCD-aware block decode: the 8 (b,sp) K/V-sharing groups
// map to the 8 XCDs (blockIdx % 8 == XCD on MI355X) so each XCD's L2 holds
// exactly one K-half + V-half (~2.8 MB < 4 MB).
// ---------------------------------------------------------------------------
__global__ void __launch_bounds__(256, 2) flash_pipe(
    const ushort_t* __restrict__ Qh, const ushort_t* __restrict__ Kh,
    const ushort_t* __restrict__ Vth,
    float* __restrict__ Pmo, float* __restrict__ Plo,
    float* __restrict__ PMo, float* __restrict__ PSo)
{
    constexpr int Cc = 448, C = 256, N = 4096, SPLIT = 2;
    constexpr int NKT  = (N / 64) / SPLIT;     // 32 key tiles per block
    constexpr long VCHO = 64L * N;             // shorts per V chunk block
    constexpr long KADV = 64L * Cc;            // shorts per K tile advance

    __shared__ __align__(16) ushort_t smem[4 * 8192 + 4 * 1152];
    const int tid  = threadIdx.x;
    const int lane = tid & 63;
    const int w    = tid >> 6;
    const int l15  = lane & 15;
    const int quad = lane >> 4;

    // XCD-aware decode: (b,sp) from low 3 bits, qb from the rest
    const int grp = blockIdx.x & 7;
    const int sp  = grp & 1;
    const int b   = grp >> 1;
    const int qb  = (int)(blockIdx.x >> 3);
    const int i0 = qb * 64 + w * 16;
    const long po = (long)(b * (N / 16) + qb * 4 + w) * SPLIT + sp;

    // ---- hoisted per-lane constants ----
    const int rs    = lane >> 3;
    const int cg    = (lane & 7) ^ rs;
    const int ldso0 = w * 1024 + lane * 8;     // LDS dest, row block i=0
    const int ldso1 = ldso0 + 512;
    const int xh    = l15 & 7;
    const int lb0   = l15 * 64 + ((quad)     ^ xh) * 8;   // swizzled read, ks=0
    const int lb1   = l15 * 64 + ((4 + quad) ^ xh) * 8;   // ks=1
    ushort_t* const Pw  = smem + 32768 + w * 1152;
    ushort_t* const pww = Pw + quad * 288 + l15;          // P write base
    const ushort_t* const pfr = Pw + l15 * 72 + quad * 8; // P read base

    // staging base pointers (advance incrementally)
    const long krow0 = (long)b * N + (long)sp * NKT * 64;
    const ushort_t* kp0 = Kh + (krow0 + w * 16 + rs) * (long)Cc + (cg << 3);
    const ushort_t* kp1 = kp0 + 8 * Cc;
    const ushort_t* vp0 = Vth + ((long)b * C + w * 16 + rs) * (long)N
                              + (cg << 3) + (long)sp * NKT * 64;
    const ushort_t* vp1 = vp0 + 8 * (long)N;

#define SLOT(k) (smem + (k) * 8192)
#define STGKP(c0, c1, slot, toff) do {                                           \
    GLD16(kp0 + (toff) + (c0) * 64, SLOT(slot) + ldso0);                         \
    GLD16(kp1 + (toff) + (c0) * 64, SLOT(slot) + ldso1);                         \
    GLD16(kp0 + (toff) + (c1) * 64, SLOT(slot) + 4096 + ldso0);                  \
    GLD16(kp1 + (toff) + (c1) * 64, SLOT(slot) + 4096 + ldso1); } while (0)
#define STGK1(c0, slot, toff) do {                                               \
    GLD16(kp0 + (toff) + (c0) * 64, SLOT(slot) + ldso0);                         \
    GLD16(kp1 + (toff) + (c0) * 64, SLOT(slot) + ldso1); } while (0)
#define STGVP(j0, slot, voff) do {                                               \
    GLD16(vp0 + (voff) + (j0) * VCHO, SLOT(slot) + ldso0);                       \
    GLD16(vp1 + (voff) + (j0) * VCHO, SLOT(slot) + ldso1);                       \
    GLD16(vp0 + (voff) + ((j0) + 1) * VCHO, SLOT(slot) + 4096 + ldso0);          \
    GLD16(vp1 + (voff) + ((j0) + 1) * VCHO, SLOT(slot) + 4096 + ldso1); } while (0)

#define WAITV(NN) asm volatile("s_waitcnt vmcnt(" #NN ")" ::: "memory");         \
    __builtin_amdgcn_sched_barrier(0);                                           \
    __builtin_amdgcn_s_barrier();                                                \
    __builtin_amdgcn_s_setprio(1);
#define PH_END __builtin_amdgcn_s_setprio(0);

#define QKPAIR(slot, c0) do {                                                    \
    const ushort_t* s0_ = SLOT(slot);                                            \
    const ushort_t* s1_ = s0_ + 4096;                                            \
    _Pragma("unroll")                                                            \
    for (int ct = 0; ct < 4; ++ct) S[ct] = MFMAH(qf[2*(c0)+0], ldh(s0_ + ct*1024 + lb0), S[ct]); \
    _Pragma("unroll")                                                            \
    for (int ct = 0; ct < 4; ++ct) S[ct] = MFMAH(qf[2*(c0)+1], ldh(s0_ + ct*1024 + lb1), S[ct]); \
    _Pragma("unroll")                                                            \
    for (int ct = 0; ct < 4; ++ct) S[ct] = MFMAH(qf[2*(c0)+2], ldh(s1_ + ct*1024 + lb0), S[ct]); \
    _Pragma("unroll")                                                            \
    for (int ct = 0; ct < 4; ++ct) S[ct] = MFMAH(qf[2*(c0)+3], ldh(s1_ + ct*1024 + lb1), S[ct]); } while (0)
#define QK1(slot, c0) do {                                                       \
    const ushort_t* s0_ = SLOT(slot);                                            \
    _Pragma("unroll")                                                            \
    for (int ct = 0; ct < 4; ++ct) S[ct] = MFMAH(qf[2*(c0)+0], ldh(s0_ + ct*1024 + lb0), S[ct]); \
    _Pragma("unroll")                                                            \
    for (int ct = 0; ct < 4; ++ct) S[ct] = MFMAH(qf[2*(c0)+1], ldh(s0_ + ct*1024 + lb1), S[ct]); } while (0)
#define PVPAIR(slot, ci0) do {                                                   \
    const ushort_t* s0_ = SLOT(slot);                                            \
    const ushort_t* s1_ = s0_ + 4096;                                            \
    _Pragma("unroll")                                                            \
    for (int ct = 0; ct < 4; ++ct) {                                             \
        half8 vh = ldh(s0_ + ct*1024 + lb0); half8 uh = vh * vh;                 \
        Mac[(ci0)*4 + ct] = MFMAH(pf0, vh, Mac[(ci0)*4 + ct]);                   \
        Sac[(ci0)*4 + ct] = MFMAH(pf0, uh, Sac[(ci0)*4 + ct]); }                 \
    _Pragma("unroll")                                                            \
    for (int ct = 0; ct < 4; ++ct) {                                             \
        half8 vh = ldh(s0_ + ct*1024 + lb1); half8 uh = vh * vh;                 \
        Mac[(ci0)*4 + ct] = MFMAH(pf1, vh, Mac[(ci0)*4 + ct]);                   \
        Sac[(ci0)*4 + ct] = MFMAH(pf1, uh, Sac[(ci0)*4 + ct]); }                 \
    _Pragma("unroll")                                                            \
    for (int ct = 0; ct < 4; ++ct) {                                             \
        half8 vh = ldh(s1_ + ct*1024 + lb0); half8 uh = vh * vh;                 \
        Mac[(ci0+1)*4 + ct] = MFMAH(pf0, vh, Mac[(ci0+1)*4 + ct]);               \
        Sac[(ci0+1)*4 + ct] = MFMAH(pf0, uh, Sac[(ci0+1)*4 + ct]); }             \
    _Pragma("unroll")                                                            \
    for (int ct = 0; ct < 4; ++ct) {                                             \
        half8 vh = ldh(s1_ + ct*1024 + lb1); half8 uh = vh * vh;                 \
        Mac[(ci0+1)*4 + ct] = MFMAH(pf1, vh, Mac[(ci0+1)*4 + ct]);               \
        Sac[(ci0+1)*4 + ct] = MFMAH(pf1, uh, Sac[(ci0+1)*4 + ct]); } } while (0)
#define RESET_S do {                                                             \
    _Pragma("unroll")                                                            \
    for (int ct = 0; ct < 4; ++ct)                                               \
        _Pragma("unroll")                                                        \
        for (int r = 0; r < 4; ++r) S[ct][r] = 0.f; } while (0)

    half8 qf[14];
    {
        const ushort_t* q1 = Qh + ((long)(b * N + i0 + l15)) * Cc + quad * 8;
#pragma unroll
        for (int ks = 0; ks < 14; ++ks) qf[ks] = ldh(q1 + ks * 32);
    }
    asm volatile("s_waitcnt vmcnt(0)" ::: "memory");   // qf drained before DMA counting

    float m_r[4], l_l[4], mw = -1e30f;
    f32x4 Mac[16], Sac[16];
    f32x4 S[4];
    half8 pf0, pf1;
#pragma unroll
    for (int r = 0; r < 4; ++r) { m_r[r] = -1e30f; l_l[r] = 0.f; }
#pragma unroll
    for (int ct = 0; ct < 16; ++ct)
#pragma unroll
        for (int r = 0; r < 4; ++r) { Mac[ct][r] = 0.f; Sac[ct][r] = 0.f; }

    auto softmax_step = [&]() {
        float tmax = S[0][0];
#pragma unroll
        for (int ct = 0; ct < 4; ++ct)
#pragma unroll
            for (int r = 0; r < 4; ++r) tmax = fmaxf(tmax, S[ct][r]);
#pragma unroll
        for (int off = 1; off <= 32; off <<= 1)
            tmax = fmaxf(tmax, __shfl_xor(tmax, off, 64));

        if (tmax > mw + 14.4269504f) {
            float rm[4];
#pragma unroll
            for (int r = 0; r < 4; ++r)
                rm[r] = fmaxf(fmaxf(S[0][r], S[1][r]), fmaxf(S[2][r], S[3][r]));
#pragma unroll
            for (int off = 1; off <= 8; off <<= 1)
#pragma unroll
                for (int r = 0; r < 4; ++r)
                    rm[r] = fmaxf(rm[r], __shfl_xor(rm[r], off, 64));
#pragma unroll
            for (int r = 0; r < 4; ++r) {
                float mn = fmaxf(m_r[r], rm[r]);
                float corr = exp2f(m_r[r] - mn);
                m_r[r] = mn;
                l_l[r] *= corr;
#pragma unroll
                for (int ct = 0; ct < 16; ++ct) { Mac[ct][r] *= corr; Sac[ct][r] *= corr; }
            }
            float tt = fminf(fminf(m_r[0], m_r[1]), fminf(m_r[2], m_r[3]));
            tt = fminf(tt, __shfl_xor(tt, 16, 64));
            tt = fminf(tt, __shfl_xor(tt, 32, 64));
            mw = tt;
        }
#pragma unroll
        for (int ct = 0; ct < 4; ++ct)
#pragma unroll
            for (int r = 0; r < 4; ++r) {
                float p = exp2f(S[ct][r] - m_r[r]);
                l_l[r] += p;
                pww[r * 72 + ct * 16] = f16_bits(p);
            }
        pf0 = ldh(pfr);
        pf1 = ldh(pfr + 32);
    };

    // ---- prologue: pair0 -> slot0, pair1 -> slot1 (8 GLD outstanding) ----
    STGKP(0, 1, 0, 0);
    STGKP(2, 3, 1, 0);

    for (int it = 0; it < NKT / 2; ++it) {
        // ================= tile A =================
        RESET_S;
        // ph0: stage K4K5(A)->s2 | compute K0K1@s0
        STGKP(4, 5, 2, 0);
        WAITV(8)  QKPAIR(0, 0); PH_END;
        // ph1: stage K6(A)->s3 | compute K2K3@s1
        STGK1(6, 3, 0);
        WAITV(6)  QKPAIR(1, 2); PH_END;
        // ph2: stage V0V1(A)->s0 | compute K4K5@s2
        STGVP(0, 0, 0);
        WAITV(6)  QKPAIR(2, 4); PH_END;
        // ph3: stage V2V3(A)->s1 | compute K6@s3 + softmax
        STGVP(2, 1, 0);
        WAITV(8)  QK1(3, 6); PH_END;
        softmax_step();
        // ph4: stage K0K1(B)->s2 | compute PV V0V1@s0
        STGKP(0, 1, 2, KADV);
        WAITV(8)  PVPAIR(0, 0); PH_END;
        // ph5: stage K2K3(B)->s3 | compute PV V2V3@s1
        STGKP(2, 3, 3, KADV);
        WAITV(8)  PVPAIR(1, 2); PH_END;

        // ================= tile B =================
        RESET_S;
        // ph6: stage K4K5(B)->s0 | compute K0K1@s2
        STGKP(4, 5, 0, KADV);
        WAITV(8)  QKPAIR(2, 0); PH_END;
        // ph7: stage K6(B)->s1 | compute K2K3@s3
        STGK1(6, 1, KADV);
        WAITV(6)  QKPAIR(3, 2); PH_END;
        // ph8: stage V0V1(B)->s2 | compute K4K5@s0
        STGVP(0, 2, 64);
        WAITV(6)  QKPAIR(0, 4); PH_END;
        // ph9: stage V2V3(B)->s3 | compute K6@s1 + softmax
        STGVP(2, 3, 64);
        WAITV(8)  QK1(1, 6); PH_END;
        softmax_step();
        // ph10: stage K0K1(A')->s0 | compute PV V0V1@s2
        const bool more = (it + 1 < NKT / 2);
        if (more) {
            kp0 += 2 * KADV; kp1 += 2 * KADV;
            STGKP(0, 1, 0, 0);
            asm volatile("s_waitcnt vmcnt(8)" ::: "memory");
        } else {
            asm volatile("s_waitcnt vmcnt(4)" ::: "memory");
        }
        __builtin_amdgcn_sched_barrier(0);
        __builtin_amdgcn_s_barrier();
        __builtin_amdgcn_s_setprio(1);
        PVPAIR(2, 0);
        PH_END;
        // ph11: stage K2K3(A')->s1 | compute PV V2V3@s3
        if (more) {
            STGKP(2, 3, 1, 0);
            asm volatile("s_waitcnt vmcnt(8)" ::: "memory");
        } else {
            asm volatile("s_waitcnt vmcnt(0)" ::: "memory");
        }
        __builtin_amdgcn_sched_barrier(0);
        __builtin_amdgcn_s_barrier();
        __builtin_amdgcn_s_setprio(1);
        PVPAIR(3, 2);
        PH_END;

        vp0 += 128; vp1 += 128;
    }
#undef SLOT
#undef STGKP
#undef STGK1
#undef STGVP
#undef WAITV
#undef PH_END
#undef QKPAIR
#undef QK1
#undef PVPAIR
#undef RESET_S

    // ---- reduce per-lane l, dump partial state ----
#pragma unroll
    for (int off = 1; off <= 8; off <<= 1)
#pragma unroll
        for (int r = 0; r < 4; ++r) l_l[r] += __shfl_xor(l_l[r], off, 64);

    if (l15 == 0) {
#pragma unroll
        for (int r = 0; r < 4; ++r) {
            Pmo[po * 16 + quad * 4 + r] = m_r[r];
            Plo[po * 16 + quad * 4 + r] = l_l[r];
        }
    }
#pragma unroll
    for (int ct = 0; ct < 16; ++ct)
#pragma unroll
        for (int r = 0; r < 4; ++r) {
            long idx = (po * 16 + quad * 4 + r) * C + ct * 16 + l15;
            PMo[idx] = Mac[ct][r];
            PSo[idx] = Sac[ct][r];
        }
}

// ---------------------------------------------------------------------------
// Generic flash (scales 3/4): __syncthreads structure, async DMA staging,
// swizzled unpadded LDS slabs.  Softmax in log2 domain (Q pre-scaled).
// ---------------------------------------------------------------------------
template<int Cc, int C, int N, int CSPLIT, bool QREG, int SPLIT, int SLABS, int KGRP>
__global__ void __launch_bounds__(256, 2) flash_mfma(
    const ushort_t* __restrict__ Qh, const ushort_t* __restrict__ Kh,
    const ushort_t* __restrict__ Vth,
    float* __restrict__ Pmo, float* __restrict__ Plo,
    float* __restrict__ PMo, float* __restrict__ PSo)
{
    constexpr int KC      = Cc / 64;
    constexpr int VC      = C / 64;
    constexpr int VCW     = VC / CSPLIT;
    constexpr int CTCW    = 4 * VCW;
    constexpr int STRIPES = 4 / CSPLIT;
    constexpr int BROWS   = 16 * STRIPES;
    constexpr int QB      = N / BROWS;
    constexpr int TILES   = N / 64;
    constexpr int NKT     = TILES / SPLIT;
    constexpr int NKS     = QREG ? (Cc / 32) : 1;
    constexpr int NGRP    = (KC + KGRP - 1) / KGRP;
    constexpr int G       = 4 / CSPLIT;
    constexpr int QCH     = BROWS * 64;
    constexpr int QOFF    = KGRP * 4096;
    constexpr int KQEND   = QOFF + KGRP * QCH;
    constexpr int REGION  = QREG ? (SLABS * 4096)
                                 : (KQEND > SLABS * 4096 ? KQEND : SLABS * 4096);

    __shared__ __align__(16) ushort_t smem[REGION + 4 * 1152];
    const int tid  = threadIdx.x;
    const int lane = tid & 63;
    const int w    = tid >> 6;
    const int l15  = lane & 15;
    const int quad = lane >> 4;

    const int bq = blockIdx.x / SPLIT;
    const int sp = blockIdx.x % SPLIT;
    const int b  = bq / QB;
    const int qb = bq % QB;
    const int ls  = w / CSPLIT;
    const int ch2 = w % CSPLIT;
    const int i0 = qb * BROWS + ls * 16;
    const long po = (long)(b * (N / 16) + qb * STRIPES + ls) * SPLIT + sp;
    ushort_t* Pw = smem + REGION + w * 1152;

    half8 qf[NKS];
    if constexpr (QREG) {
        const ushort_t* q1 = Qh + ((long)(b * N + i0 + l15)) * Cc + quad * 8;
#pragma unroll
        for (int ks = 0; ks < NKS; ++ks) qf[ks] = ldh(q1 + ks * 32);
    }

    float m_r[4], l_l[4], mw = -1e30f;
    f32x4 Mac[CTCW], Sac[CTCW];
#pragma unroll
    for (int r = 0; r < 4; ++r) { m_r[r] = -1e30f; l_l[r] = 0.f; }
#pragma unroll
    for (int ct = 0; ct < CTCW; ++ct)
#pragma unroll
        for (int r = 0; r < 4; ++r) { Mac[ct][r] = 0.f; Sac[ct][r] = 0.f; }

    for (int kt = sp * NKT; kt < sp * NKT + NKT; ++kt) {
        const long krow = (long)b * N + kt * 64;

        f32x4 S[4];
#pragma unroll
        for (int ct = 0; ct < 4; ++ct)
#pragma unroll
            for (int r = 0; r < 4; ++r) S[ct][r] = 0.f;

        // ---- QK ----
#pragma unroll
        for (int grp = 0; grp < NGRP; ++grp) {
            const int g0 = grp * KGRP;
            const int gn = (KC - g0 < KGRP) ? (KC - g0) : KGRP;
            __syncthreads();
#pragma unroll
            for (int j = 0; j < KGRP; ++j) if (j < gn) {
                stage64_async(Kh, krow, Cc, (g0 + j) * 64, smem + j * 4096, tid);
                if constexpr (!QREG)
                    stageQ_async<BROWS>(Qh, (long)b * N + qb * BROWS, Cc, (g0 + j) * 64,
                                        smem + QOFF + j * QCH, tid);
            }
            __syncthreads();
#pragma unroll
            for (int j = 0; j < KGRP; ++j) if (j < gn) {
#pragma unroll
                for (int ks = 0; ks < 2; ++ks) {
                    half8 a;
                    if constexpr (QREG) a = qf[(g0 + j) * 2 + ks];
                    else a = ldsw(smem + QOFF + j * QCH, ls * 16 + l15, ks * 32 + quad * 8);
#pragma unroll
                    for (int ct = 0; ct < 4; ++ct) {
                        half8 bf = ldsw(smem + j * 4096, ct * 16 + l15, ks * 32 + quad * 8);
                        S[ct] = MFMAH(a, bf, S[ct]);
                    }
                }
            }
        }

        // ---- online softmax, lazy base (log2 domain) ----
        float tmax = S[0][0];
#pragma unroll
        for (int ct = 0; ct < 4; ++ct)
#pragma unroll
            for (int r = 0; r < 4; ++r) tmax = fmaxf(tmax, S[ct][r]);
#pragma unroll
        for (int off = 1; off <= 32; off <<= 1)
            tmax = fmaxf(tmax, __shfl_xor(tmax, off, 64));

        if (tmax > mw + 14.4269504f) {
            float rm[4];
#pragma unroll
            for (int r = 0; r < 4; ++r)
                rm[r] = fmaxf(fmaxf(S[0][r], S[1][r]), fmaxf(S[2][r], S[3][r]));
#pragma unroll
            for (int off = 1; off <= 8; off <<= 1)
#pragma unroll
                for (int r = 0; r < 4; ++r)
                    rm[r] = fmaxf(rm[r], __shfl_xor(rm[r], off, 64));
#pragma unroll
            for (int r = 0; r < 4; ++r) {
                float mn = fmaxf(m_r[r], rm[r]);
                float corr = exp2f(m_r[r] - mn);
                m_r[r] = mn;
                l_l[r] *= corr;
#pragma unroll
                for (int ct = 0; ct < CTCW; ++ct) { Mac[ct][r] *= corr; Sac[ct][r] *= corr; }
            }
            float t = fminf(fminf(m_r[0], m_r[1]), fminf(m_r[2], m_r[3]));
            t = fminf(t, __shfl_xor(t, 16, 64));
            t = fminf(t, __shfl_xor(t, 32, 64));
            mw = t;
        }

#pragma unroll
        for (int ct = 0; ct < 4; ++ct)
#pragma unroll
            for (int r = 0; r < 4; ++r) {
                float p = exp2f(S[ct][r] - m_r[r]);
                l_l[r] += p;
                Pw[(quad * 4 + r) * 72 + ct * 16 + l15] = f16_bits(p);
            }

        half8 pf0 = ldh(Pw + l15 * 72 + 0  + quad * 8);
        half8 pf1 = ldh(Pw + l15 * 72 + 32 + quad * 8);

        // ---- PV / PV^2 ----
#pragma unroll
        for (int g = 0; g < VCW; g += G) {
            __syncthreads();
#pragma unroll
            for (int s = 0; s < 4; ++s) {
                const int h = s / G, j = s % G;
                stage64_async(Vth, (long)b * C + (h * VCW + g + j) * 64, N, kt * 64,
                              smem + s * 4096, tid);
            }
            __syncthreads();
#pragma unroll
            for (int ks = 0; ks < 2; ++ks) {
                half8 pf = ks ? pf1 : pf0;
#pragma unroll
                for (int j = 0; j < G; ++j)
#pragma unroll
                    for (int ct = 0; ct < 4; ++ct) {
                        half8 vh = ldsw(smem + (ch2 * G + j) * 4096,
                                        ct * 16 + l15, ks * 32 + quad * 8);
                        half8 uh = vh * vh;
                        const int ci = (g + j) * 4 + ct;
                        Mac[ci] = MFMAH(pf, vh, Mac[ci]);
                        Sac[ci] = MFMAH(pf, uh, Sac[ci]);
                    }
            }
        }
    }

    // ---- reduce per-lane l, dump partial state ----
#pragma unroll
    for (int off = 1; off <= 8; off <<= 1)
#pragma unroll
        for (int r = 0; r < 4; ++r) l_l[r] += __shfl_xor(l_l[r], off, 64);

    if (ch2 == 0 && l15 == 0) {
#pragma unroll
        for (int r = 0; r < 4; ++r) {
            Pmo[po * 16 + quad * 4 + r] = m_r[r];
            Plo[po * 16 + quad * 4 + r] = l_l[r];
        }
    }
    const int chb = ch2 * (C / CSPLIT);
#pragma unroll
    for (int ct = 0; ct < CTCW; ++ct)
#pragma unroll
        for (int r = 0; r < 4; ++r) {
            long idx = (po * 16 + quad * 4 + r) * C + chb + ct * 16 + l15;
            PMo[idx] = Mac[ct][r];
            PSo[idx] = Sac[ct][r];
        }
}

// ---------------------------------------------------------------------------
// Combine: merge SPLIT flash partials (log2-domain m), float4 inner loop,
// fused epilogue + MSE.
// ---------------------------------------------------------------------------
template<int C, int SPLIT>
__global__ void __launch_bounds__(256) combine_aat(
    const float* __restrict__ Pm, const float* __restrict__ Pl,
    const float* __restrict__ PM, const float* __restrict__ PS,
    const float* __restrict__ CT, const float* __restrict__ CS,
    const float* __restrict__ cmean, const float* __restrict__ crstd,
    float* __restrict__ loss, int N)
{
    constexpr int CL4 = C / 4;
    __shared__ float wS[SPLIT][16];
    __shared__ float invL[16];
    __shared__ float red[4];
    const int pi = blockIdx.x;
    const int nb = N / 16;
    const int b  = pi / nb;
    const long g0 = (long)b * N + (long)(pi % nb) * 16;
    const int tid = threadIdx.x;

    if (tid < 16) {
        float m = -1e30f;
#pragma unroll
        for (int s = 0; s < SPLIT; ++s)
            m = fmaxf(m, Pm[((long)pi * SPLIT + s) * 16 + tid]);
        float L = 0.f;
#pragma unroll
        for (int s = 0; s < SPLIT; ++s) {
            float e = exp2f(Pm[((long)pi * SPLIT + s) * 16 + tid] - m);
            wS[s][tid] = e;
            L = fmaf(e, Pl[((long)pi * SPLIT + s) * 16 + tid], L);
        }
        invL[tid] = 1.f / L;
    }
    __syncthreads();

    float acc = 0.f;
    for (int v = tid; v < 4 * C; v += 256) {
        const int r  = v / CL4;
        const int c0 = (v - r * CL4) * 4;
        const long q0 = (((long)pi * SPLIT) * 16 + r) * C + c0;
        float4 Ms = {0.f, 0.f, 0.f, 0.f}, Ss = {0.f, 0.f, 0.f, 0.f};
#pragma unroll
        for (int s = 0; s < SPLIT; ++s) {
            const float ws_ = wS[s][r];
            const float4 pm = *(const float4*)&PM[q0 + (long)s * 16 * C];
            const float4 ps = *(const float4*)&PS[q0 + (long)s * 16 * C];
            Ms.x = fmaf(ws_, pm.x, Ms.x); Ms.y = fmaf(ws_, pm.y, Ms.y);
            Ms.z = fmaf(ws_, pm.z, Ms.z); Ms.w = fmaf(ws_, pm.w, Ms.w);
            Ss.x = fmaf(ws_, ps.x, Ss.x); Ss.y = fmaf(ws_, ps.y, Ss.y);
            Ss.z = fmaf(ws_, ps.z, Ss.z); Ss.w = fmaf(ws_, ps.w, Ss.w);
        }
        const float iL = invL[r];
        const float4 ctv = *(const float4*)&CT[(g0 + r) * C + c0];
        const float4 csv = *(const float4*)&CS[(g0 + r) * C + c0];
        const float4 cmv = *(const float4*)&cmean[b * C + c0];
        const float4 crv = *(const float4*)&crstd[b * C + c0];
#pragma unroll
        for (int e = 0; e < 4; ++e) {
            const float Msx = (&Ms.x)[e] * iL;
            const float S2  = (&Ss.x)[e] * iL - Msx * Msx;
            const float Sx  = sqrtf(fmaxf(S2, EPS_VAR));
            const float nc  = ((&ctv.x)[e] - (&cmv.x)[e]) * (&crv.x)[e];
            const float d   = (&csv.x)[e] - (Sx * nc + Msx);
            acc = fmaf(d, d, acc);
        }
    }
#pragma unroll
    for (int off = 1; off <= 32; off <<= 1) acc += __shfl_xor(acc, off, 64);
    if ((tid & 63) == 0) red[tid >> 6] = acc;
    __syncthreads();
    if (tid == 0) atomicAdd(loss, red[0] + red[1] + red[2] + red[3]);
}

// ---------------------------------------------------------------------------
// Fallback scalar flash kernel (only if ws_size too small)
// ---------------------------------------------------------------------------
template<int CCL, int CL, int NQ>
__global__ void __launch_bounds__(256) flash_aat(
    const float* __restrict__ Q, const float* __restrict__ K, const float* __restrict__ V,
    const float* __restrict__ CT, const float* __restrict__ CS,
    const float* __restrict__ qmean, const float* __restrict__ qrstd,
    const float* __restrict__ kmean, const float* __restrict__ krstd,
    const float* __restrict__ cmean, const float* __restrict__ crstd,
    float* __restrict__ loss, int N)
{
    constexpr int CC   = CCL * 64;
    constexpr int C    = CL * 64;
    constexpr int ROWS = 4 * NQ;
    const int lane = threadIdx.x & 63;
    const int wave = threadIdx.x >> 6;
    const int rowBlocks = N / ROWS;
    const int b  = blockIdx.x / rowBlocks;
    const int rb = blockIdx.x % rowBlocks;
    const int i0 = rb * ROWS + wave * NQ;

    float kmu[CCL], krs[CCL];
#pragma unroll
    for (int t = 0; t < CCL; ++t) {
        int ch = lane + 64 * t;
        kmu[t] = kmean[b * CC + ch];
        krs[t] = krstd[b * CC + ch];
    }
    float q[NQ][CCL];
#pragma unroll
    for (int qi = 0; qi < NQ; ++qi) {
        long base = (long)(b * N + i0 + qi) * CC;
#pragma unroll
        for (int t = 0; t < CCL; ++t) {
            int ch = lane + 64 * t;
            q[qi][t] = (Q[base + ch] - qmean[b * CC + ch]) * qrstd[b * CC + ch];
        }
    }
    float mval[NQ], lsum[NQ];
    float Macc[NQ][CL], Sacc[NQ][CL];
#pragma unroll
    for (int qi = 0; qi < NQ; ++qi) {
        mval[qi] = -1e30f; lsum[qi] = 0.f;
#pragma unroll
        for (int t = 0; t < CL; ++t) { Macc[qi][t] = 0.f; Sacc[qi][t] = 0.f; }
    }
    for (int j = 0; j < N; ++j) {
        long kb = (long)(b * N + j) * CC;
        float dot[NQ];
#pragma unroll
        for (int qi = 0; qi < NQ; ++qi) dot[qi] = 0.f;
#pragma unroll
        for (int t = 0; t < CCL; ++t) {
            float kv = (K[kb + lane + 64 * t] - kmu[t]) * krs[t];
#pragma unroll
            for (int qi = 0; qi < NQ; ++qi) dot[qi] = fmaf(q[qi][t], kv, dot[qi]);
        }
#pragma unroll
        for (int off = 32; off > 0; off >>= 1)
#pragma unroll
            for (int qi = 0; qi < NQ; ++qi) dot[qi] += __shfl_xor(dot[qi], off, 64);
        long vb = (long)(b * N + j) * C;
        float vv[CL];
#pragma unroll
        for (int t = 0; t < CL; ++t) vv[t] = V[vb + lane + 64 * t];
#pragma unroll
        for (int qi = 0; qi < NQ; ++qi) {
            float s = dot[qi];
            float p;
            if (s > mval[qi]) {
                float cr2 = __expf(mval[qi] - s);
                lsum[qi] *= cr2;
#pragma unroll
                for (int t = 0; t < CL; ++t) { Macc[qi][t] *= cr2; Sacc[qi][t] *= cr2; }
                mval[qi] = s; p = 1.f;
            } else p = __expf(s - mval[qi]);
            lsum[qi] += p;
#pragma unroll
            for (int t = 0; t < CL; ++t) {
                float pv = p * vv[t];
                Macc[qi][t] += pv;
                Sacc[qi][t] = fmaf(pv, vv[t], Sacc[qi][t]);
            }
        }
    }
    float acc = 0.f;
#pragma unroll
    for (int qi = 0; qi < NQ; ++qi) {
        float inv_l = 1.f / lsum[qi];
        long base = (long)(b * N + i0 + qi) * C;
#pragma unroll
        for (int t = 0; t < CL; ++t) {
            int ch = lane + 64 * t;
            float M  = Macc[qi][t] * inv_l;
            float S2 = Sacc[qi][t] * inv_l - M * M;
            float S  = sqrtf(fmaxf(S2, EPS_VAR));
            float nc = (CT[base + ch] - cmean[b * C + ch]) * crstd[b * C + ch];
            float d  = CS[base + ch] - (S * nc + M);
            acc = fmaf(d, d, acc);
        }
    }
#pragma unroll
    for (int off = 32; off > 0; off >>= 1) acc += __shfl_xor(acc, off, 64);
    if (lane == 0) atomicAdd(loss, acc);
}

__global__ void combine_loss(const float* __restrict__ lp, float* __restrict__ out,
                             float s0, float s1, float s2)
{
    out[0] = lp[0] * s0 + lp[1] * s1 + lp[2] * s2;
}

// ---------------------------------------------------------------------------
extern "C" void kernel_launch(void* const* d_in, const int* in_sizes, int n_in,
                              void* d_out, int out_size, void* d_ws, size_t ws_size,
                              hipStream_t stream)
{
    const float* cs2 = (const float*)d_in[0];
    const float* c2  = (const float*)d_in[1];
    const float* s2v = (const float*)d_in[2];
    const float* cc2 = (const float*)d_in[3];
    const float* sc2 = (const float*)d_in[4];
    const float* cs3 = (const float*)d_in[5];
    const float* c3  = (const float*)d_in[6];
    const float* s3v = (const float*)d_in[7];
    const float* cc3 = (const float*)d_in[8];
    const float* sc3 = (const float*)d_in[9];
    const float* cs4 = (const float*)d_in[10];
    const float* c4  = (const float*)d_in[11];
    const float* s4v = (const float*)d_in[12];
    const float* cc4 = (const float*)d_in[13];
    const float* sc4 = (const float*)d_in[14];

    const int B = 4;
    float* ws = (float*)d_ws;
    size_t fo = 0;
    auto allocF = [&](size_t n) { float* p = ws + fo; fo += n; return p; };

    float* lossp = allocF(4);
    float* c2m = allocF(B * 256);  float* c2r = allocF(B * 256);
    float* q2m = allocF(B * 448);  float* q2r = allocF(B * 448);
    float* k2m = allocF(B * 448);  float* k2r = allocF(B * 448);
    float* c3m = allocF(B * 512);  float* c3r = allocF(B * 512);
    float* q3m = allocF(B * 960);  float* q3r = allocF(B * 960);
    float* k3m = allocF(B * 960);  float* k3r = allocF(B * 960);
    float* c4m = allocF(B * 512);  float* c4r = allocF(B * 512);
    float* q4m = allocF(B * 1472); float* q4r = allocF(B * 1472);
    float* k4m = allocF(B * 1472); float* k4r = allocF(B * 1472);
    size_t zeroBytes = fo * sizeof(float);

    // partial-state buffers (shared across scales; stream-ordered reuse)
    float* Pm = allocF(32768);
    float* Pl = allocF(32768);
    float* PM = allocF(8388608);
    float* PS = allocF(8388608);

    // fp16 arena (16B aligned), reused per scale
    size_t arenaOff = ((fo * 4 + 15) & ~(size_t)15) / 2;
    ushort_t* arena = (ushort_t*)d_ws + arenaOff;
    const size_t arenaShorts = 18874400;   // max per-scale need (scale 2)
    size_t need = arenaOff * 2 + arenaShorts * 2;
    const bool fast = (ws_size >= need);

    hipMemsetAsync(d_ws, 0, zeroBytes, stream);

    // ---- fused stats (2 launches for all 9 tensors) ----
    {
        StatJobs SJ; FinJobs FJ;
        const float* xs[9] = {c2, cc2, sc2, c3, cc3, sc3, c4, cc4, sc4};
        float* sms[9] = {c2m, q2m, k2m, c3m, q3m, k3m, c4m, q4m, k4m};
        float* sqs[9] = {c2r, q2r, k2r, c3r, q3r, k3r, c4r, q4r, k4r};
        const int Ns[9]  = {4096, 4096, 4096, 1024, 1024, 1024, 256, 256, 256};
        const int Cns[9] = {256, 448, 448, 512, 960, 960, 512, 1472, 1472};
        int pb = 0, fb = 0;
        for (int j = 0; j < 9; ++j) {
            int chG = (Cns[j] + 255) / 256;
            int nG  = (Ns[j] + 255) / 256;
            SJ.x[j] = xs[j]; SJ.sm[j] = sms[j]; SJ.sq[j] = sqs[j];
            SJ.N[j] = Ns[j]; SJ.Cn[j] = Cns[j]; SJ.chG[j] = chG; SJ.nG[j] = nG;
            SJ.base[j] = pb;
            pb += B * chG * nG;
            FJ.sm[j] = sms[j]; FJ.sq[j] = sqs[j]; FJ.base[j] = fb;
            FJ.invN[j] = 1.0f / (float)Ns[j];
            fb += B * Cns[j];
        }
        FJ.total = fb;
        hipLaunchKernelGGL(stat_partial_all, dim3(pb), dim3(256), 0, stream, SJ);
        hipLaunchKernelGGL(stat_finalize_all, dim3((fb + 255) / 256), dim3(256), 0, stream, FJ);
    }

    if (fast) {
        auto arenaFor = [&](size_t& o, size_t n) {
            ushort_t* p = arena + o; o += (n + 7) & ~(size_t)7; return p;
        };
        size_t o2 = 0;
        ushort_t* qh2 = arenaFor(o2, (size_t)B*4096*448);
        ushort_t* kh2 = arenaFor(o2, (size_t)B*4096*448);
        ushort_t* vh2 = arenaFor(o2, (size_t)B*4096*256);
        size_t o3 = 0;
        ushort_t* qh3 = arenaFor(o3, (size_t)B*1024*960);
        ushort_t* kh3 = arenaFor(o3, (size_t)B*1024*960);
        ushort_t* vh3 = arenaFor(o3, (size_t)B*1024*512);
        size_t o4 = 0;
        ushort_t* qh4 = arenaFor(o4, (size_t)B*256*1472);
        ushort_t* kh4 = arenaFor(o4, (size_t)B*256*1472);
        ushort_t* vh4 = arenaFor(o4, (size_t)B*256*512);

        // V-tile block counts per scale: (C/64)*(N/64)*B
        const int vt2 = (256/64)*(4096/64)*B;   // 1024
        const int vt3 = (512/64)*(1024/64)*B;   // 512
        const int vt4 = (512/64)*(256/64)*B;    // 128

        size_t totShorts = o2 + o3 + o4;
        bool prepFused = (ws_size >= arenaOff * 2 + totShorts * 2);
        if (prepFused) {
            qh3 = arena + o2;        kh3 = qh3 + (((size_t)B*1024*960 + 7) & ~(size_t)7);
            vh3 = kh3 + (((size_t)B*1024*960 + 7) & ~(size_t)7);
            qh4 = arena + o2 + o3;   kh4 = qh4 + (((size_t)B*256*1472 + 7) & ~(size_t)7);
            vh4 = kh4 + (((size_t)B*256*1472 + 7) & ~(size_t)7);

            PrepJobs PJ;
            PJ.qx[0]=cc2; PJ.qm[0]=q2m; PJ.qr[0]=q2r; PJ.qh[0]=qh2;
            PJ.kx[0]=sc2; PJ.km[0]=k2m; PJ.kr[0]=k2r; PJ.kh[0]=kh2;
            PJ.vx[0]=s2v; PJ.vt[0]=vh2; PJ.N[0]=4096; PJ.Cc[0]=448; PJ.C[0]=256;
            PJ.qx[1]=cc3; PJ.qm[1]=q3m; PJ.qr[1]=q3r; PJ.qh[1]=qh3;
            PJ.kx[1]=sc3; PJ.km[1]=k3m; PJ.kr[1]=k3r; PJ.kh[1]=kh3;
            PJ.vx[1]=s3v; PJ.vt[1]=vh3; PJ.N[1]=1024; PJ.Cc[1]=960; PJ.C[1]=512;
            PJ.qx[2]=cc4; PJ.qm[2]=q4m; PJ.qr[2]=q4r; PJ.qh[2]=qh4;
            PJ.kx[2]=sc4; PJ.km[2]=k4m; PJ.kr[2]=k4r; PJ.kh[2]=kh4;
            PJ.vx[2]=s4v; PJ.vt[2]=vh4; PJ.N[2]=256;  PJ.Cc[2]=1472; PJ.C[2]=512;
            int g0n = 2*4096 + vt2;
            int g1n = 2*1024 + vt3;
            int g2n = 2*256  + vt4;
            PJ.nbase[0] = 0; PJ.nbase[1] = g0n; PJ.nbase[2] = g0n + g1n;
            hipLaunchKernelGGL(prep_all, dim3(g0n + g1n + g2n), dim3(256), 0, stream, PJ);
        }

        // ---- scale 2 ----
        {
            if (!prepFused) {
                PrepJobs PJ;
                PJ.qx[0]=cc2; PJ.qm[0]=q2m; PJ.qr[0]=q2r; PJ.qh[0]=qh2;
                PJ.kx[0]=sc2; PJ.km[0]=k2m; PJ.kr[0]=k2r; PJ.kh[0]=kh2;
                PJ.vx[0]=s2v; PJ.vt[0]=vh2; PJ.N[0]=4096; PJ.Cc[0]=448; PJ.C[0]=256;
                for (int k = 1; k < 3; ++k) { PJ.N[k]=4096; PJ.Cc[k]=448; PJ.C[k]=256;
                    PJ.qx[k]=cc2; PJ.qm[k]=q2m; PJ.qr[k]=q2r; PJ.qh[k]=qh2;
                    PJ.kx[k]=sc2; PJ.km[k]=k2m; PJ.kr[k]=k2r; PJ.kh[k]=kh2;
                    PJ.vx[k]=s2v; PJ.vt[k]=vh2; }
                int gn = 2*4096 + vt2;
                PJ.nbase[0]=0; PJ.nbase[1]=gn; PJ.nbase[2]=gn;
                hipLaunchKernelGGL(prep_all, dim3(gn), dim3(256), 0, stream, PJ);
            }
            hipLaunchKernelGGL(flash_pipe, dim3(B*(4096/64)*2), dim3(256), 0, stream,
                               qh2, kh2, vh2, Pm, Pl, PM, PS);
            hipLaunchKernelGGL((combine_aat<256, 2>), dim3(B*4096/16), dim3(256), 0, stream,
                               Pm, Pl, PM, PS, c2, cs2, c2m, c2r, &lossp[0], 4096);
        }
        // ---- scale 3 ----
        {
            if (!prepFused) {
                PrepJobs PJ;
                PJ.qx[0]=cc3; PJ.qm[0]=q3m; PJ.qr[0]=q3r; PJ.qh[0]=qh3;
                PJ.kx[0]=sc3; PJ.km[0]=k3m; PJ.kr[0]=k3r; PJ.kh[0]=kh3;
                PJ.vx[0]=s3v; PJ.vt[0]=vh3; PJ.N[0]=1024; PJ.Cc[0]=960; PJ.C[0]=512;
                for (int k = 1; k < 3; ++k) { PJ.N[k]=1024; PJ.Cc[k]=960; PJ.C[k]=512;
                    PJ.qx[k]=cc3; PJ.qm[k]=q3m; PJ.qr[k]=q3r; PJ.qh[k]=qh3;
                    PJ.kx[k]=sc3; PJ.km[k]=k3m; PJ.kr[k]=k3r; PJ.kh[k]=kh3;
                    PJ.vx[k]=s3v; PJ.vt[k]=vh3; }
                int gn = 2*1024 + vt3;
                PJ.nbase[0]=0; PJ.nbase[1]=gn; PJ.nbase[2]=gn;
                hipLaunchKernelGGL(prep_all, dim3(gn), dim3(256), 0, stream, PJ);
            }
            hipLaunchKernelGGL((flash_mfma<960, 512, 1024, 2, false, 4, 5, 5>),
                               dim3(B*(1024/32)*4), dim3(256), 0, stream,
                               qh3, kh3, vh3, Pm, Pl, PM, PS);
            hipLaunchKernelGGL((combine_aat<512, 4>), dim3(B*1024/16), dim3(256), 0, stream,
                               Pm, Pl, PM, PS, c3, cs3, c3m, c3r, &lossp[1], 1024);
        }
        // ---- scale 4 ----
        {
            if (!prepFused) {
                PrepJobs PJ;
                PJ.qx[0]=cc4; PJ.qm[0]=q4m; PJ.qr[0]=q4r; PJ.qh[0]=qh4;
                PJ.kx[0]=sc4; PJ.km[0]=k4m; PJ.kr[0]=k4r; PJ.kh[0]=kh4;
                PJ.vx[0]=s4v; PJ.vt[0]=vh4; PJ.N[0]=256; PJ.Cc[0]=1472; PJ.C[0]=512;
                for (int k = 1; k < 3; ++k) { PJ.N[k]=256; PJ.Cc[k]=1472; PJ.C[k]=512;
                    PJ.qx[k]=cc4; PJ.qm[k]=q4m; PJ.qr[k]=q4r; PJ.qh[k]=qh4;
                    PJ.kx[k]=sc4; PJ.km[k]=k4m; PJ.kr[k]=k4r; PJ.kh[k]=kh4;
                    PJ.vx[k]=s4v; PJ.vt[k]=vh4; }
                int gn = 2*256 + vt4;
                PJ.nbase[0]=0; PJ.nbase[1]=gn; PJ.nbase[2]=gn;
                hipLaunchKernelGGL(prep_all, dim3(gn), dim3(256), 0, stream, PJ);
            }
            hipLaunchKernelGGL((flash_mfma<1472, 512, 256, 4, false, 4, 6, 6>),
                               dim3(B*(256/16)*4), dim3(256), 0, stream,
                               qh4, kh4, vh4, Pm, Pl, PM, PS);
            hipLaunchKernelGGL((combine_aat<512, 4>), dim3(B*256/16), dim3(256), 0, stream,
                               Pm, Pl, PM, PS, c4, cs4, c4m, c4r, &lossp[2], 256);
        }
    } else {
        hipLaunchKernelGGL((flash_aat<7, 4, 4>), dim3(B * 4096 / 16), dim3(256), 0, stream,
                           cc2, sc2, s2v, c2, cs2, q2m, q2r, k2m, k2r, c2m, c2r, &lossp[0], 4096);
        hipLaunchKernelGGL((flash_aat<15, 8, 2>), dim3(B * 1024 / 8), dim3(256), 0, stream,
                           cc3, sc3, s3v, c3, cs3, q3m, q3r, k3m, k3r, c3m, c3r, &lossp[1], 1024);
        hipLaunchKernelGGL((flash_aat<23, 8, 2>), dim3(B * 256 / 8), dim3(256), 0, stream,
                           cc4, sc4, s4v, c4, cs4, q4m, q4r, k4m, k4r, c4m, c4r, &lossp[2], 256);
    }

    hipLaunchKernelGGL(combine_loss, dim3(1), dim3(1), 0, stream,
                       lossp, (float*)d_out,
                       1.0f / (4.0f * 4096.0f * 256.0f),
                       1.0f / (4.0f * 1024.0f * 512.0f),
                       1.0f / (4.0f * 256.0f * 512.0f));
}

// Round 6
// 672.406 us; speedup vs baseline: 2.4054x; 1.0145x over previous
//
#include <hip/hip_runtime.h>
#include <math.h>

#define EPS_NORM 1e-5f
#define EPS_VAR  1e-9f
#define LOG2E    1.4426950408889634f

typedef unsigned short ushort_t;
typedef __attribute__((ext_vector_type(4))) float f32x4;
typedef _Float16 half8 __attribute__((ext_vector_type(8)));

#define MFMAH(a, b, c) __builtin_amdgcn_mfma_f32_16x16x32_f16((a), (b), (c), 0, 0, 0)

// async global->LDS DMA, 16B per lane; LDS dest = wave-uniform base + lane*16
#define GLD16(gp, lp) __builtin_amdgcn_global_load_lds(                          \
    (const __attribute__((address_space(1))) unsigned int*)(gp),                 \
    (__attribute__((address_space(3))) unsigned int*)(lp), 16, 0, 0)

// ---------------------------------------------------------------------------
// fp16 helpers
// ---------------------------------------------------------------------------
__device__ inline ushort_t f16_bits(float x) {
    _Float16 h = (_Float16)x;
    ushort_t u;
    __builtin_memcpy(&u, &h, 2);
    return u;
}
__device__ inline half8 ldh(const ushort_t* p) {   // 16B-aligned load
    half8 h;
    __builtin_memcpy(&h, p, 16);
    return h;
}
__device__ inline uint4 pack8(const ushort_t* s) {
    uint4 r;
    r.x = (unsigned)s[0] | ((unsigned)s[1] << 16);
    r.y = (unsigned)s[2] | ((unsigned)s[3] << 16);
    r.z = (unsigned)s[4] | ((unsigned)s[5] << 16);
    r.w = (unsigned)s[6] | ((unsigned)s[7] << 16);
    return r;
}

// ---------------------------------------------------------------------------
// Fused stage-1 stats: all 9 tensors in one launch (job table)
// ---------------------------------------------------------------------------
struct StatJobs {
    const float* x[9];
    float* sm[9];
    float* sq[9];
    int N[9], Cn[9], chG[9], nG[9], base[9];
};
__global__ void __launch_bounds__(256) stat_partial_all(StatJobs J)
{
    int bx = blockIdx.x;
    int j = 0;
#pragma unroll
    for (int k = 1; k < 9; ++k) if (bx >= J.base[k]) j = k;
    bx -= J.base[j];
    const int N = J.N[j], Cn = J.Cn[j], chG = J.chG[j], nG = J.nG[j];
    int b  = bx / (chG * nG);
    int r  = bx % (chG * nG);
    int cg = r / nG;
    int ng = r % nG;
    int ch = cg * 256 + threadIdx.x;
    if (ch >= Cn) return;
    int n0 = ng * 256;
    int n1 = min(n0 + 256, N);
    const float* p = J.x[j] + (long)(b * N) * Cn + ch;
    float s = 0.f, ss = 0.f;
    for (int n = n0; n < n1; ++n) {
        float v = p[(long)n * Cn];
        s += v;
        ss = fmaf(v, v, ss);
    }
    atomicAdd(&J.sm[j][b * Cn + ch], s);
    atomicAdd(&J.sq[j][b * Cn + ch], ss);
}

struct FinJobs {
    float* sm[9];
    float* sq[9];
    int base[9];
    float invN[9];
    int total;
};
__global__ void __launch_bounds__(256) stat_finalize_all(FinJobs J)
{
    int i = blockIdx.x * 256 + threadIdx.x;
    if (i >= J.total) return;
    int j = 0;
#pragma unroll
    for (int k = 1; k < 9; ++k) if (i >= J.base[k]) j = k;
    int e = i - J.base[j];
    float m = J.sm[j][e] * J.invN[j];
    float v = J.sq[j][e] * J.invN[j] - m * m;
    J.sm[j][e] = m;
    J.sq[j][e] = rsqrtf(v + EPS_NORM);
}

// ---------------------------------------------------------------------------
// Fused prep for ALL scales in ONE launch.  Per scale:
//  - norm jobs: wave-per-row, float4 in / uint4 (8 fp16) out; Q scaled log2e
//  - V transpose -> (B,C,N) fp16 via LDS tile (coalesced reads AND writes)
// ---------------------------------------------------------------------------
struct PrepJobs {
    const float* qx[3]; const float* qm[3]; const float* qr[3]; ushort_t* qh[3];
    const float* kx[3]; const float* km[3]; const float* kr[3]; ushort_t* kh[3];
    const float* vx[3]; ushort_t* vt[3];
    int N[3], Cc[3], C[3], nbase[3];
};
__global__ void __launch_bounds__(256) prep_all(PrepJobs J)
{
    __shared__ __align__(16) ushort_t tbuf[64 * 72];
    int bx = blockIdx.x;
    int j = 0;
#pragma unroll
    for (int k = 1; k < 3; ++k) if (bx >= J.nbase[k]) j = k;
    bx -= J.nbase[j];
    const int N = J.N[j], Cc = J.Cc[j];
    const int normBlocks = 2 * N;             // (2*B*N)/4 rows-blocks, B=4
    if (bx < normBlocks) {
        const int wave = threadIdx.x >> 6, lane = threadIdx.x & 63;
        int rr = bx * 4 + wave;               // 0 .. 2*B*N-1
        const int BN = 4 * N;
        const bool isQ = rr < BN;
        int bn = isQ ? rr : rr - BN;
        const float* x    = isQ ? J.qx[j] : J.kx[j];
        const float* mean = isQ ? J.qm[j] : J.km[j];
        const float* rstd = isQ ? J.qr[j] : J.kr[j];
        ushort_t* out     = isQ ? J.qh[j] : J.kh[j];
        const float scl   = isQ ? LOG2E : 1.0f;
        int b = bn / N;
        long base = (long)bn * Cc;
        const float* mb = mean + b * Cc;
        const float* rb = rstd + b * Cc;
        for (int c8 = lane; c8 * 8 < Cc; c8 += 64) {
            int ch = c8 * 8;
            float4 a0 = *(const float4*)(x + base + ch);
            float4 a1 = *(const float4*)(x + base + ch + 4);
            float4 m0 = *(const float4*)(mb + ch);
            float4 m1 = *(const float4*)(mb + ch + 4);
            float4 r0 = *(const float4*)(rb + ch);
            float4 r1 = *(const float4*)(rb + ch + 4);
            ushort_t h8[8];
            h8[0] = f16_bits((a0.x - m0.x) * r0.x * scl);
            h8[1] = f16_bits((a0.y - m0.y) * r0.y * scl);
            h8[2] = f16_bits((a0.z - m0.z) * r0.z * scl);
            h8[3] = f16_bits((a0.w - m0.w) * r0.w * scl);
            h8[4] = f16_bits((a1.x - m1.x) * r1.x * scl);
            h8[5] = f16_bits((a1.y - m1.y) * r1.y * scl);
            h8[6] = f16_bits((a1.z - m1.z) * r1.z * scl);
            h8[7] = f16_bits((a1.w - m1.w) * r1.w * scl);
            *(uint4*)(out + base + ch) = pack8(h8);
        }
    } else {
        // V transpose: one 64ch x 64n tile per block, via LDS
        int bid2 = bx - normBlocks;
        const int C = J.C[j];
        const int cT = C >> 6, nT = N >> 6;
        int b   = bid2 / (cT * nT);
        int rem = bid2 % (cT * nT);
        int ch0 = (rem / nT) << 6;
        int n0  = (rem % nT) << 6;
        const int lane = threadIdx.x & 63, wv = threadIdx.x >> 6;
        const float* vb_ = J.vx[j] + (long)b * N * C + ch0 + lane;
#pragma unroll
        for (int jj = 0; jj < 2; ++jj) {
            int nl = wv * 16 + jj * 8;
            ushort_t h8[8];
#pragma unroll
            for (int i = 0; i < 8; ++i)
                h8[i] = f16_bits(vb_[(long)(n0 + nl + i) * C]);
            *(uint4*)&tbuf[lane * 72 + nl] = pack8(h8);
        }
        __syncthreads();
        {
            const int chl = threadIdx.x >> 2;
            const int nq  = (threadIdx.x & 3) * 16;
            ushort_t* op = J.vt[j] + ((long)b * C + ch0 + chl) * N + n0 + nq;
            *(uint4*)op       = *(const uint4*)&tbuf[chl * 72 + nq];
            *(uint4*)(op + 8) = *(const uint4*)&tbuf[chl * 72 + nq + 8];
        }
    }
}

// ---------------------------------------------------------------------------
// Async DMA tile stagers.  LDS tiles 64 shorts/row, XOR-swizzled.
// ---------------------------------------------------------------------------
__device__ inline void stage64_async(const ushort_t* __restrict__ g, long rowBase,
                                     int gstride, int col0, ushort_t* slab, int tid)
{
    const int l  = tid & 63, w = tid >> 6;
    const int rs = l >> 3;
    const int cg = (l & 7) ^ rs;
#pragma unroll
    for (int i = 0; i < 2; ++i) {
        const int r = w * 16 + i * 8 + rs;
        const ushort_t* gp = g + (rowBase + r) * (long)gstride + col0 + (cg << 3);
        ushort_t* lp = slab + (w * 16 + i * 8) * 64 + l * 8;
        GLD16(gp, lp);
    }
}
template<int BROWS>
__device__ inline void stageQ_async(const ushort_t* __restrict__ g, long rowBase,
                                    int gstride, int col0, ushort_t* slab, int tid)
{
    if (tid < BROWS * 8) {
        const int l  = tid & 63, w = tid >> 6;
        const int rs = l >> 3;
        const int cg = (l & 7) ^ rs;
        const int r  = w * 8 + rs;
        const ushort_t* gp = g + (rowBase + r) * (long)gstride + col0 + (cg << 3);
        ushort_t* lp = slab + w * 8 * 64 + l * 8;
        GLD16(gp, lp);
    }
}
__device__ inline half8 ldsw(const ushort_t* slab, int row, int soff)
{
    const int gr = (soff >> 3) ^ (row & 7);
    return ldh(slab + row * 64 + (gr << 3));
}

// ---------------------------------------------------------------------------
// Pipelined flash for scale 2 (unchanged from round 5 — proven 243 us;
// structurally register-bound at 2 waves/SIMD).
// ---------------------------------------------------------------------------
__global__ void __launch_bounds__(256, 2) flash_pipe(
    const ushort_t* __restrict__ Qh, const ushort_t* __restrict__ Kh,
    const ushort_t* __restrict__ Vth,
    float* __restrict__ Pmo, float* __restrict__ Plo,
    float* __restrict__ PMo, float* __restrict__ PSo)
{
    constexpr int Cc = 448, C = 256, N = 4096, SPLIT = 2;
    constexpr int NKT  = (N / 64) / SPLIT;
    constexpr long VCHO = 64L * N;
    constexpr long KADV = 64L * Cc;

    __shared__ __align__(16) ushort_t smem[4 * 8192 + 4 * 1152];
    const int tid  = threadIdx.x;
    const int lane = tid & 63;
    const int w    = tid >> 6;
    const int l15  = lane & 15;
    const int quad = lane >> 4;

    const int grp = blockIdx.x & 7;
    const int sp  = grp & 1;
    const int b   = grp >> 1;
    const int qb  = (int)(blockIdx.x >> 3);
    const int i0 = qb * 64 + w * 16;
    const long po = (long)(b * (N / 16) + qb * 4 + w) * SPLIT + sp;

    const int rs    = lane >> 3;
    const int cg    = (lane & 7) ^ rs;
    const int ldso0 = w * 1024 + lane * 8;
    const int ldso1 = ldso0 + 512;
    const int xh    = l15 & 7;
    const int lb0   = l15 * 64 + ((quad)     ^ xh) * 8;
    const int lb1   = l15 * 64 + ((4 + quad) ^ xh) * 8;
    ushort_t* const Pw  = smem + 32768 + w * 1152;
    ushort_t* const pww = Pw + quad * 288 + l15;
    const ushort_t* const pfr = Pw + l15 * 72 + quad * 8;

    const long krow0 = (long)b * N + (long)sp * NKT * 64;
    const ushort_t* kp0 = Kh + (krow0 + w * 16 + rs) * (long)Cc + (cg << 3);
    const ushort_t* kp1 = kp0 + 8 * Cc;
    const ushort_t* vp0 = Vth + ((long)b * C + w * 16 + rs) * (long)N
                              + (cg << 3) + (long)sp * NKT * 64;
    const ushort_t* vp1 = vp0 + 8 * (long)N;

#define SLOT(k) (smem + (k) * 8192)
#define STGKP(c0, c1, slot, toff) do {                                           \
    GLD16(kp0 + (toff) + (c0) * 64, SLOT(slot) + ldso0);                         \
    GLD16(kp1 + (toff) + (c0) * 64, SLOT(slot) + ldso1);                         \
    GLD16(kp0 + (toff) + (c1) * 64, SLOT(slot) + 4096 + ldso0);                  \
    GLD16(kp1 + (toff) + (c1) * 64, SLOT(slot) + 4096 + ldso1); } while (0)
#define STGK1(c0, slot, toff) do {                                               \
    GLD16(kp0 + (toff) + (c0) * 64, SLOT(slot) + ldso0);                         \
    GLD16(kp1 + (toff) + (c0) * 64, SLOT(slot) + ldso1); } while (0)
#define STGVP(j0, slot, voff) do {                                               \
    GLD16(vp0 + (voff) + (j0) * VCHO, SLOT(slot) + ldso0);                       \
    GLD16(vp1 + (voff) + (j0) * VCHO, SLOT(slot) + ldso1);                       \
    GLD16(vp0 + (voff) + ((j0) + 1) * VCHO, SLOT(slot) + 4096 + ldso0);          \
    GLD16(vp1 + (voff) + ((j0) + 1) * VCHO, SLOT(slot) + 4096 + ldso1); } while (0)

#define WAITV(NN) asm volatile("s_waitcnt vmcnt(" #NN ")" ::: "memory");         \
    __builtin_amdgcn_sched_barrier(0);                                           \
    __builtin_amdgcn_s_barrier();                                                \
    __builtin_amdgcn_s_setprio(1);
#define PH_END __builtin_amdgcn_s_setprio(0);

#define QKPAIR(slot, c0) do {                                                    \
    const ushort_t* s0_ = SLOT(slot);                                            \
    const ushort_t* s1_ = s0_ + 4096;                                            \
    _Pragma("unroll")                                                            \
    for (int ct = 0; ct < 4; ++ct) S[ct] = MFMAH(qf[2*(c0)+0], ldh(s0_ + ct*1024 + lb0), S[ct]); \
    _Pragma("unroll")                                                            \
    for (int ct = 0; ct < 4; ++ct) S[ct] = MFMAH(qf[2*(c0)+1], ldh(s0_ + ct*1024 + lb1), S[ct]); \
    _Pragma("unroll")                                                            \
    for (int ct = 0; ct < 4; ++ct) S[ct] = MFMAH(qf[2*(c0)+2], ldh(s1_ + ct*1024 + lb0), S[ct]); \
    _Pragma("unroll")                                                            \
    for (int ct = 0; ct < 4; ++ct) S[ct] = MFMAH(qf[2*(c0)+3], ldh(s1_ + ct*1024 + lb1), S[ct]); } while (0)
#define QK1(slot, c0) do {                                                       \
    const ushort_t* s0_ = SLOT(slot);                                            \
    _Pragma("unroll")                                                            \
    for (int ct = 0; ct < 4; ++ct) S[ct] = MFMAH(qf[2*(c0)+0], ldh(s0_ + ct*1024 + lb0), S[ct]); \
    _Pragma("unroll")                                                            \
    for (int ct = 0; ct < 4; ++ct) S[ct] = MFMAH(qf[2*(c0)+1], ldh(s0_ + ct*1024 + lb1), S[ct]); } while (0)
#define PVPAIR(slot, ci0) do {                                                   \
    const ushort_t* s0_ = SLOT(slot);                                            \
    const ushort_t* s1_ = s0_ + 4096;                                            \
    _Pragma("unroll")                                                            \
    for (int ct = 0; ct < 4; ++ct) {                                             \
        half8 vh = ldh(s0_ + ct*1024 + lb0); half8 uh = vh * vh;                 \
        Mac[(ci0)*4 + ct] = MFMAH(pf0, vh, Mac[(ci0)*4 + ct]);                   \
        Sac[(ci0)*4 + ct] = MFMAH(pf0, uh, Sac[(ci0)*4 + ct]); }                 \
    _Pragma("unroll")                                                            \
    for (int ct = 0; ct < 4; ++ct) {                                             \
        half8 vh = ldh(s0_ + ct*1024 + lb1); half8 uh = vh * vh;                 \
        Mac[(ci0)*4 + ct] = MFMAH(pf1, vh, Mac[(ci0)*4 + ct]);                   \
        Sac[(ci0)*4 + ct] = MFMAH(pf1, uh, Sac[(ci0)*4 + ct]); }                 \
    _Pragma("unroll")                                                            \
    for (int ct = 0; ct < 4; ++ct) {                                             \
        half8 vh = ldh(s1_ + ct*1024 + lb0); half8 uh = vh * vh;                 \
        Mac[(ci0+1)*4 + ct] = MFMAH(pf0, vh, Mac[(ci0+1)*4 + ct]);               \
        Sac[(ci0+1)*4 + ct] = MFMAH(pf0, uh, Sac[(ci0+1)*4 + ct]); }             \
    _Pragma("unroll")                                                            \
    for (int ct = 0; ct < 4; ++ct) {                                             \
        half8 vh = ldh(s1_ + ct*1024 + lb1); half8 uh = vh * vh;                 \
        Mac[(ci0+1)*4 + ct] = MFMAH(pf1, vh, Mac[(ci0+1)*4 + ct]);               \
        Sac[(ci0+1)*4 + ct] = MFMAH(pf1, uh, Sac[(ci0+1)*4 + ct]); } } while (0)
#define RESET_S do {                                                             \
    _Pragma("unroll")                                                            \
    for (int ct = 0; ct < 4; ++ct)                                               \
        _Pragma("unroll")                                                        \
        for (int r = 0; r < 4; ++r) S[ct][r] = 0.f; } while (0)

    half8 qf[14];
    {
        const ushort_t* q1 = Qh + ((long)(b * N + i0 + l15)) * Cc + quad * 8;
#pragma unroll
        for (int ks = 0; ks < 14; ++ks) qf[ks] = ldh(q1 + ks * 32);
    }
    asm volatile("s_waitcnt vmcnt(0)" ::: "memory");

    float m_r[4], l_l[4], mw = -1e30f;
    f32x4 Mac[16], Sac[16];
    f32x4 S[4];
    half8 pf0, pf1;
#pragma unroll
    for (int r = 0; r < 4; ++r) { m_r[r] = -1e30f; l_l[r] = 0.f; }
#pragma unroll
    for (int ct = 0; ct < 16; ++ct)
#pragma unroll
        for (int r = 0; r < 4; ++r) { Mac[ct][r] = 0.f; Sac[ct][r] = 0.f; }

    auto softmax_step = [&]() {
        float tmax = S[0][0];
#pragma unroll
        for (int ct = 0; ct < 4; ++ct)
#pragma unroll
            for (int r = 0; r < 4; ++r) tmax = fmaxf(tmax, S[ct][r]);
#pragma unroll
        for (int off = 1; off <= 32; off <<= 1)
            tmax = fmaxf(tmax, __shfl_xor(tmax, off, 64));

        if (tmax > mw + 14.4269504f) {
            float rm[4];
#pragma unroll
            for (int r = 0; r < 4; ++r)
                rm[r] = fmaxf(fmaxf(S[0][r], S[1][r]), fmaxf(S[2][r], S[3][r]));
#pragma unroll
            for (int off = 1; off <= 8; off <<= 1)
#pragma unroll
                for (int r = 0; r < 4; ++r)
                    rm[r] = fmaxf(rm[r], __shfl_xor(rm[r], off, 64));
#pragma unroll
            for (int r = 0; r < 4; ++r) {
                float mn = fmaxf(m_r[r], rm[r]);
                float corr = exp2f(m_r[r] - mn);
                m_r[r] = mn;
                l_l[r] *= corr;
#pragma unroll
                for (int ct = 0; ct < 16; ++ct) { Mac[ct][r] *= corr; Sac[ct][r] *= corr; }
            }
            float tt = fminf(fminf(m_r[0], m_r[1]), fminf(m_r[2], m_r[3]));
            tt = fminf(tt, __shfl_xor(tt, 16, 64));
            tt = fminf(tt, __shfl_xor(tt, 32, 64));
            mw = tt;
        }
#pragma unroll
        for (int ct = 0; ct < 4; ++ct)
#pragma unroll
            for (int r = 0; r < 4; ++r) {
                float p = exp2f(S[ct][r] - m_r[r]);
                l_l[r] += p;
                pww[r * 72 + ct * 16] = f16_bits(p);
            }
        pf0 = ldh(pfr);
        pf1 = ldh(pfr + 32);
    };

    STGKP(0, 1, 0, 0);
    STGKP(2, 3, 1, 0);

    for (int it = 0; it < NKT / 2; ++it) {
        // ================= tile A =================
        RESET_S;
        STGKP(4, 5, 2, 0);
        WAITV(8)  QKPAIR(0, 0); PH_END;
        STGK1(6, 3, 0);
        WAITV(6)  QKPAIR(1, 2); PH_END;
        STGVP(0, 0, 0);
        WAITV(6)  QKPAIR(2, 4); PH_END;
        STGVP(2, 1, 0);
        WAITV(8)  QK1(3, 6); PH_END;
        softmax_step();
        STGKP(0, 1, 2, KADV);
        WAITV(8)  PVPAIR(0, 0); PH_END;
        STGKP(2, 3, 3, KADV);
        WAITV(8)  PVPAIR(1, 2); PH_END;

        // ================= tile B =================
        RESET_S;
        STGKP(4, 5, 0, KADV);
        WAITV(8)  QKPAIR(2, 0); PH_END;
        STGK1(6, 1, KADV);
        WAITV(6)  QKPAIR(3, 2); PH_END;
        STGVP(0, 2, 64);
        WAITV(6)  QKPAIR(0, 4); PH_END;
        STGVP(2, 3, 64);
        WAITV(8)  QK1(1, 6); PH_END;
        softmax_step();
        const bool more = (it + 1 < NKT / 2);
        if (more) {
            kp0 += 2 * KADV; kp1 += 2 * KADV;
            STGKP(0, 1, 0, 0);
            asm volatile("s_waitcnt vmcnt(8)" ::: "memory");
        } else {
            asm volatile("s_waitcnt vmcnt(4)" ::: "memory");
        }
        __builtin_amdgcn_sched_barrier(0);
        __builtin_amdgcn_s_barrier();
        __builtin_amdgcn_s_setprio(1);
        PVPAIR(2, 0);
        PH_END;
        if (more) {
            STGKP(2, 3, 1, 0);
            asm volatile("s_waitcnt vmcnt(8)" ::: "memory");
        } else {
            asm volatile("s_waitcnt vmcnt(0)" ::: "memory");
        }
        __builtin_amdgcn_sched_barrier(0);
        __builtin_amdgcn_s_barrier();
        __builtin_amdgcn_s_setprio(1);
        PVPAIR(3, 2);
        PH_END;

        vp0 += 128; vp1 += 128;
    }
#undef SLOT
#undef STGKP
#undef STGK1
#undef STGVP
#undef WAITV
#undef PH_END
#undef QKPAIR
#undef QK1
#undef PVPAIR
#undef RESET_S

#pragma unroll
    for (int off = 1; off <= 8; off <<= 1)
#pragma unroll
        for (int r = 0; r < 4; ++r) l_l[r] += __shfl_xor(l_l[r], off, 64);

    if (l15 == 0) {
#pragma unroll
        for (int r = 0; r < 4; ++r) {
            Pmo[po * 16 + quad * 4 + r] = m_r[r];
            Plo[po * 16 + quad * 4 + r] = l_l[r];
        }
    }
#pragma unroll
    for (int ct = 0; ct < 16; ++ct)
#pragma unroll
        for (int r = 0; r < 4; ++r) {
            long idx = (po * 16 + quad * 4 + r) * C + ct * 16 + l15;
            PMo[idx] = Mac[ct][r];
            PSo[idx] = Sac[ct][r];
        }
}

// ---------------------------------------------------------------------------
// Generic flash body (scales 3/4), now as a device function so s3+s4 can be
// fused into one launch.  NEW: QK chunk-split across the CSPLIT waves of a
// stripe (each wave computes chunks with (chunk % CSPLIT)==ch2) followed by
// an S-merge through LDS — eliminates the 2x/4x duplicated QK work.
// ---------------------------------------------------------------------------
template<int Cc, int C, int N, int CSPLIT, bool QREG, int SPLIT, int SLABS, int KGRP>
__device__ __forceinline__ void flash_body(
    const ushort_t* __restrict__ Qh, const ushort_t* __restrict__ Kh,
    const ushort_t* __restrict__ Vth,
    float* __restrict__ Pmo, float* __restrict__ Plo,
    float* __restrict__ PMo, float* __restrict__ PSo,
    ushort_t* smem, int bid)
{
    constexpr int KC      = Cc / 64;
    constexpr int VC      = C / 64;
    constexpr int VCW     = VC / CSPLIT;
    constexpr int CTCW    = 4 * VCW;
    constexpr int STRIPES = 4 / CSPLIT;
    constexpr int BROWS   = 16 * STRIPES;
    constexpr int QB      = N / BROWS;
    constexpr int TILES   = N / 64;
    constexpr int NKT     = TILES / SPLIT;
    constexpr int NKS     = QREG ? (Cc / 32) : 1;
    constexpr int NGRP    = (KC + KGRP - 1) / KGRP;
    constexpr int G       = 4 / CSPLIT;
    constexpr int QCH     = BROWS * 64;
    constexpr int QOFF    = KGRP * 4096;
    constexpr int KQEND   = QOFF + KGRP * QCH;
    constexpr int REGION  = QREG ? (SLABS * 4096)
                                 : (KQEND > SLABS * 4096 ? KQEND : SLABS * 4096);

    const int tid  = threadIdx.x;
    const int lane = tid & 63;
    const int w    = tid >> 6;
    const int l15  = lane & 15;
    const int quad = lane >> 4;

    const int bq = bid / SPLIT;
    const int sp = bid % SPLIT;
    const int b  = bq / QB;
    const int qb = bq % QB;
    const int ls  = w / CSPLIT;
    const int ch2 = w % CSPLIT;
    const int i0 = qb * BROWS + ls * 16;
    const long po = (long)(b * (N / 16) + qb * STRIPES + ls) * SPLIT + sp;
    ushort_t* Pw = smem + REGION + w * 1152;

    half8 qf[NKS];
    if constexpr (QREG) {
        const ushort_t* q1 = Qh + ((long)(b * N + i0 + l15)) * Cc + quad * 8;
#pragma unroll
        for (int ks = 0; ks < NKS; ++ks) qf[ks] = ldh(q1 + ks * 32);
    }

    float m_r[4], l_l[4], mw = -1e30f;
    f32x4 Mac[CTCW], Sac[CTCW];
#pragma unroll
    for (int r = 0; r < 4; ++r) { m_r[r] = -1e30f; l_l[r] = 0.f; }
#pragma unroll
    for (int ct = 0; ct < CTCW; ++ct)
#pragma unroll
        for (int r = 0; r < 4; ++r) { Mac[ct][r] = 0.f; Sac[ct][r] = 0.f; }

    for (int kt = sp * NKT; kt < sp * NKT + NKT; ++kt) {
        const long krow = (long)b * N + kt * 64;

        f32x4 S[4];
#pragma unroll
        for (int ct = 0; ct < 4; ++ct)
#pragma unroll
            for (int r = 0; r < 4; ++r) S[ct][r] = 0.f;

        // ---- QK (each wave computes its chunk subset; partial S) ----
#pragma unroll
        for (int grp = 0; grp < NGRP; ++grp) {
            const int g0 = grp * KGRP;
            const int gn = (KC - g0 < KGRP) ? (KC - g0) : KGRP;
            __syncthreads();
#pragma unroll
            for (int j = 0; j < KGRP; ++j) if (j < gn) {
                stage64_async(Kh, krow, Cc, (g0 + j) * 64, smem + j * 4096, tid);
                if constexpr (!QREG)
                    stageQ_async<BROWS>(Qh, (long)b * N + qb * BROWS, Cc, (g0 + j) * 64,
                                        smem + QOFF + j * QCH, tid);
            }
            __syncthreads();
#pragma unroll
            for (int j = 0; j < KGRP; ++j) if (j < gn) {
                if (((g0 + j) % CSPLIT) == ch2) {
#pragma unroll
                    for (int ks = 0; ks < 2; ++ks) {
                        half8 a;
                        if constexpr (QREG) a = qf[(g0 + j) * 2 + ks];
                        else a = ldsw(smem + QOFF + j * QCH, ls * 16 + l15, ks * 32 + quad * 8);
#pragma unroll
                        for (int ct = 0; ct < 4; ++ct) {
                            half8 bf = ldsw(smem + j * 4096, ct * 16 + l15, ks * 32 + quad * 8);
                            S[ct] = MFMAH(a, bf, S[ct]);
                        }
                    }
                }
            }
        }

        // ---- S-merge across the CSPLIT waves of a stripe (16 KB scratch) ----
        if constexpr (CSPLIT > 1) {
            float* sred = (float*)smem;
            __syncthreads();                    // QK slab reads done
#pragma unroll
            for (int ct = 0; ct < 4; ++ct)
                *(f32x4*)&sred[(w * 4 + ct) * 256 + lane * 4] = S[ct];
            __syncthreads();
#pragma unroll
            for (int p = 0; p < 4; ++p) {
                if (p == w) continue;
                if ((p / CSPLIT) != ls) continue;
#pragma unroll
                for (int ct = 0; ct < 4; ++ct) {
                    f32x4 t = *(const f32x4*)&sred[(p * 4 + ct) * 256 + lane * 4];
                    S[ct] = S[ct] + t;
                }
            }
        }

        // ---- online softmax, lazy base (log2 domain) ----
        float tmax = S[0][0];
#pragma unroll
        for (int ct = 0; ct < 4; ++ct)
#pragma unroll
            for (int r = 0; r < 4; ++r) tmax = fmaxf(tmax, S[ct][r]);
#pragma unroll
        for (int off = 1; off <= 32; off <<= 1)
            tmax = fmaxf(tmax, __shfl_xor(tmax, off, 64));

        if (tmax > mw + 14.4269504f) {
            float rm[4];
#pragma unroll
            for (int r = 0; r < 4; ++r)
                rm[r] = fmaxf(fmaxf(S[0][r], S[1][r]), fmaxf(S[2][r], S[3][r]));
#pragma unroll
            for (int off = 1; off <= 8; off <<= 1)
#pragma unroll
                for (int r = 0; r < 4; ++r)
                    rm[r] = fmaxf(rm[r], __shfl_xor(rm[r], off, 64));
#pragma unroll
            for (int r = 0; r < 4; ++r) {
                float mn = fmaxf(m_r[r], rm[r]);
                float corr = exp2f(m_r[r] - mn);
                m_r[r] = mn;
                l_l[r] *= corr;
#pragma unroll
                for (int ct = 0; ct < CTCW; ++ct) { Mac[ct][r] *= corr; Sac[ct][r] *= corr; }
            }
            float t = fminf(fminf(m_r[0], m_r[1]), fminf(m_r[2], m_r[3]));
            t = fminf(t, __shfl_xor(t, 16, 64));
            t = fminf(t, __shfl_xor(t, 32, 64));
            mw = t;
        }

#pragma unroll
        for (int ct = 0; ct < 4; ++ct)
#pragma unroll
            for (int r = 0; r < 4; ++r) {
                float p = exp2f(S[ct][r] - m_r[r]);
                l_l[r] += p;
                Pw[(quad * 4 + r) * 72 + ct * 16 + l15] = f16_bits(p);
            }

        half8 pf0 = ldh(Pw + l15 * 72 + 0  + quad * 8);
        half8 pf1 = ldh(Pw + l15 * 72 + 32 + quad * 8);

        // ---- PV / PV^2 ----
#pragma unroll
        for (int g = 0; g < VCW; g += G) {
            __syncthreads();
#pragma unroll
            for (int s = 0; s < 4; ++s) {
                const int h = s / G, j = s % G;
                stage64_async(Vth, (long)b * C + (h * VCW + g + j) * 64, N, kt * 64,
                              smem + s * 4096, tid);
            }
            __syncthreads();
#pragma unroll
            for (int ks = 0; ks < 2; ++ks) {
                half8 pf = ks ? pf1 : pf0;
#pragma unroll
                for (int j = 0; j < G; ++j)
#pragma unroll
                    for (int ct = 0; ct < 4; ++ct) {
                        half8 vh = ldsw(smem + (ch2 * G + j) * 4096,
                                        ct * 16 + l15, ks * 32 + quad * 8);
                        half8 uh = vh * vh;
                        const int ci = (g + j) * 4 + ct;
                        Mac[ci] = MFMAH(pf, vh, Mac[ci]);
                        Sac[ci] = MFMAH(pf, uh, Sac[ci]);
                    }
            }
        }
    }

    // ---- reduce per-lane l, dump partial state ----
#pragma unroll
    for (int off = 1; off <= 8; off <<= 1)
#pragma unroll
        for (int r = 0; r < 4; ++r) l_l[r] += __shfl_xor(l_l[r], off, 64);

    if (ch2 == 0 && l15 == 0) {
#pragma unroll
        for (int r = 0; r < 4; ++r) {
            Pmo[po * 16 + quad * 4 + r] = m_r[r];
            Plo[po * 16 + quad * 4 + r] = l_l[r];
        }
    }
    const int chb = ch2 * (C / CSPLIT);
#pragma unroll
    for (int ct = 0; ct < CTCW; ++ct)
#pragma unroll
        for (int r = 0; r < 4; ++r) {
            long idx = (po * 16 + quad * 4 + r) * C + chb + ct * 16 + l15;
            PMo[idx] = Mac[ct][r];
            PSo[idx] = Sac[ct][r];
        }
}

// standalone wrappers (sequential fallback path)
template<int Cc, int C, int N, int CSPLIT, bool QREG, int SPLIT, int SLABS, int KGRP>
__global__ void __launch_bounds__(256, 2) flash_mfma(
    const ushort_t* __restrict__ Qh, const ushort_t* __restrict__ Kh,
    const ushort_t* __restrict__ Vth,
    float* __restrict__ Pmo, float* __restrict__ Plo,
    float* __restrict__ PMo, float* __restrict__ PSo)
{
    __shared__ __align__(16) ushort_t smem[35328];
    flash_body<Cc, C, N, CSPLIT, QREG, SPLIT, SLABS, KGRP>(
        Qh, Kh, Vth, Pmo, Plo, PMo, PSo, smem, (int)blockIdx.x);
}

// fused s3+s4 flash: one launch, job split by block range
__global__ void __launch_bounds__(256, 2) flash34(
    const ushort_t* __restrict__ Qh3, const ushort_t* __restrict__ Kh3,
    const ushort_t* __restrict__ Vth3,
    float* __restrict__ Pm3, float* __restrict__ Pl3,
    float* __restrict__ PM3, float* __restrict__ PS3,
    const ushort_t* __restrict__ Qh4, const ushort_t* __restrict__ Kh4,
    const ushort_t* __restrict__ Vth4,
    float* __restrict__ Pm4, float* __restrict__ Pl4,
    float* __restrict__ PM4, float* __restrict__ PS4, int G3)
{
    __shared__ __align__(16) ushort_t smem[35328];
    if ((int)blockIdx.x < G3)
        flash_body<960, 512, 1024, 2, false, 4, 5, 5>(
            Qh3, Kh3, Vth3, Pm3, Pl3, PM3, PS3, smem, (int)blockIdx.x);
    else
        flash_body<1472, 512, 256, 4, false, 4, 6, 6>(
            Qh4, Kh4, Vth4, Pm4, Pl4, PM4, PS4, smem, (int)blockIdx.x - G3);
}

// ---------------------------------------------------------------------------
// Combine body (merge SPLIT partials, fused epilogue + MSE), device-fn form.
// ---------------------------------------------------------------------------
template<int C, int SPLIT>
__device__ __forceinline__ void combine_body(
    const float* __restrict__ Pm, const float* __restrict__ Pl,
    const float* __restrict__ PM, const float* __restrict__ PS,
    const float* __restrict__ CT, const float* __restrict__ CS,
    const float* __restrict__ cmean, const float* __restrict__ crstd,
    float* __restrict__ loss, int N, int pi, float* shm)
{
    constexpr int CL4 = C / 4;
    float (*wS)[16] = (float(*)[16])shm;       // SPLIT x 16
    float* invL = shm + SPLIT * 16;
    float* red  = invL + 16;
    const int nb = N / 16;
    const int b  = pi / nb;
    const long g0 = (long)b * N + (long)(pi % nb) * 16;
    const int tid = threadIdx.x;

    if (tid < 16) {
        float m = -1e30f;
#pragma unroll
        for (int s = 0; s < SPLIT; ++s)
            m = fmaxf(m, Pm[((long)pi * SPLIT + s) * 16 + tid]);
        float L = 0.f;
#pragma unroll
        for (int s = 0; s < SPLIT; ++s) {
            float e = exp2f(Pm[((long)pi * SPLIT + s) * 16 + tid] - m);
            wS[s][tid] = e;
            L = fmaf(e, Pl[((long)pi * SPLIT + s) * 16 + tid], L);
        }
        invL[tid] = 1.f / L;
    }
    __syncthreads();

    float acc = 0.f;
    for (int v = tid; v < 4 * C; v += 256) {
        const int r  = v / CL4;
        const int c0 = (v - r * CL4) * 4;
        const long q0 = (((long)pi * SPLIT) * 16 + r) * C + c0;
        float4 Ms = {0.f, 0.f, 0.f, 0.f}, Ss = {0.f, 0.f, 0.f, 0.f};
#pragma unroll
        for (int s = 0; s < SPLIT; ++s) {
            const float ws_ = wS[s][r];
            const float4 pm = *(const float4*)&PM[q0 + (long)s * 16 * C];
            const float4 ps = *(const float4*)&PS[q0 + (long)s * 16 * C];
            Ms.x = fmaf(ws_, pm.x, Ms.x); Ms.y = fmaf(ws_, pm.y, Ms.y);
            Ms.z = fmaf(ws_, pm.z, Ms.z); Ms.w = fmaf(ws_, pm.w, Ms.w);
            Ss.x = fmaf(ws_, ps.x, Ss.x); Ss.y = fmaf(ws_, ps.y, Ss.y);
            Ss.z = fmaf(ws_, ps.z, Ss.z); Ss.w = fmaf(ws_, ps.w, Ss.w);
        }
        const float iL = invL[r];
        const float4 ctv = *(const float4*)&CT[(g0 + r) * C + c0];
        const float4 csv = *(const float4*)&CS[(g0 + r) * C + c0];
        const float4 cmv = *(const float4*)&cmean[b * C + c0];
        const float4 crv = *(const float4*)&crstd[b * C + c0];
#pragma unroll
        for (int e = 0; e < 4; ++e) {
            const float Msx = (&Ms.x)[e] * iL;
            const float S2  = (&Ss.x)[e] * iL - Msx * Msx;
            const float Sx  = sqrtf(fmaxf(S2, EPS_VAR));
            const float nc  = ((&ctv.x)[e] - (&cmv.x)[e]) * (&crv.x)[e];
            const float d   = (&csv.x)[e] - (Sx * nc + Msx);
            acc = fmaf(d, d, acc);
        }
    }
#pragma unroll
    for (int off = 1; off <= 32; off <<= 1) acc += __shfl_xor(acc, off, 64);
    if ((tid & 63) == 0) red[tid >> 6] = acc;
    __syncthreads();
    if (tid == 0) atomicAdd(loss, red[0] + red[1] + red[2] + red[3]);
}

template<int C, int SPLIT>
__global__ void __launch_bounds__(256) combine_aat(
    const float* __restrict__ Pm, const float* __restrict__ Pl,
    const float* __restrict__ PM, const float* __restrict__ PS,
    const float* __restrict__ CT, const float* __restrict__ CS,
    const float* __restrict__ cmean, const float* __restrict__ crstd,
    float* __restrict__ loss, int N)
{
    __shared__ float shm[SPLIT * 16 + 20];
    combine_body<C, SPLIT>(Pm, Pl, PM, PS, CT, CS, cmean, crstd, loss, N,
                           (int)blockIdx.x, shm);
}

__global__ void __launch_bounds__(256) combine34(
    const float* __restrict__ Pm3, const float* __restrict__ Pl3,
    const float* __restrict__ PM3, const float* __restrict__ PS3,
    const float* __restrict__ CT3, const float* __restrict__ CS3,
    const float* __restrict__ cm3, const float* __restrict__ cr3,
    float* __restrict__ l3, int N3,
    const float* __restrict__ Pm4, const float* __restrict__ Pl4,
    const float* __restrict__ PM4, const float* __restrict__ PS4,
    const float* __restrict__ CT4, const float* __restrict__ CS4,
    const float* __restrict__ cm4, const float* __restrict__ cr4,
    float* __restrict__ l4, int N4, int G3)
{
    __shared__ float shm[4 * 16 + 20];
    if ((int)blockIdx.x < G3)
        combine_body<512, 4>(Pm3, Pl3, PM3, PS3, CT3, CS3, cm3, cr3, l3, N3,
                             (int)blockIdx.x, shm);
    else
        combine_body<512, 4>(Pm4, Pl4, PM4, PS4, CT4, CS4, cm4, cr4, l4, N4,
                             (int)blockIdx.x - G3, shm);
}

// ---------------------------------------------------------------------------
// Fallback scalar flash kernel (only if ws_size too small)
// ---------------------------------------------------------------------------
template<int CCL, int CL, int NQ>
__global__ void __launch_bounds__(256) flash_aat(
    const float* __restrict__ Q, const float* __restrict__ K, const float* __restrict__ V,
    const float* __restrict__ CT, const float* __restrict__ CS,
    const float* __restrict__ qmean, const float* __restrict__ qrstd,
    const float* __restrict__ kmean, const float* __restrict__ krstd,
    const float* __restrict__ cmean, const float* __restrict__ crstd,
    float* __restrict__ loss, int N)
{
    constexpr int CC   = CCL * 64;
    constexpr int C    = CL * 64;
    constexpr int ROWS = 4 * NQ;
    const int lane = threadIdx.x & 63;
    const int wave = threadIdx.x >> 6;
    const int rowBlocks = N / ROWS;
    const int b  = blockIdx.x / rowBlocks;
    const int rb = blockIdx.x % rowBlocks;
    const int i0 = rb * ROWS + wave * NQ;

    float kmu[CCL], krs[CCL];
#pragma unroll
    for (int t = 0; t < CCL; ++t) {
        int ch = lane + 64 * t;
        kmu[t] = kmean[b * CC + ch];
        krs[t] = krstd[b * CC + ch];
    }
    float q[NQ][CCL];
#pragma unroll
    for (int qi = 0; qi < NQ; ++qi) {
        long base = (long)(b * N + i0 + qi) * CC;
#pragma unroll
        for (int t = 0; t < CCL; ++t) {
            int ch = lane + 64 * t;
            q[qi][t] = (Q[base + ch] - qmean[b * CC + ch]) * qrstd[b * CC + ch];
        }
    }
    float mval[NQ], lsum[NQ];
    float Macc[NQ][CL], Sacc[NQ][CL];
#pragma unroll
    for (int qi = 0; qi < NQ; ++qi) {
        mval[qi] = -1e30f; lsum[qi] = 0.f;
#pragma unroll
        for (int t = 0; t < CL; ++t) { Macc[qi][t] = 0.f; Sacc[qi][t] = 0.f; }
    }
    for (int j = 0; j < N; ++j) {
        long kb = (long)(b * N + j) * CC;
        float dot[NQ];
#pragma unroll
        for (int qi = 0; qi < NQ; ++qi) dot[qi] = 0.f;
#pragma unroll
        for (int t = 0; t < CCL; ++t) {
            float kv = (K[kb + lane + 64 * t] - kmu[t]) * krs[t];
#pragma unroll
            for (int qi = 0; qi < NQ; ++qi) dot[qi] = fmaf(q[qi][t], kv, dot[qi]);
        }
#pragma unroll
        for (int off = 32; off > 0; off >>= 1)
#pragma unroll
            for (int qi = 0; qi < NQ; ++qi) dot[qi] += __shfl_xor(dot[qi], off, 64);
        long vb = (long)(b * N + j) * C;
        float vv[CL];
#pragma unroll
        for (int t = 0; t < CL; ++t) vv[t] = V[vb + lane + 64 * t];
#pragma unroll
        for (int qi = 0; qi < NQ; ++qi) {
            float s = dot[qi];
            float p;
            if (s > mval[qi]) {
                float cr2 = __expf(mval[qi] - s);
                lsum[qi] *= cr2;
#pragma unroll
                for (int t = 0; t < CL; ++t) { Macc[qi][t] *= cr2; Sacc[qi][t] *= cr2; }
                mval[qi] = s; p = 1.f;
            } else p = __expf(s - mval[qi]);
            lsum[qi] += p;
#pragma unroll
            for (int t = 0; t < CL; ++t) {
                float pv = p * vv[t];
                Macc[qi][t] += pv;
                Sacc[qi][t] = fmaf(pv, vv[t], Sacc[qi][t]);
            }
        }
    }
    float acc = 0.f;
#pragma unroll
    for (int qi = 0; qi < NQ; ++qi) {
        float inv_l = 1.f / lsum[qi];
        long base = (long)(b * N + i0 + qi) * C;
#pragma unroll
        for (int t = 0; t < CL; ++t) {
            int ch = lane + 64 * t;
            float M  = Macc[qi][t] * inv_l;
            float S2 = Sacc[qi][t] * inv_l - M * M;
            float S  = sqrtf(fmaxf(S2, EPS_VAR));
            float nc = (CT[base + ch] - cmean[b * C + ch]) * crstd[b * C + ch];
            float d  = CS[base + ch] - (S * nc + M);
            acc = fmaf(d, d, acc);
        }
    }
#pragma unroll
    for (int off = 32; off > 0; off >>= 1) acc += __shfl_xor(acc, off, 64);
    if (lane == 0) atomicAdd(loss, acc);
}

__global__ void combine_loss(const float* __restrict__ lp, float* __restrict__ out,
                             float s0, float s1, float s2)
{
    out[0] = lp[0] * s0 + lp[1] * s1 + lp[2] * s2;
}

// ---------------------------------------------------------------------------
extern "C" void kernel_launch(void* const* d_in, const int* in_sizes, int n_in,
                              void* d_out, int out_size, void* d_ws, size_t ws_size,
                              hipStream_t stream)
{
    const float* cs2 = (const float*)d_in[0];
    const float* c2  = (const float*)d_in[1];
    const float* s2v = (const float*)d_in[2];
    const float* cc2 = (const float*)d_in[3];
    const float* sc2 = (const float*)d_in[4];
    const float* cs3 = (const float*)d_in[5];
    const float* c3  = (const float*)d_in[6];
    const float* s3v = (const float*)d_in[7];
    const float* cc3 = (const float*)d_in[8];
    const float* sc3 = (const float*)d_in[9];
    const float* cs4 = (const float*)d_in[10];
    const float* c4  = (const float*)d_in[11];
    const float* s4v = (const float*)d_in[12];
    const float* cc4 = (const float*)d_in[13];
    const float* sc4 = (const float*)d_in[14];

    const int B = 4;
    float* ws = (float*)d_ws;
    size_t fo = 0;
    auto allocF = [&](size_t n) { float* p = ws + fo; fo += n; return p; };

    float* lossp = allocF(4);
    float* c2m = allocF(B * 256);  float* c2r = allocF(B * 256);
    float* q2m = allocF(B * 448);  float* q2r = allocF(B * 448);
    float* k2m = allocF(B * 448);  float* k2r = allocF(B * 448);
    float* c3m = allocF(B * 512);  float* c3r = allocF(B * 512);
    float* q3m = allocF(B * 960);  float* q3r = allocF(B * 960);
    float* k3m = allocF(B * 960);  float* k3r = allocF(B * 960);
    float* c4m = allocF(B * 512);  float* c4r = allocF(B * 512);
    float* q4m = allocF(B * 1472); float* q4r = allocF(B * 1472);
    float* k4m = allocF(B * 1472); float* k4r = allocF(B * 1472);
    size_t zeroBytes = fo * sizeof(float);

    // partial-state buffers (shared across scales; stream-ordered reuse)
    float* Pm = allocF(32768);
    float* Pl = allocF(32768);
    float* PM = allocF(8388608);
    float* PS = allocF(8388608);

    // fp16 arena (16B aligned), reused per scale
    size_t arenaOff = ((fo * 4 + 15) & ~(size_t)15) / 2;
    ushort_t* arena = (ushort_t*)d_ws + arenaOff;
    const size_t arenaShorts = 18874400;   // max per-scale need (scale 2)
    size_t need = arenaOff * 2 + arenaShorts * 2;
    const bool fast = (ws_size >= need);

    hipMemsetAsync(d_ws, 0, zeroBytes, stream);

    // ---- fused stats (2 launches for all 9 tensors) ----
    {
        StatJobs SJ; FinJobs FJ;
        const float* xs[9] = {c2, cc2, sc2, c3, cc3, sc3, c4, cc4, sc4};
        float* sms[9] = {c2m, q2m, k2m, c3m, q3m, k3m, c4m, q4m, k4m};
        float* sqs[9] = {c2r, q2r, k2r, c3r, q3r, k3r, c4r, q4r, k4r};
        const int Ns[9]  = {4096, 4096, 4096, 1024, 1024, 1024, 256, 256, 256};
        const int Cns[9] = {256, 448, 448, 512, 960, 960, 512, 1472, 1472};
        int pb = 0, fb = 0;
        for (int j = 0; j < 9; ++j) {
            int chG = (Cns[j] + 255) / 256;
            int nG  = (Ns[j] + 255) / 256;
            SJ.x[j] = xs[j]; SJ.sm[j] = sms[j]; SJ.sq[j] = sqs[j];
            SJ.N[j] = Ns[j]; SJ.Cn[j] = Cns[j]; SJ.chG[j] = chG; SJ.nG[j] = nG;
            SJ.base[j] = pb;
            pb += B * chG * nG;
            FJ.sm[j] = sms[j]; FJ.sq[j] = sqs[j]; FJ.base[j] = fb;
            FJ.invN[j] = 1.0f / (float)Ns[j];
            fb += B * Cns[j];
        }
        FJ.total = fb;
        hipLaunchKernelGGL(stat_partial_all, dim3(pb), dim3(256), 0, stream, SJ);
        hipLaunchKernelGGL(stat_finalize_all, dim3((fb + 255) / 256), dim3(256), 0, stream, FJ);
    }

    if (fast) {
        auto arenaFor = [&](size_t& o, size_t n) {
            ushort_t* p = arena + o; o += (n + 7) & ~(size_t)7; return p;
        };
        size_t o2 = 0;
        ushort_t* qh2 = arenaFor(o2, (size_t)B*4096*448);
        ushort_t* kh2 = arenaFor(o2, (size_t)B*4096*448);
        ushort_t* vh2 = arenaFor(o2, (size_t)B*4096*256);
        size_t o3 = 0;
        ushort_t* qh3 = arenaFor(o3, (size_t)B*1024*960);
        ushort_t* kh3 = arenaFor(o3, (size_t)B*1024*960);
        ushort_t* vh3 = arenaFor(o3, (size_t)B*1024*512);
        size_t o4 = 0;
        ushort_t* qh4 = arenaFor(o4, (size_t)B*256*1472);
        ushort_t* kh4 = arenaFor(o4, (size_t)B*256*1472);
        ushort_t* vh4 = arenaFor(o4, (size_t)B*256*512);

        // V-tile block counts per scale: (C/64)*(N/64)*B
        const int vt2 = (256/64)*(4096/64)*B;   // 1024
        const int vt3 = (512/64)*(1024/64)*B;   // 512
        const int vt4 = (512/64)*(256/64)*B;    // 128

        size_t totShorts = o2 + o3 + o4;
        bool prepFused = (ws_size >= arenaOff * 2 + totShorts * 2);

        // s4 private partials at the workspace tail (fused flash34 path)
        const size_t PS4N = (size_t)256 * 16 * 512;      // 2,097,152 floats
        size_t tailByte = (((arenaOff + totShorts) * 2) + 255) & ~(size_t)255;
        bool fused34 = prepFused && (ws_size >= tailByte + 2 * PS4N * 4);
        float* PM4 = nullptr; float* PS4 = nullptr;
        if (fused34) {
            PM4 = (float*)((char*)d_ws + tailByte);
            PS4 = PM4 + PS4N;
        }

        if (prepFused) {
            qh3 = arena + o2;        kh3 = qh3 + (((size_t)B*1024*960 + 7) & ~(size_t)7);
            vh3 = kh3 + (((size_t)B*1024*960 + 7) & ~(size_t)7);
            qh4 = arena + o2 + o3;   kh4 = qh4 + (((size_t)B*256*1472 + 7) & ~(size_t)7);
            vh4 = kh4 + (((size_t)B*256*1472 + 7) & ~(size_t)7);

            PrepJobs PJ;
            PJ.qx[0]=cc2; PJ.qm[0]=q2m; PJ.qr[0]=q2r; PJ.qh[0]=qh2;
            PJ.kx[0]=sc2; PJ.km[0]=k2m; PJ.kr[0]=k2r; PJ.kh[0]=kh2;
            PJ.vx[0]=s2v; PJ.vt[0]=vh2; PJ.N[0]=4096; PJ.Cc[0]=448; PJ.C[0]=256;
            PJ.qx[1]=cc3; PJ.qm[1]=q3m; PJ.qr[1]=q3r; PJ.qh[1]=qh3;
            PJ.kx[1]=sc3; PJ.km[1]=k3m; PJ.kr[1]=k3r; PJ.kh[1]=kh3;
            PJ.vx[1]=s3v; PJ.vt[1]=vh3; PJ.N[1]=1024; PJ.Cc[1]=960; PJ.C[1]=512;
            PJ.qx[2]=cc4; PJ.qm[2]=q4m; PJ.qr[2]=q4r; PJ.qh[2]=qh4;
            PJ.kx[2]=sc4; PJ.km[2]=k4m; PJ.kr[2]=k4r; PJ.kh[2]=kh4;
            PJ.vx[2]=s4v; PJ.vt[2]=vh4; PJ.N[2]=256;  PJ.Cc[2]=1472; PJ.C[2]=512;
            int g0n = 2*4096 + vt2;
            int g1n = 2*1024 + vt3;
            int g2n = 2*256  + vt4;
            PJ.nbase[0] = 0; PJ.nbase[1] = g0n; PJ.nbase[2] = g0n + g1n;
            hipLaunchKernelGGL(prep_all, dim3(g0n + g1n + g2n), dim3(256), 0, stream, PJ);
        }

        // ---- scale 2 ----
        {
            if (!prepFused) {
                PrepJobs PJ;
                PJ.qx[0]=cc2; PJ.qm[0]=q2m; PJ.qr[0]=q2r; PJ.qh[0]=qh2;
                PJ.kx[0]=sc2; PJ.km[0]=k2m; PJ.kr[0]=k2r; PJ.kh[0]=kh2;
                PJ.vx[0]=s2v; PJ.vt[0]=vh2; PJ.N[0]=4096; PJ.Cc[0]=448; PJ.C[0]=256;
                for (int k = 1; k < 3; ++k) { PJ.N[k]=4096; PJ.Cc[k]=448; PJ.C[k]=256;
                    PJ.qx[k]=cc2; PJ.qm[k]=q2m; PJ.qr[k]=q2r; PJ.qh[k]=qh2;
                    PJ.kx[k]=sc2; PJ.km[k]=k2m; PJ.kr[k]=k2r; PJ.kh[k]=kh2;
                    PJ.vx[k]=s2v; PJ.vt[k]=vh2; }
                int gn = 2*4096 + vt2;
                PJ.nbase[0]=0; PJ.nbase[1]=gn; PJ.nbase[2]=gn;
                hipLaunchKernelGGL(prep_all, dim3(gn), dim3(256), 0, stream, PJ);
            }
            hipLaunchKernelGGL(flash_pipe, dim3(B*(4096/64)*2), dim3(256), 0, stream,
                               qh2, kh2, vh2, Pm, Pl, PM, PS);
            hipLaunchKernelGGL((combine_aat<256, 2>), dim3(B*4096/16), dim3(256), 0, stream,
                               Pm, Pl, PM, PS, c2, cs2, c2m, c2r, &lossp[0], 4096);
        }

        if (fused34) {
            // ---- fused scales 3+4: one flash launch, one combine launch ----
            const int G3 = B*(1024/32)*4;      // 512
            const int G4 = B*(256/16)*4;       // 256
            hipLaunchKernelGGL(flash34, dim3(G3 + G4), dim3(256), 0, stream,
                               qh3, kh3, vh3, Pm, Pl, PM, PS,
                               qh4, kh4, vh4, Pm + 16384, Pl + 16384, PM4, PS4, G3);
            const int C3 = B*1024/16;          // 256
            const int C4 = B*256/16;           // 64
            hipLaunchKernelGGL(combine34, dim3(C3 + C4), dim3(256), 0, stream,
                               Pm, Pl, PM, PS, c3, cs3, c3m, c3r, &lossp[1], 1024,
                               Pm + 16384, Pl + 16384, PM4, PS4,
                               c4, cs4, c4m, c4r, &lossp[2], 256, C3);
        } else {
            // ---- scale 3 (sequential) ----
            {
                if (!prepFused) {
                    PrepJobs PJ;
                    PJ.qx[0]=cc3; PJ.qm[0]=q3m; PJ.qr[0]=q3r; PJ.qh[0]=qh3;
                    PJ.kx[0]=sc3; PJ.km[0]=k3m; PJ.kr[0]=k3r; PJ.kh[0]=kh3;
                    PJ.vx[0]=s3v; PJ.vt[0]=vh3; PJ.N[0]=1024; PJ.Cc[0]=960; PJ.C[0]=512;
                    for (int k = 1; k < 3; ++k) { PJ.N[k]=1024; PJ.Cc[k]=960; PJ.C[k]=512;
                        PJ.qx[k]=cc3; PJ.qm[k]=q3m; PJ.qr[k]=q3r; PJ.qh[k]=qh3;
                        PJ.kx[k]=sc3; PJ.km[k]=k3m; PJ.kr[k]=k3r; PJ.kh[k]=kh3;
                        PJ.vx[k]=s3v; PJ.vt[k]=vh3; }
                    int gn = 2*1024 + vt3;
                    PJ.nbase[0]=0; PJ.nbase[1]=gn; PJ.nbase[2]=gn;
                    hipLaunchKernelGGL(prep_all, dim3(gn), dim3(256), 0, stream, PJ);
                }
                hipLaunchKernelGGL((flash_mfma<960, 512, 1024, 2, false, 4, 5, 5>),
                                   dim3(B*(1024/32)*4), dim3(256), 0, stream,
                                   qh3, kh3, vh3, Pm, Pl, PM, PS);
                hipLaunchKernelGGL((combine_aat<512, 4>), dim3(B*1024/16), dim3(256), 0, stream,
                                   Pm, Pl, PM, PS, c3, cs3, c3m, c3r, &lossp[1], 1024);
            }
            // ---- scale 4 (sequential) ----
            {
                if (!prepFused) {
                    PrepJobs PJ;
                    PJ.qx[0]=cc4; PJ.qm[0]=q4m; PJ.qr[0]=q4r; PJ.qh[0]=qh4;
                    PJ.kx[0]=sc4; PJ.km[0]=k4m; PJ.kr[0]=k4r; PJ.kh[0]=kh4;
                    PJ.vx[0]=s4v; PJ.vt[0]=vh4; PJ.N[0]=256; PJ.Cc[0]=1472; PJ.C[0]=512;
                    for (int k = 1; k < 3; ++k) { PJ.N[k]=256; PJ.Cc[k]=1472; PJ.C[k]=512;
                        PJ.qx[k]=cc4; PJ.qm[k]=q4m; PJ.qr[k]=q4r; PJ.qh[k]=qh4;
                        PJ.kx[k]=sc4; PJ.km[k]=k4m; PJ.kr[k]=k4r; PJ.kh[k]=kh4;
                        PJ.vx[k]=s4v; PJ.vt[k]=vh4; }
                    int gn = 2*256 + vt4;
                    PJ.nbase[0]=0; PJ.nbase[1]=gn; PJ.nbase[2]=gn;
                    hipLaunchKernelGGL(prep_all, dim3(gn), dim3(256), 0, stream, PJ);
                }
                hipLaunchKernelGGL((flash_mfma<1472, 512, 256, 4, false, 4, 6, 6>),
                                   dim3(B*(256/16)*4), dim3(256), 0, stream,
                                   qh4, kh4, vh4, Pm, Pl, PM, PS);
                hipLaunchKernelGGL((combine_aat<512, 4>), dim3(B*256/16), dim3(256), 0, stream,
                                   Pm, Pl, PM, PS, c4, cs4, c4m, c4r, &lossp[2], 256);
            }
        }
    } else {
        hipLaunchKernelGGL((flash_aat<7, 4, 4>), dim3(B * 4096 / 16), dim3(256), 0, stream,
                           cc2, sc2, s2v, c2, cs2, q2m, q2r, k2m, k2r, c2m, c2r, &lossp[0], 4096);
        hipLaunchKernelGGL((flash_aat<15, 8, 2>), dim3(B * 1024 / 8), dim3(256), 0, stream,
                           cc3, sc3, s3v, c3, cs3, q3m, q3r, k3m, k3r, c3m, c3r, &lossp[1], 1024);
        hipLaunchKernelGGL((flash_aat<23, 8, 2>), dim3(B * 256 / 8), dim3(256), 0, stream,
                           cc4, sc4, s4v, c4, cs4, q4m, q4r, k4m, k4r, c4m, c4r, &lossp[2], 256);
    }

    hipLaunchKernelGGL(combine_loss, dim3(1), dim3(1), 0, stream,
                       lossp, (float*)d_out,
                       1.0f / (4.0f * 4096.0f * 256.0f),
                       1.0f / (4.0f * 1024.0f * 512.0f),
                       1.0f / (4.0f * 256.0f * 512.0f));
}

// Round 7
// 650.261 us; speedup vs baseline: 2.4873x; 1.0341x over previous
//
#include <hip/hip_runtime.h>
#include <math.h>

#define EPS_NORM 1e-5f
#define EPS_VAR  1e-9f
#define LOG2E    1.4426950408889634f

typedef unsigned short ushort_t;
typedef __attribute__((ext_vector_type(4))) float f32x4;
typedef _Float16 half8 __attribute__((ext_vector_type(8)));

#define MFMAH(a, b, c) __builtin_amdgcn_mfma_f32_16x16x32_f16((a), (b), (c), 0, 0, 0)

// async global->LDS DMA, 16B per lane; LDS dest = wave-uniform base + lane*16
#define GLD16(gp, lp) __builtin_amdgcn_global_load_lds(                          \
    (const __attribute__((address_space(1))) unsigned int*)(gp),                 \
    (__attribute__((address_space(3))) unsigned int*)(lp), 16, 0, 0)

// ---------------------------------------------------------------------------
// fp16 helpers
// ---------------------------------------------------------------------------
__device__ inline ushort_t f16_bits(float x) {
    _Float16 h = (_Float16)x;
    ushort_t u;
    __builtin_memcpy(&u, &h, 2);
    return u;
}
__device__ inline half8 ldh(const ushort_t* p) {   // 16B-aligned load
    half8 h;
    __builtin_memcpy(&h, p, 16);
    return h;
}
__device__ inline uint4 pack8(const ushort_t* s) {
    uint4 r;
    r.x = (unsigned)s[0] | ((unsigned)s[1] << 16);
    r.y = (unsigned)s[2] | ((unsigned)s[3] << 16);
    r.z = (unsigned)s[4] | ((unsigned)s[5] << 16);
    r.w = (unsigned)s[6] | ((unsigned)s[7] << 16);
    return r;
}

// ---------------------------------------------------------------------------
// Fused stage-1 stats: all 9 tensors in one launch (job table, nPer=128)
// ---------------------------------------------------------------------------
struct StatJobs {
    const float* x[9];
    float* sm[9];
    float* sq[9];
    int N[9], Cn[9], chG[9], nG[9], base[9];
};
__global__ void __launch_bounds__(256) stat_partial_all(StatJobs J)
{
    int bx = blockIdx.x;
    int j = 0;
#pragma unroll
    for (int k = 1; k < 9; ++k) if (bx >= J.base[k]) j = k;
    bx -= J.base[j];
    const int N = J.N[j], Cn = J.Cn[j], chG = J.chG[j], nG = J.nG[j];
    int b  = bx / (chG * nG);
    int r  = bx % (chG * nG);
    int cg = r / nG;
    int ng = r % nG;
    int ch = cg * 256 + threadIdx.x;
    if (ch >= Cn) return;
    int n0 = ng * 128;
    int n1 = min(n0 + 128, N);
    const float* p = J.x[j] + (long)(b * N) * Cn + ch;
    float s = 0.f, ss = 0.f;
    for (int n = n0; n < n1; ++n) {
        float v = p[(long)n * Cn];
        s += v;
        ss = fmaf(v, v, ss);
    }
    atomicAdd(&J.sm[j][b * Cn + ch], s);
    atomicAdd(&J.sq[j][b * Cn + ch], ss);
}

// finalize kept ONLY for the scalar fallback path
struct FinJobs {
    float* sm[9];
    float* sq[9];
    int base[9];
    float invN[9];
    int total;
};
__global__ void __launch_bounds__(256) stat_finalize_all(FinJobs J)
{
    int i = blockIdx.x * 256 + threadIdx.x;
    if (i >= J.total) return;
    int j = 0;
#pragma unroll
    for (int k = 1; k < 9; ++k) if (i >= J.base[k]) j = k;
    int e = i - J.base[j];
    float m = J.sm[j][e] * J.invN[j];
    float v = J.sq[j][e] * J.invN[j] - m * m;
    J.sm[j][e] = m;
    J.sq[j][e] = rsqrtf(v + EPS_NORM);
}

// ---------------------------------------------------------------------------
// Device building blocks: norm (inline finalize, wave-per-row, float4) and
// V-transpose via LDS tile.
// ---------------------------------------------------------------------------
__device__ __forceinline__ void norm_quad(
    int bx, const float* __restrict__ qx, const float* __restrict__ qs,
    const float* __restrict__ qq, const float* __restrict__ kx,
    const float* __restrict__ ks, const float* __restrict__ kq,
    ushort_t* __restrict__ qh, ushort_t* __restrict__ kh,
    int N, int Cc, float invN)
{
    const int wave = threadIdx.x >> 6, lane = threadIdx.x & 63;
    int rr = bx * 4 + wave;               // 0 .. 2*B*N-1
    const int BN = 4 * N;
    const bool isQ = rr < BN;
    int bn = isQ ? rr : rr - BN;
    const float* x  = isQ ? qx : kx;
    const float* sm = isQ ? qs : ks;
    const float* sq = isQ ? qq : kq;
    ushort_t* out   = isQ ? qh : kh;
    const float scl = isQ ? LOG2E : 1.0f;
    int b = bn / N;
    long base = (long)bn * Cc;
    const float* smb = sm + b * Cc;
    const float* sqb = sq + b * Cc;
    for (int c8 = lane; c8 * 8 < Cc; c8 += 64) {
        int ch = c8 * 8;
        float4 a0 = *(const float4*)(x + base + ch);
        float4 a1 = *(const float4*)(x + base + ch + 4);
        float4 s0 = *(const float4*)(smb + ch);
        float4 s1 = *(const float4*)(smb + ch + 4);
        float4 t0 = *(const float4*)(sqb + ch);
        float4 t1 = *(const float4*)(sqb + ch + 4);
        ushort_t h8[8];
#pragma unroll
        for (int e = 0; e < 4; ++e) {
            float m = (&s0.x)[e] * invN;
            float r = rsqrtf((&t0.x)[e] * invN - m * m + EPS_NORM);
            h8[e] = f16_bits(((&a0.x)[e] - m) * r * scl);
        }
#pragma unroll
        for (int e = 0; e < 4; ++e) {
            float m = (&s1.x)[e] * invN;
            float r = rsqrtf((&t1.x)[e] * invN - m * m + EPS_NORM);
            h8[4 + e] = f16_bits(((&a1.x)[e] - m) * r * scl);
        }
        *(uint4*)(out + base + ch) = pack8(h8);
    }
}

__device__ __forceinline__ void vtile(
    int bid2, const float* __restrict__ vx, ushort_t* __restrict__ vt,
    int N, int C, ushort_t* tbuf)
{
    const int cT = C >> 6, nT = N >> 6;
    int b   = bid2 / (cT * nT);
    int rem = bid2 % (cT * nT);
    int ch0 = (rem / nT) << 6;
    int n0  = (rem % nT) << 6;
    const int lane = threadIdx.x & 63, wv = threadIdx.x >> 6;
    const float* vb_ = vx + (long)b * N * C + ch0 + lane;
#pragma unroll
    for (int jj = 0; jj < 2; ++jj) {
        int nl = wv * 16 + jj * 8;
        ushort_t h8[8];
#pragma unroll
        for (int i = 0; i < 8; ++i)
            h8[i] = f16_bits(vb_[(long)(n0 + nl + i) * C]);
        *(uint4*)&tbuf[lane * 72 + nl] = pack8(h8);
    }
    __syncthreads();
    {
        const int chl = threadIdx.x >> 2;
        const int nq  = (threadIdx.x & 3) * 16;
        ushort_t* op = vt + ((long)b * C + ch0 + chl) * N + n0 + nq;
        *(uint4*)op       = *(const uint4*)&tbuf[chl * 72 + nq];
        *(uint4*)(op + 8) = *(const uint4*)&tbuf[chl * 72 + nq + 8];
    }
}

// prep for scale 2 only (norm q2/k2 + V2 transpose)
__global__ void __launch_bounds__(256) prep2(
    const float* __restrict__ qx, const float* __restrict__ qs, const float* __restrict__ qq,
    const float* __restrict__ kx, const float* __restrict__ ks, const float* __restrict__ kq,
    ushort_t* __restrict__ qh, ushort_t* __restrict__ kh,
    const float* __restrict__ vx, ushort_t* __restrict__ vt)
{
    __shared__ __align__(16) ushort_t lbuf[4608];
    int bx = blockIdx.x;
    if (bx < 8192) norm_quad(bx, qx, qs, qq, kx, ks, kq, qh, kh, 4096, 448, 1.0f / 4096.0f);
    else           vtile(bx - 8192, vx, vt, 4096, 256, lbuf);
}

// ---------------------------------------------------------------------------
// Async DMA tile stagers.  LDS tiles 64 shorts/row, XOR-swizzled.
// ---------------------------------------------------------------------------
__device__ inline void stage64_async(const ushort_t* __restrict__ g, long rowBase,
                                     int gstride, int col0, ushort_t* slab, int tid)
{
    const int l  = tid & 63, w = tid >> 6;
    const int rs = l >> 3;
    const int cg = (l & 7) ^ rs;
#pragma unroll
    for (int i = 0; i < 2; ++i) {
        const int r = w * 16 + i * 8 + rs;
        const ushort_t* gp = g + (rowBase + r) * (long)gstride + col0 + (cg << 3);
        ushort_t* lp = slab + (w * 16 + i * 8) * 64 + l * 8;
        GLD16(gp, lp);
    }
}
template<int BROWS>
__device__ inline void stageQ_async(const ushort_t* __restrict__ g, long rowBase,
                                    int gstride, int col0, ushort_t* slab, int tid)
{
    if (tid < BROWS * 8) {
        const int l  = tid & 63, w = tid >> 6;
        const int rs = l >> 3;
        const int cg = (l & 7) ^ rs;
        const int r  = w * 8 + rs;
        const ushort_t* gp = g + (rowBase + r) * (long)gstride + col0 + (cg << 3);
        ushort_t* lp = slab + w * 8 * 64 + l * 8;
        GLD16(gp, lp);
    }
}
__device__ inline half8 ldsw(const ushort_t* slab, int row, int soff)
{
    const int gr = (soff >> 3) ^ (row & 7);
    return ldh(slab + row * 64 + (gr << 3));
}

// ---------------------------------------------------------------------------
// Pipelined flash for scale 2 (unchanged — proven 240 us; register-bound).
// ---------------------------------------------------------------------------
__global__ void __launch_bounds__(256, 2) flash_pipe(
    const ushort_t* __restrict__ Qh, const ushort_t* __restrict__ Kh,
    const ushort_t* __restrict__ Vth,
    float* __restrict__ Pmo, float* __restrict__ Plo,
    float* __restrict__ PMo, float* __restrict__ PSo)
{
    constexpr int Cc = 448, C = 256, N = 4096, SPLIT = 2;
    constexpr int NKT  = (N / 64) / SPLIT;
    constexpr long VCHO = 64L * N;
    constexpr long KADV = 64L * Cc;

    __shared__ __align__(16) ushort_t smem[4 * 8192 + 4 * 1152];
    const int tid  = threadIdx.x;
    const int lane = tid & 63;
    const int w    = tid >> 6;
    const int l15  = lane & 15;
    const int quad = lane >> 4;

    const int grp = blockIdx.x & 7;
    const int sp  = grp & 1;
    const int b   = grp >> 1;
    const int qb  = (int)(blockIdx.x >> 3);
    const int i0 = qb * 64 + w * 16;
    const long po = (long)(b * (N / 16) + qb * 4 + w) * SPLIT + sp;

    const int rs    = lane >> 3;
    const int cg    = (lane & 7) ^ rs;
    const int ldso0 = w * 1024 + lane * 8;
    const int ldso1 = ldso0 + 512;
    const int xh    = l15 & 7;
    const int lb0   = l15 * 64 + ((quad)     ^ xh) * 8;
    const int lb1   = l15 * 64 + ((4 + quad) ^ xh) * 8;
    ushort_t* const Pw  = smem + 32768 + w * 1152;
    ushort_t* const pww = Pw + quad * 288 + l15;
    const ushort_t* const pfr = Pw + l15 * 72 + quad * 8;

    const long krow0 = (long)b * N + (long)sp * NKT * 64;
    const ushort_t* kp0 = Kh + (krow0 + w * 16 + rs) * (long)Cc + (cg << 3);
    const ushort_t* kp1 = kp0 + 8 * Cc;
    const ushort_t* vp0 = Vth + ((long)b * C + w * 16 + rs) * (long)N
                              + (cg << 3) + (long)sp * NKT * 64;
    const ushort_t* vp1 = vp0 + 8 * (long)N;

#define SLOT(k) (smem + (k) * 8192)
#define STGKP(c0, c1, slot, toff) do {                                           \
    GLD16(kp0 + (toff) + (c0) * 64, SLOT(slot) + ldso0);                         \
    GLD16(kp1 + (toff) + (c0) * 64, SLOT(slot) + ldso1);                         \
    GLD16(kp0 + (toff) + (c1) * 64, SLOT(slot) + 4096 + ldso0);                  \
    GLD16(kp1 + (toff) + (c1) * 64, SLOT(slot) + 4096 + ldso1); } while (0)
#define STGK1(c0, slot, toff) do {                                               \
    GLD16(kp0 + (toff) + (c0) * 64, SLOT(slot) + ldso0);                         \
    GLD16(kp1 + (toff) + (c0) * 64, SLOT(slot) + ldso1); } while (0)
#define STGVP(j0, slot, voff) do {                                               \
    GLD16(vp0 + (voff) + (j0) * VCHO, SLOT(slot) + ldso0);                       \
    GLD16(vp1 + (voff) + (j0) * VCHO, SLOT(slot) + ldso1);                       \
    GLD16(vp0 + (voff) + ((j0) + 1) * VCHO, SLOT(slot) + 4096 + ldso0);          \
    GLD16(vp1 + (voff) + ((j0) + 1) * VCHO, SLOT(slot) + 4096 + ldso1); } while (0)

#define WAITV(NN) asm volatile("s_waitcnt vmcnt(" #NN ")" ::: "memory");         \
    __builtin_amdgcn_sched_barrier(0);                                           \
    __builtin_amdgcn_s_barrier();                                                \
    __builtin_amdgcn_s_setprio(1);
#define PH_END __builtin_amdgcn_s_setprio(0);

#define QKPAIR(slot, c0) do {                                                    \
    const ushort_t* s0_ = SLOT(slot);                                            \
    const ushort_t* s1_ = s0_ + 4096;                                            \
    _Pragma("unroll")                                                            \
    for (int ct = 0; ct < 4; ++ct) S[ct] = MFMAH(qf[2*(c0)+0], ldh(s0_ + ct*1024 + lb0), S[ct]); \
    _Pragma("unroll")                                                            \
    for (int ct = 0; ct < 4; ++ct) S[ct] = MFMAH(qf[2*(c0)+1], ldh(s0_ + ct*1024 + lb1), S[ct]); \
    _Pragma("unroll")                                                            \
    for (int ct = 0; ct < 4; ++ct) S[ct] = MFMAH(qf[2*(c0)+2], ldh(s1_ + ct*1024 + lb0), S[ct]); \
    _Pragma("unroll")                                                            \
    for (int ct = 0; ct < 4; ++ct) S[ct] = MFMAH(qf[2*(c0)+3], ldh(s1_ + ct*1024 + lb1), S[ct]); } while (0)
#define QK1(slot, c0) do {                                                       \
    const ushort_t* s0_ = SLOT(slot);                                            \
    _Pragma("unroll")                                                            \
    for (int ct = 0; ct < 4; ++ct) S[ct] = MFMAH(qf[2*(c0)+0], ldh(s0_ + ct*1024 + lb0), S[ct]); \
    _Pragma("unroll")                                                            \
    for (int ct = 0; ct < 4; ++ct) S[ct] = MFMAH(qf[2*(c0)+1], ldh(s0_ + ct*1024 + lb1), S[ct]); } while (0)
#define PVPAIR(slot, ci0) do {                                                   \
    const ushort_t* s0_ = SLOT(slot);                                            \
    const ushort_t* s1_ = s0_ + 4096;                                            \
    _Pragma("unroll")                                                            \
    for (int ct = 0; ct < 4; ++ct) {                                             \
        half8 vh = ldh(s0_ + ct*1024 + lb0); half8 uh = vh * vh;                 \
        Mac[(ci0)*4 + ct] = MFMAH(pf0, vh, Mac[(ci0)*4 + ct]);                   \
        Sac[(ci0)*4 + ct] = MFMAH(pf0, uh, Sac[(ci0)*4 + ct]); }                 \
    _Pragma("unroll")                                                            \
    for (int ct = 0; ct < 4; ++ct) {                                             \
        half8 vh = ldh(s0_ + ct*1024 + lb1); half8 uh = vh * vh;                 \
        Mac[(ci0)*4 + ct] = MFMAH(pf1, vh, Mac[(ci0)*4 + ct]);                   \
        Sac[(ci0)*4 + ct] = MFMAH(pf1, uh, Sac[(ci0)*4 + ct]); }                 \
    _Pragma("unroll")                                                            \
    for (int ct = 0; ct < 4; ++ct) {                                             \
        half8 vh = ldh(s1_ + ct*1024 + lb0); half8 uh = vh * vh;                 \
        Mac[(ci0+1)*4 + ct] = MFMAH(pf0, vh, Mac[(ci0+1)*4 + ct]);               \
        Sac[(ci0+1)*4 + ct] = MFMAH(pf0, uh, Sac[(ci0+1)*4 + ct]); }             \
    _Pragma("unroll")                                                            \
    for (int ct = 0; ct < 4; ++ct) {                                             \
        half8 vh = ldh(s1_ + ct*1024 + lb1); half8 uh = vh * vh;                 \
        Mac[(ci0+1)*4 + ct] = MFMAH(pf1, vh, Mac[(ci0+1)*4 + ct]);               \
        Sac[(ci0+1)*4 + ct] = MFMAH(pf1, uh, Sac[(ci0+1)*4 + ct]); } } while (0)
#define RESET_S do {                                                             \
    _Pragma("unroll")                                                            \
    for (int ct = 0; ct < 4; ++ct)                                               \
        _Pragma("unroll")                                                        \
        for (int r = 0; r < 4; ++r) S[ct][r] = 0.f; } while (0)

    half8 qf[14];
    {
        const ushort_t* q1 = Qh + ((long)(b * N + i0 + l15)) * Cc + quad * 8;
#pragma unroll
        for (int ks = 0; ks < 14; ++ks) qf[ks] = ldh(q1 + ks * 32);
    }
    asm volatile("s_waitcnt vmcnt(0)" ::: "memory");

    float m_r[4], l_l[4], mw = -1e30f;
    f32x4 Mac[16], Sac[16];
    f32x4 S[4];
    half8 pf0, pf1;
#pragma unroll
    for (int r = 0; r < 4; ++r) { m_r[r] = -1e30f; l_l[r] = 0.f; }
#pragma unroll
    for (int ct = 0; ct < 16; ++ct)
#pragma unroll
        for (int r = 0; r < 4; ++r) { Mac[ct][r] = 0.f; Sac[ct][r] = 0.f; }

    auto softmax_step = [&]() {
        float tmax = S[0][0];
#pragma unroll
        for (int ct = 0; ct < 4; ++ct)
#pragma unroll
            for (int r = 0; r < 4; ++r) tmax = fmaxf(tmax, S[ct][r]);
#pragma unroll
        for (int off = 1; off <= 32; off <<= 1)
            tmax = fmaxf(tmax, __shfl_xor(tmax, off, 64));

        if (tmax > mw + 14.4269504f) {
            float rm[4];
#pragma unroll
            for (int r = 0; r < 4; ++r)
                rm[r] = fmaxf(fmaxf(S[0][r], S[1][r]), fmaxf(S[2][r], S[3][r]));
#pragma unroll
            for (int off = 1; off <= 8; off <<= 1)
#pragma unroll
                for (int r = 0; r < 4; ++r)
                    rm[r] = fmaxf(rm[r], __shfl_xor(rm[r], off, 64));
#pragma unroll
            for (int r = 0; r < 4; ++r) {
                float mn = fmaxf(m_r[r], rm[r]);
                float corr = exp2f(m_r[r] - mn);
                m_r[r] = mn;
                l_l[r] *= corr;
#pragma unroll
                for (int ct = 0; ct < 16; ++ct) { Mac[ct][r] *= corr; Sac[ct][r] *= corr; }
            }
            float tt = fminf(fminf(m_r[0], m_r[1]), fminf(m_r[2], m_r[3]));
            tt = fminf(tt, __shfl_xor(tt, 16, 64));
            tt = fminf(tt, __shfl_xor(tt, 32, 64));
            mw = tt;
        }
#pragma unroll
        for (int ct = 0; ct < 4; ++ct)
#pragma unroll
            for (int r = 0; r < 4; ++r) {
                float p = exp2f(S[ct][r] - m_r[r]);
                l_l[r] += p;
                pww[r * 72 + ct * 16] = f16_bits(p);
            }
        pf0 = ldh(pfr);
        pf1 = ldh(pfr + 32);
    };

    STGKP(0, 1, 0, 0);
    STGKP(2, 3, 1, 0);

    for (int it = 0; it < NKT / 2; ++it) {
        // ================= tile A =================
        RESET_S;
        STGKP(4, 5, 2, 0);
        WAITV(8)  QKPAIR(0, 0); PH_END;
        STGK1(6, 3, 0);
        WAITV(6)  QKPAIR(1, 2); PH_END;
        STGVP(0, 0, 0);
        WAITV(6)  QKPAIR(2, 4); PH_END;
        STGVP(2, 1, 0);
        WAITV(8)  QK1(3, 6); PH_END;
        softmax_step();
        STGKP(0, 1, 2, KADV);
        WAITV(8)  PVPAIR(0, 0); PH_END;
        STGKP(2, 3, 3, KADV);
        WAITV(8)  PVPAIR(1, 2); PH_END;

        // ================= tile B =================
        RESET_S;
        STGKP(4, 5, 0, KADV);
        WAITV(8)  QKPAIR(2, 0); PH_END;
        STGK1(6, 1, KADV);
        WAITV(6)  QKPAIR(3, 2); PH_END;
        STGVP(0, 2, 64);
        WAITV(6)  QKPAIR(0, 4); PH_END;
        STGVP(2, 3, 64);
        WAITV(8)  QK1(1, 6); PH_END;
        softmax_step();
        const bool more = (it + 1 < NKT / 2);
        if (more) {
            kp0 += 2 * KADV; kp1 += 2 * KADV;
            STGKP(0, 1, 0, 0);
            asm volatile("s_waitcnt vmcnt(8)" ::: "memory");
        } else {
            asm volatile("s_waitcnt vmcnt(4)" ::: "memory");
        }
        __builtin_amdgcn_sched_barrier(0);
        __builtin_amdgcn_s_barrier();
        __builtin_amdgcn_s_setprio(1);
        PVPAIR(2, 0);
        PH_END;
        if (more) {
            STGKP(2, 3, 1, 0);
            asm volatile("s_waitcnt vmcnt(8)" ::: "memory");
        } else {
            asm volatile("s_waitcnt vmcnt(0)" ::: "memory");
        }
        __builtin_amdgcn_sched_barrier(0);
        __builtin_amdgcn_s_barrier();
        __builtin_amdgcn_s_setprio(1);
        PVPAIR(3, 2);
        PH_END;

        vp0 += 128; vp1 += 128;
    }
#undef SLOT
#undef STGKP
#undef STGK1
#undef STGVP
#undef WAITV
#undef PH_END
#undef QKPAIR
#undef QK1
#undef PVPAIR
#undef RESET_S

#pragma unroll
    for (int off = 1; off <= 8; off <<= 1)
#pragma unroll
        for (int r = 0; r < 4; ++r) l_l[r] += __shfl_xor(l_l[r], off, 64);

    if (l15 == 0) {
#pragma unroll
        for (int r = 0; r < 4; ++r) {
            Pmo[po * 16 + quad * 4 + r] = m_r[r];
            Plo[po * 16 + quad * 4 + r] = l_l[r];
        }
    }
#pragma unroll
    for (int ct = 0; ct < 16; ++ct)
#pragma unroll
        for (int r = 0; r < 4; ++r) {
            long idx = (po * 16 + quad * 4 + r) * C + ct * 16 + l15;
            PMo[idx] = Mac[ct][r];
            PSo[idx] = Sac[ct][r];
        }
}

// ---------------------------------------------------------------------------
// Generic flash body (scales 3/4): QK chunk-split + S-merge (round-6 proven).
// ---------------------------------------------------------------------------
template<int Cc, int C, int N, int CSPLIT, bool QREG, int SPLIT, int SLABS, int KGRP>
__device__ __forceinline__ void flash_body(
    const ushort_t* __restrict__ Qh, const ushort_t* __restrict__ Kh,
    const ushort_t* __restrict__ Vth,
    float* __restrict__ Pmo, float* __restrict__ Plo,
    float* __restrict__ PMo, float* __restrict__ PSo,
    ushort_t* smem, int bid)
{
    constexpr int KC      = Cc / 64;
    constexpr int VC      = C / 64;
    constexpr int VCW     = VC / CSPLIT;
    constexpr int CTCW    = 4 * VCW;
    constexpr int STRIPES = 4 / CSPLIT;
    constexpr int BROWS   = 16 * STRIPES;
    constexpr int QB      = N / BROWS;
    constexpr int TILES   = N / 64;
    constexpr int NKT     = TILES / SPLIT;
    constexpr int NKS     = QREG ? (Cc / 32) : 1;
    constexpr int NGRP    = (KC + KGRP - 1) / KGRP;
    constexpr int G       = 4 / CSPLIT;
    constexpr int QCH     = BROWS * 64;
    constexpr int QOFF    = KGRP * 4096;
    constexpr int KQEND   = QOFF + KGRP * QCH;
    constexpr int REGION  = QREG ? (SLABS * 4096)
                                 : (KQEND > SLABS * 4096 ? KQEND : SLABS * 4096);

    const int tid  = threadIdx.x;
    const int lane = tid & 63;
    const int w    = tid >> 6;
    const int l15  = lane & 15;
    const int quad = lane >> 4;

    const int bq = bid / SPLIT;
    const int sp = bid % SPLIT;
    const int b  = bq / QB;
    const int qb = bq % QB;
    const int ls  = w / CSPLIT;
    const int ch2 = w % CSPLIT;
    const int i0 = qb * BROWS + ls * 16;
    const long po = (long)(b * (N / 16) + qb * STRIPES + ls) * SPLIT + sp;
    ushort_t* Pw = smem + REGION + w * 1152;

    half8 qf[NKS];
    if constexpr (QREG) {
        const ushort_t* q1 = Qh + ((long)(b * N + i0 + l15)) * Cc + quad * 8;
#pragma unroll
        for (int ks = 0; ks < NKS; ++ks) qf[ks] = ldh(q1 + ks * 32);
    }

    float m_r[4], l_l[4], mw = -1e30f;
    f32x4 Mac[CTCW], Sac[CTCW];
#pragma unroll
    for (int r = 0; r < 4; ++r) { m_r[r] = -1e30f; l_l[r] = 0.f; }
#pragma unroll
    for (int ct = 0; ct < CTCW; ++ct)
#pragma unroll
        for (int r = 0; r < 4; ++r) { Mac[ct][r] = 0.f; Sac[ct][r] = 0.f; }

    for (int kt = sp * NKT; kt < sp * NKT + NKT; ++kt) {
        const long krow = (long)b * N + kt * 64;

        f32x4 S[4];
#pragma unroll
        for (int ct = 0; ct < 4; ++ct)
#pragma unroll
            for (int r = 0; r < 4; ++r) S[ct][r] = 0.f;

        // ---- QK (each wave computes its chunk subset; partial S) ----
#pragma unroll
        for (int grp = 0; grp < NGRP; ++grp) {
            const int g0 = grp * KGRP;
            const int gn = (KC - g0 < KGRP) ? (KC - g0) : KGRP;
            __syncthreads();
#pragma unroll
            for (int j = 0; j < KGRP; ++j) if (j < gn) {
                stage64_async(Kh, krow, Cc, (g0 + j) * 64, smem + j * 4096, tid);
                if constexpr (!QREG)
                    stageQ_async<BROWS>(Qh, (long)b * N + qb * BROWS, Cc, (g0 + j) * 64,
                                        smem + QOFF + j * QCH, tid);
            }
            __syncthreads();
#pragma unroll
            for (int j = 0; j < KGRP; ++j) if (j < gn) {
                if (((g0 + j) % CSPLIT) == ch2) {
#pragma unroll
                    for (int ks = 0; ks < 2; ++ks) {
                        half8 a;
                        if constexpr (QREG) a = qf[(g0 + j) * 2 + ks];
                        else a = ldsw(smem + QOFF + j * QCH, ls * 16 + l15, ks * 32 + quad * 8);
#pragma unroll
                        for (int ct = 0; ct < 4; ++ct) {
                            half8 bf = ldsw(smem + j * 4096, ct * 16 + l15, ks * 32 + quad * 8);
                            S[ct] = MFMAH(a, bf, S[ct]);
                        }
                    }
                }
            }
        }

        // ---- S-merge across the CSPLIT waves of a stripe ----
        if constexpr (CSPLIT > 1) {
            float* sred = (float*)smem;
            __syncthreads();
#pragma unroll
            for (int ct = 0; ct < 4; ++ct)
                *(f32x4*)&sred[(w * 4 + ct) * 256 + lane * 4] = S[ct];
            __syncthreads();
#pragma unroll
            for (int p = 0; p < 4; ++p) {
                if (p == w) continue;
                if ((p / CSPLIT) != ls) continue;
#pragma unroll
                for (int ct = 0; ct < 4; ++ct) {
                    f32x4 t = *(const f32x4*)&sred[(p * 4 + ct) * 256 + lane * 4];
                    S[ct] = S[ct] + t;
                }
            }
        }

        // ---- online softmax, lazy base (log2 domain) ----
        float tmax = S[0][0];
#pragma unroll
        for (int ct = 0; ct < 4; ++ct)
#pragma unroll
            for (int r = 0; r < 4; ++r) tmax = fmaxf(tmax, S[ct][r]);
#pragma unroll
        for (int off = 1; off <= 32; off <<= 1)
            tmax = fmaxf(tmax, __shfl_xor(tmax, off, 64));

        if (tmax > mw + 14.4269504f) {
            float rm[4];
#pragma unroll
            for (int r = 0; r < 4; ++r)
                rm[r] = fmaxf(fmaxf(S[0][r], S[1][r]), fmaxf(S[2][r], S[3][r]));
#pragma unroll
            for (int off = 1; off <= 8; off <<= 1)
#pragma unroll
                for (int r = 0; r < 4; ++r)
                    rm[r] = fmaxf(rm[r], __shfl_xor(rm[r], off, 64));
#pragma unroll
            for (int r = 0; r < 4; ++r) {
                float mn = fmaxf(m_r[r], rm[r]);
                float corr = exp2f(m_r[r] - mn);
                m_r[r] = mn;
                l_l[r] *= corr;
#pragma unroll
                for (int ct = 0; ct < CTCW; ++ct) { Mac[ct][r] *= corr; Sac[ct][r] *= corr; }
            }
            float t = fminf(fminf(m_r[0], m_r[1]), fminf(m_r[2], m_r[3]));
            t = fminf(t, __shfl_xor(t, 16, 64));
            t = fminf(t, __shfl_xor(t, 32, 64));
            mw = t;
        }

#pragma unroll
        for (int ct = 0; ct < 4; ++ct)
#pragma unroll
            for (int r = 0; r < 4; ++r) {
                float p = exp2f(S[ct][r] - m_r[r]);
                l_l[r] += p;
                Pw[(quad * 4 + r) * 72 + ct * 16 + l15] = f16_bits(p);
            }

        half8 pf0 = ldh(Pw + l15 * 72 + 0  + quad * 8);
        half8 pf1 = ldh(Pw + l15 * 72 + 32 + quad * 8);

        // ---- PV / PV^2 ----
#pragma unroll
        for (int g = 0; g < VCW; g += G) {
            __syncthreads();
#pragma unroll
            for (int s = 0; s < 4; ++s) {
                const int h = s / G, j = s % G;
                stage64_async(Vth, (long)b * C + (h * VCW + g + j) * 64, N, kt * 64,
                              smem + s * 4096, tid);
            }
            __syncthreads();
#pragma unroll
            for (int ks = 0; ks < 2; ++ks) {
                half8 pf = ks ? pf1 : pf0;
#pragma unroll
                for (int j = 0; j < G; ++j)
#pragma unroll
                    for (int ct = 0; ct < 4; ++ct) {
                        half8 vh = ldsw(smem + (ch2 * G + j) * 4096,
                                        ct * 16 + l15, ks * 32 + quad * 8);
                        half8 uh = vh * vh;
                        const int ci = (g + j) * 4 + ct;
                        Mac[ci] = MFMAH(pf, vh, Mac[ci]);
                        Sac[ci] = MFMAH(pf, uh, Sac[ci]);
                    }
            }
        }
    }

    // ---- reduce per-lane l, dump partial state ----
#pragma unroll
    for (int off = 1; off <= 8; off <<= 1)
#pragma unroll
        for (int r = 0; r < 4; ++r) l_l[r] += __shfl_xor(l_l[r], off, 64);

    if (ch2 == 0 && l15 == 0) {
#pragma unroll
        for (int r = 0; r < 4; ++r) {
            Pmo[po * 16 + quad * 4 + r] = m_r[r];
            Plo[po * 16 + quad * 4 + r] = l_l[r];
        }
    }
    const int chb = ch2 * (C / CSPLIT);
#pragma unroll
    for (int ct = 0; ct < CTCW; ++ct)
#pragma unroll
        for (int r = 0; r < 4; ++r) {
            long idx = (po * 16 + quad * 4 + r) * C + chb + ct * 16 + l15;
            PMo[idx] = Mac[ct][r];
            PSo[idx] = Sac[ct][r];
        }
}

// fused s3+s4 flash: one launch (s4 now SPLIT=2, private partials in arena)
__global__ void __launch_bounds__(256, 2) flash34(
    const ushort_t* __restrict__ Qh3, const ushort_t* __restrict__ Kh3,
    const ushort_t* __restrict__ Vth3,
    float* __restrict__ Pm3, float* __restrict__ Pl3,
    float* __restrict__ PM3, float* __restrict__ PS3,
    const ushort_t* __restrict__ Qh4, const ushort_t* __restrict__ Kh4,
    const ushort_t* __restrict__ Vth4,
    float* __restrict__ Pm4, float* __restrict__ Pl4,
    float* __restrict__ PM4, float* __restrict__ PS4)
{
    __shared__ __align__(16) ushort_t smem[35328];
    if ((int)blockIdx.x < 512)
        flash_body<960, 512, 1024, 2, false, 4, 5, 5>(
            Qh3, Kh3, Vth3, Pm3, Pl3, PM3, PS3, smem, (int)blockIdx.x);
    else
        flash_body<1472, 512, 256, 4, false, 2, 6, 6>(
            Qh4, Kh4, Vth4, Pm4, Pl4, PM4, PS4, smem, (int)blockIdx.x - 512);
}

// ---------------------------------------------------------------------------
// Combine body (merge SPLIT partials, inline content stats, fused MSE).
// ---------------------------------------------------------------------------
template<int C, int SPLIT>
__device__ __forceinline__ void combine_body(
    const float* __restrict__ Pm, const float* __restrict__ Pl,
    const float* __restrict__ PM, const float* __restrict__ PS,
    const float* __restrict__ CT, const float* __restrict__ CS,
    const float* __restrict__ csum, const float* __restrict__ csq,
    float invN, float* __restrict__ loss, int N, int pi, float* shm)
{
    constexpr int CL4 = C / 4;
    float (*wS)[16] = (float(*)[16])shm;
    float* invL = shm + SPLIT * 16;
    float* red  = invL + 16;
    const int nb = N / 16;
    const int b  = pi / nb;
    const long g0 = (long)b * N + (long)(pi % nb) * 16;
    const int tid = threadIdx.x;

    if (tid < 16) {
        float m = -1e30f;
#pragma unroll
        for (int s = 0; s < SPLIT; ++s)
            m = fmaxf(m, Pm[((long)pi * SPLIT + s) * 16 + tid]);
        float L = 0.f;
#pragma unroll
        for (int s = 0; s < SPLIT; ++s) {
            float e = exp2f(Pm[((long)pi * SPLIT + s) * 16 + tid] - m);
            wS[s][tid] = e;
            L = fmaf(e, Pl[((long)pi * SPLIT + s) * 16 + tid], L);
        }
        invL[tid] = 1.f / L;
    }
    __syncthreads();

    float acc = 0.f;
    for (int v = tid; v < 4 * C; v += 256) {
        const int r  = v / CL4;
        const int c0 = (v - r * CL4) * 4;
        const long q0 = (((long)pi * SPLIT) * 16 + r) * C + c0;
        float4 Ms = {0.f, 0.f, 0.f, 0.f}, Ss = {0.f, 0.f, 0.f, 0.f};
#pragma unroll
        for (int s = 0; s < SPLIT; ++s) {
            const float ws_ = wS[s][r];
            const float4 pm = *(const float4*)&PM[q0 + (long)s * 16 * C];
            const float4 ps = *(const float4*)&PS[q0 + (long)s * 16 * C];
            Ms.x = fmaf(ws_, pm.x, Ms.x); Ms.y = fmaf(ws_, pm.y, Ms.y);
            Ms.z = fmaf(ws_, pm.z, Ms.z); Ms.w = fmaf(ws_, pm.w, Ms.w);
            Ss.x = fmaf(ws_, ps.x, Ss.x); Ss.y = fmaf(ws_, ps.y, Ss.y);
            Ss.z = fmaf(ws_, ps.z, Ss.z); Ss.w = fmaf(ws_, ps.w, Ss.w);
        }
        const float iL = invL[r];
        const float4 ctv = *(const float4*)&CT[(g0 + r) * C + c0];
        const float4 csv = *(const float4*)&CS[(g0 + r) * C + c0];
        const float4 cs4 = *(const float4*)&csum[b * C + c0];
        const float4 cq4 = *(const float4*)&csq[b * C + c0];
#pragma unroll
        for (int e = 0; e < 4; ++e) {
            const float Msx = (&Ms.x)[e] * iL;
            const float S2  = (&Ss.x)[e] * iL - Msx * Msx;
            const float Sx  = sqrtf(fmaxf(S2, EPS_VAR));
            const float cm  = (&cs4.x)[e] * invN;
            const float cr  = rsqrtf((&cq4.x)[e] * invN - cm * cm + EPS_NORM);
            const float nc  = ((&ctv.x)[e] - cm) * cr;
            const float d   = (&csv.x)[e] - (Sx * nc + Msx);
            acc = fmaf(d, d, acc);
        }
    }
#pragma unroll
    for (int off = 1; off <= 32; off <<= 1) acc += __shfl_xor(acc, off, 64);
    if ((tid & 63) == 0) red[tid >> 6] = acc;
    __syncthreads();
    if (tid == 0) atomicAdd(loss, red[0] + red[1] + red[2] + red[3]);
}

// ---------------------------------------------------------------------------
// mid_fused: combine2 (1024) || prep3 norm (2048) || vt3 (512) || prep4 norm
// (512) || vt4 (128) — all depend only on flash_pipe.
// ---------------------------------------------------------------------------
struct MidP {
    const float *Pm, *Pl, *PM, *PS, *CT, *CS, *csum, *csq;
    float* loss;
    const float *q3x, *q3s, *q3q, *k3x, *k3s, *k3q, *v3x;
    ushort_t *qh3, *kh3, *vt3;
    const float *q4x, *q4s, *q4q, *k4x, *k4s, *k4q, *v4x;
    ushort_t *qh4, *kh4, *vt4;
};
__global__ void __launch_bounds__(256) mid_fused(MidP P)
{
    __shared__ __align__(16) ushort_t lbuf[4608];
    int bx = blockIdx.x;
    if (bx < 1024) {
        combine_body<256, 2>(P.Pm, P.Pl, P.PM, P.PS, P.CT, P.CS, P.csum, P.csq,
                             1.0f / 4096.0f, P.loss, 4096, bx, (float*)lbuf);
    } else if (bx < 3072) {
        norm_quad(bx - 1024, P.q3x, P.q3s, P.q3q, P.k3x, P.k3s, P.k3q,
                  P.qh3, P.kh3, 1024, 960, 1.0f / 1024.0f);
    } else if (bx < 3584) {
        vtile(bx - 3072, P.v3x, P.vt3, 1024, 512, lbuf);
    } else if (bx < 4096) {
        norm_quad(bx - 3584, P.q4x, P.q4s, P.q4q, P.k4x, P.k4s, P.k4q,
                  P.qh4, P.kh4, 256, 1472, 1.0f / 256.0f);
    } else {
        vtile(bx - 4096, P.v4x, P.vt4, 256, 512, lbuf);
    }
}

// ---------------------------------------------------------------------------
// combine34_final: combine3 (256, SPLIT=4) || combine4 (64, SPLIT=2), then
// last-finishing block folds the final weighted loss (counter in lossp[3]).
// ---------------------------------------------------------------------------
struct C34P {
    const float *Pm3, *Pl3, *PM3, *PS3, *CT3, *CS3, *c3s, *c3q;
    const float *Pm4, *Pl4, *PM4, *PS4, *CT4, *CS4, *c4s, *c4q;
    float* lossp;      // [0..2] partial losses, [3] = completion counter bits
    float* out;
    float s0, s1, s2;
};
__global__ void __launch_bounds__(256) combine34_final(C34P P)
{
    __shared__ float shm[4 * 16 + 20];
    int bx = blockIdx.x;
    if (bx < 256)
        combine_body<512, 4>(P.Pm3, P.Pl3, P.PM3, P.PS3, P.CT3, P.CS3, P.c3s, P.c3q,
                             1.0f / 1024.0f, &P.lossp[1], 1024, bx, shm);
    else
        combine_body<512, 2>(P.Pm4, P.Pl4, P.PM4, P.PS4, P.CT4, P.CS4, P.c4s, P.c4q,
                             1.0f / 256.0f, &P.lossp[2], 256, bx - 256, shm);
    __threadfence();
    if (threadIdx.x == 0) {
        unsigned old = atomicAdd((unsigned*)&P.lossp[3], 1u);
        if (old == 319u) {
            float l0 = atomicAdd(&P.lossp[0], 0.0f);
            float l1 = atomicAdd(&P.lossp[1], 0.0f);
            float l2 = atomicAdd(&P.lossp[2], 0.0f);
            P.out[0] = l0 * P.s0 + l1 * P.s1 + l2 * P.s2;
        }
    }
}

// ---------------------------------------------------------------------------
// Fallback scalar flash kernel (only if ws_size too small)
// ---------------------------------------------------------------------------
template<int CCL, int CL, int NQ>
__global__ void __launch_bounds__(256) flash_aat(
    const float* __restrict__ Q, const float* __restrict__ K, const float* __restrict__ V,
    const float* __restrict__ CT, const float* __restrict__ CS,
    const float* __restrict__ qmean, const float* __restrict__ qrstd,
    const float* __restrict__ kmean, const float* __restrict__ krstd,
    const float* __restrict__ cmean, const float* __restrict__ crstd,
    float* __restrict__ loss, int N)
{
    constexpr int CC   = CCL * 64;
    constexpr int C    = CL * 64;
    constexpr int ROWS = 4 * NQ;
    const int lane = threadIdx.x & 63;
    const int wave = threadIdx.x >> 6;
    const int rowBlocks = N / ROWS;
    const int b  = blockIdx.x / rowBlocks;
    const int rb = blockIdx.x % rowBlocks;
    const int i0 = rb * ROWS + wave * NQ;

    float kmu[CCL], krs[CCL];
#pragma unroll
    for (int t = 0; t < CCL; ++t) {
        int ch = lane + 64 * t;
        kmu[t] = kmean[b * CC + ch];
        krs[t] = krstd[b * CC + ch];
    }
    float q[NQ][CCL];
#pragma unroll
    for (int qi = 0; qi < NQ; ++qi) {
        long base = (long)(b * N + i0 + qi) * CC;
#pragma unroll
        for (int t = 0; t < CCL; ++t) {
            int ch = lane + 64 * t;
            q[qi][t] = (Q[base + ch] - qmean[b * CC + ch]) * qrstd[b * CC + ch];
        }
    }
    float mval[NQ], lsum[NQ];
    float Macc[NQ][CL], Sacc[NQ][CL];
#pragma unroll
    for (int qi = 0; qi < NQ; ++qi) {
        mval[qi] = -1e30f; lsum[qi] = 0.f;
#pragma unroll
        for (int t = 0; t < CL; ++t) { Macc[qi][t] = 0.f; Sacc[qi][t] = 0.f; }
    }
    for (int j = 0; j < N; ++j) {
        long kb = (long)(b * N + j) * CC;
        float dot[NQ];
#pragma unroll
        for (int qi = 0; qi < NQ; ++qi) dot[qi] = 0.f;
#pragma unroll
        for (int t = 0; t < CCL; ++t) {
            float kv = (K[kb + lane + 64 * t] - kmu[t]) * krs[t];
#pragma unroll
            for (int qi = 0; qi < NQ; ++qi) dot[qi] = fmaf(q[qi][t], kv, dot[qi]);
        }
#pragma unroll
        for (int off = 32; off > 0; off >>= 1)
#pragma unroll
            for (int qi = 0; qi < NQ; ++qi) dot[qi] += __shfl_xor(dot[qi], off, 64);
        long vb = (long)(b * N + j) * C;
        float vv[CL];
#pragma unroll
        for (int t = 0; t < CL; ++t) vv[t] = V[vb + lane + 64 * t];
#pragma unroll
        for (int qi = 0; qi < NQ; ++qi) {
            float s = dot[qi];
            float p;
            if (s > mval[qi]) {
                float cr2 = __expf(mval[qi] - s);
                lsum[qi] *= cr2;
#pragma unroll
                for (int t = 0; t < CL; ++t) { Macc[qi][t] *= cr2; Sacc[qi][t] *= cr2; }
                mval[qi] = s; p = 1.f;
            } else p = __expf(s - mval[qi]);
            lsum[qi] += p;
#pragma unroll
            for (int t = 0; t < CL; ++t) {
                float pv = p * vv[t];
                Macc[qi][t] += pv;
                Sacc[qi][t] = fmaf(pv, vv[t], Sacc[qi][t]);
            }
        }
    }
    float acc = 0.f;
#pragma unroll
    for (int qi = 0; qi < NQ; ++qi) {
        float inv_l = 1.f / lsum[qi];
        long base = (long)(b * N + i0 + qi) * C;
#pragma unroll
        for (int t = 0; t < CL; ++t) {
            int ch = lane + 64 * t;
            float M  = Macc[qi][t] * inv_l;
            float S2 = Sacc[qi][t] * inv_l - M * M;
            float S  = sqrtf(fmaxf(S2, EPS_VAR));
            float nc = (CT[base + ch] - cmean[b * C + ch]) * crstd[b * C + ch];
            float d  = CS[base + ch] - (S * nc + M);
            acc = fmaf(d, d, acc);
        }
    }
#pragma unroll
    for (int off = 32; off > 0; off >>= 1) acc += __shfl_xor(acc, off, 64);
    if (lane == 0) atomicAdd(loss, acc);
}

__global__ void combine_loss(const float* __restrict__ lp, float* __restrict__ out,
                             float s0, float s1, float s2)
{
    out[0] = lp[0] * s0 + lp[1] * s1 + lp[2] * s2;
}

// ---------------------------------------------------------------------------
extern "C" void kernel_launch(void* const* d_in, const int* in_sizes, int n_in,
                              void* d_out, int out_size, void* d_ws, size_t ws_size,
                              hipStream_t stream)
{
    const float* cs2 = (const float*)d_in[0];
    const float* c2  = (const float*)d_in[1];
    const float* s2v = (const float*)d_in[2];
    const float* cc2 = (const float*)d_in[3];
    const float* sc2 = (const float*)d_in[4];
    const float* cs3 = (const float*)d_in[5];
    const float* c3  = (const float*)d_in[6];
    const float* s3v = (const float*)d_in[7];
    const float* cc3 = (const float*)d_in[8];
    const float* sc3 = (const float*)d_in[9];
    const float* cs4 = (const float*)d_in[10];
    const float* c4  = (const float*)d_in[11];
    const float* s4v = (const float*)d_in[12];
    const float* cc4 = (const float*)d_in[13];
    const float* sc4 = (const float*)d_in[14];

    const int B = 4;
    float* ws = (float*)d_ws;
    size_t fo = 0;
    auto allocF = [&](size_t n) { float* p = ws + fo; fo += n; return p; };

    // NOTE: allocation layout kept byte-identical to the proven round-0 budget.
    float* lossp = allocF(4);                  // [3] doubles as completion counter
    float* c2m = allocF(B * 256);  float* c2r = allocF(B * 256);
    float* q2m = allocF(B * 448);  float* q2r = allocF(B * 448);
    float* k2m = allocF(B * 448);  float* k2r = allocF(B * 448);
    float* c3m = allocF(B * 512);  float* c3r = allocF(B * 512);
    float* q3m = allocF(B * 960);  float* q3r = allocF(B * 960);
    float* k3m = allocF(B * 960);  float* k3r = allocF(B * 960);
    float* c4m = allocF(B * 512);  float* c4r = allocF(B * 512);
    float* q4m = allocF(B * 1472); float* q4r = allocF(B * 1472);
    float* k4m = allocF(B * 1472); float* k4r = allocF(B * 1472);
    size_t zeroBytes = fo * sizeof(float);

    float* Pm = allocF(32768);
    float* Pl = allocF(32768);
    float* PM = allocF(8388608);
    float* PS = allocF(8388608);

    size_t arenaOff = ((fo * 4 + 15) & ~(size_t)15) / 2;
    ushort_t* arena = (ushort_t*)d_ws + arenaOff;
    const size_t arenaShorts = 18874400;
    size_t need = arenaOff * 2 + arenaShorts * 2;
    const bool fast = (ws_size >= need);

    hipMemsetAsync(d_ws, 0, zeroBytes, stream);

    // ---- fused stats (1 launch, raw sums; consumers finalize inline) ----
    {
        StatJobs SJ;
        const float* xs[9] = {c2, cc2, sc2, c3, cc3, sc3, c4, cc4, sc4};
        float* sms[9] = {c2m, q2m, k2m, c3m, q3m, k3m, c4m, q4m, k4m};
        float* sqs[9] = {c2r, q2r, k2r, c3r, q3r, k3r, c4r, q4r, k4r};
        const int Ns[9]  = {4096, 4096, 4096, 1024, 1024, 1024, 256, 256, 256};
        const int Cns[9] = {256, 448, 448, 512, 960, 960, 512, 1472, 1472};
        int pb = 0;
        for (int j = 0; j < 9; ++j) {
            int chG = (Cns[j] + 255) / 256;
            int nG  = (Ns[j] + 127) / 128;
            SJ.x[j] = xs[j]; SJ.sm[j] = sms[j]; SJ.sq[j] = sqs[j];
            SJ.N[j] = Ns[j]; SJ.Cn[j] = Cns[j]; SJ.chG[j] = chG; SJ.nG[j] = nG;
            SJ.base[j] = pb;
            pb += B * chG * nG;
        }
        hipLaunchKernelGGL(stat_partial_all, dim3(pb), dim3(256), 0, stream, SJ);
    }

    if (fast) {
        // scale-2 fp16 tensors occupy the arena head (as always)
        ushort_t* qh2 = arena;
        ushort_t* kh2 = qh2 + (size_t)B * 4096 * 448;
        ushort_t* vh2 = kh2 + (size_t)B * 4096 * 448;
        // scales 3/4 reuse the SAME region after scale-2 flash completes
        ushort_t* qh3 = arena;
        ushort_t* kh3 = qh3 + (size_t)B * 1024 * 960;
        ushort_t* vh3 = kh3 + (size_t)B * 1024 * 960;
        ushort_t* qh4 = vh3 + (size_t)B * 1024 * 512;
        ushort_t* kh4 = qh4 + (size_t)B * 256 * 1472;
        ushort_t* vh4 = kh4 + (size_t)B * 256 * 1472;
        // s4 private partials in the arena tail (SPLIT=2: 2 x 1,048,576 floats)
        size_t o34 = (size_t)B * 1024 * 960 * 2 + (size_t)B * 1024 * 512
                   + (size_t)B * 256 * 1472 * 2 + (size_t)B * 256 * 512;
        float* PM4 = (float*)(arena + o34);
        float* PS4 = PM4 + 1048576;
        float* Pm4 = Pm + 16384;
        float* Pl4 = Pl + 16384;

        // 1) prep scale 2 (norm q/k + V transpose)
        hipLaunchKernelGGL(prep2, dim3(8192 + 1024), dim3(256), 0, stream,
                           cc2, q2m, q2r, sc2, k2m, k2r, qh2, kh2, s2v, vh2);
        // 2) flash scale 2
        hipLaunchKernelGGL(flash_pipe, dim3(512), dim3(256), 0, stream,
                           qh2, kh2, vh2, Pm, Pl, PM, PS);
        // 3) combine2 || prep scales 3+4 (arena now free of scale-2 readers)
        {
            MidP MP;
            MP.Pm = Pm; MP.Pl = Pl; MP.PM = PM; MP.PS = PS;
            MP.CT = c2; MP.CS = cs2; MP.csum = c2m; MP.csq = c2r;
            MP.loss = &lossp[0];
            MP.q3x = cc3; MP.q3s = q3m; MP.q3q = q3r;
            MP.k3x = sc3; MP.k3s = k3m; MP.k3q = k3r; MP.v3x = s3v;
            MP.qh3 = qh3; MP.kh3 = kh3; MP.vt3 = vh3;
            MP.q4x = cc4; MP.q4s = q4m; MP.q4q = q4r;
            MP.k4x = sc4; MP.k4s = k4m; MP.k4q = k4r; MP.v4x = s4v;
            MP.qh4 = qh4; MP.kh4 = kh4; MP.vt4 = vh4;
            hipLaunchKernelGGL(mid_fused, dim3(4224), dim3(256), 0, stream, MP);
        }
        // 4) flash scales 3+4 fused
        hipLaunchKernelGGL(flash34, dim3(512 + 128), dim3(256), 0, stream,
                           qh3, kh3, vh3, Pm, Pl, PM, PS,
                           qh4, kh4, vh4, Pm4, Pl4, PM4, PS4);
        // 5) combine3 || combine4 + final loss fold (last block)
        {
            C34P CP;
            CP.Pm3 = Pm; CP.Pl3 = Pl; CP.PM3 = PM; CP.PS3 = PS;
            CP.CT3 = c3; CP.CS3 = cs3; CP.c3s = c3m; CP.c3q = c3r;
            CP.Pm4 = Pm4; CP.Pl4 = Pl4; CP.PM4 = PM4; CP.PS4 = PS4;
            CP.CT4 = c4; CP.CS4 = cs4; CP.c4s = c4m; CP.c4q = c4r;
            CP.lossp = lossp; CP.out = (float*)d_out;
            CP.s0 = 1.0f / (4.0f * 4096.0f * 256.0f);
            CP.s1 = 1.0f / (4.0f * 1024.0f * 512.0f);
            CP.s2 = 1.0f / (4.0f * 256.0f * 512.0f);
            hipLaunchKernelGGL(combine34_final, dim3(256 + 64), dim3(256), 0, stream, CP);
        }
    } else {
        // fallback: finalize stats then scalar flash
        {
            FinJobs FJ;
            float* sms[9] = {c2m, q2m, k2m, c3m, q3m, k3m, c4m, q4m, k4m};
            float* sqs[9] = {c2r, q2r, k2r, c3r, q3r, k3r, c4r, q4r, k4r};
            const int Ns[9]  = {4096, 4096, 4096, 1024, 1024, 1024, 256, 256, 256};
            const int Cns[9] = {256, 448, 448, 512, 960, 960, 512, 1472, 1472};
            int fb = 0;
            for (int j = 0; j < 9; ++j) {
                FJ.sm[j] = sms[j]; FJ.sq[j] = sqs[j]; FJ.base[j] = fb;
                FJ.invN[j] = 1.0f / (float)Ns[j];
                fb += B * Cns[j];
            }
            FJ.total = fb;
            hipLaunchKernelGGL(stat_finalize_all, dim3((fb + 255) / 256), dim3(256), 0, stream, FJ);
        }
        hipLaunchKernelGGL((flash_aat<7, 4, 4>), dim3(B * 4096 / 16), dim3(256), 0, stream,
                           cc2, sc2, s2v, c2, cs2, q2m, q2r, k2m, k2r, c2m, c2r, &lossp[0], 4096);
        hipLaunchKernelGGL((flash_aat<15, 8, 2>), dim3(B * 1024 / 8), dim3(256), 0, stream,
                           cc3, sc3, s3v, c3, cs3, q3m, q3r, k3m, k3r, c3m, c3r, &lossp[1], 1024);
        hipLaunchKernelGGL((flash_aat<23, 8, 2>), dim3(B * 256 / 8), dim3(256), 0, stream,
                           cc4, sc4, s4v, c4, cs4, q4m, q4r, k4m, k4r, c4m, c4r, &lossp[2], 256);
        hipLaunchKernelGGL(combine_loss, dim3(1), dim3(1), 0, stream,
                           lossp, (float*)d_out,
                           1.0f / (4.0f * 4096.0f * 256.0f),
                           1.0f / (4.0f * 1024.0f * 512.0f),
                           1.0f / (4.0f * 256.0f * 512.0f));
    }
}